// Round 15
// baseline (412.278 us; speedup 1.0000x reference)
//
#include <hip/hip_runtime.h>
#include <math.h>

#define BB 8
#define NN 325
#define TT 24
#define DD 64
#define HH 8
#define MM 16
#define E2 128
#define DK 16
#define NEG 0.1f
#define NNODE (BB * NN)          // 2600
#define HTM 328                  // padded m-extent of ht rows

typedef short bf16x8 __attribute__((ext_vector_type(8)));
typedef float f32x4 __attribute__((ext_vector_type(4)));

__device__ __forceinline__ unsigned short f2bf(float f) {
    union { float f; unsigned u; } v; v.f = f;
    unsigned r = v.u + 0x7fffu + ((v.u >> 16) & 1u);   // RNE
    return (unsigned short)(r >> 16);
}
__device__ __forceinline__ unsigned packbf(float a, float b) {
    return (unsigned)f2bf(a) | ((unsigned)f2bf(b) << 16);
}
__device__ __forceinline__ float bflo(unsigned u) { return __uint_as_float(u << 16); }
__device__ __forceinline__ float bfhi(unsigned u) { return __uint_as_float(u & 0xffff0000u); }

__device__ __forceinline__ bf16x8 pack_bf8(float4 lo, float4 hi) {
    bf16x8 r;
    r[0] = (short)f2bf(lo.x); r[1] = (short)f2bf(lo.y);
    r[2] = (short)f2bf(lo.z); r[3] = (short)f2bf(lo.w);
    r[4] = (short)f2bf(hi.x); r[5] = (short)f2bf(hi.y);
    r[6] = (short)f2bf(hi.z); r[7] = (short)f2bf(hi.w);
    return r;
}

// ---------------- K1: tfeat[b][m] = tanh(mean_t(tXin[b,0,t,:]) @ tproj_w + tproj_b)
__global__ void k_tfeat(const float* __restrict__ tXin, const float* __restrict__ tproj_w,
                        const float* __restrict__ tproj_b, float* __restrict__ tfeat) {
    int b = blockIdx.x;
    int d = threadIdx.x;  // 64 threads
    __shared__ float mv[DD];
    float a = 0.f;
    for (int t = 0; t < TT; ++t)
        a += tXin[((size_t)(b * NN + 0) * TT + t) * DD + d];
    mv[d] = a * (1.f / (float)TT);
    __syncthreads();
    if (d < MM) {
        float acc = tproj_b[d];
        for (int j = 0; j < DD; ++j) acc += mv[j] * tproj_w[j * MM + d];
        tfeat[b * MM + d] = tanhf(acc);
    }
}

// ---------------- K_cw: out_w/gate_w -> bf16 B-fragment layout (once, 1 block)
__global__ __launch_bounds__(256) void k_cw(const float* __restrict__ out_w,
                                            const float* __restrict__ gate_w,
                                            unsigned short* __restrict__ cw) {
    int tid = threadIdx.x;
    for (int idx = tid; idx < 8192; idx += 256) {
        int i = idx >> 6, k = idx & 63;
        int nt = k >> 4, ks = i >> 5;
        int lane = (k & 15) | (((i >> 3) & 3) << 4);
        int off = (nt * 4 + ks) * 512 + lane * 8 + (i & 7);
        cw[off] = f2bf(out_w[i * 64 + k]);
        cw[8192 + off] = f2bf(gate_w[i * 64 + k]);
    }
}

// ---------------- K_wconv: W (fp32) -> bf16 A-fragment tensor over n = k*128 + i ordering.
// wb[((p*1024 + T)*64 + lane)*8 + j] = bf16(W_p[m][i][k]) with n = T*16 + (lane&15),
// i = n&127, k = n>>7, m = (lane>>4)*8 + j (zero for m>=16). Total 3 MB, one-time.
__global__ __launch_bounds__(256) void k_wconv(const float* __restrict__ WQ,
                                               const float* __restrict__ WK,
                                               const float* __restrict__ WV,
                                               unsigned short* __restrict__ wb) {
    int idx = blockIdx.x * 256 + threadIdx.x;   // 3*1024*64 = 196608
    int lane = idx & 63;
    int pt = idx >> 6;
    int T = pt & 1023, p = pt >> 10;
    const float* __restrict__ W = (p == 0) ? WQ : ((p == 1) ? WK : WV);
    int n = T * 16 + (lane & 15);
    int i = n & 127, k = n >> 7;
    int mb = (lane >> 4) * 8;
    unsigned short v[8];
#pragma unroll
    for (int j = 0; j < 8; ++j) {
        int m = mb + j;
        v[j] = (m < MM) ? f2bf(W[(size_t)m * 16384 + i * 128 + k]) : (unsigned short)0;
    }
    *(uint4*)&wb[(size_t)idx * 8] = *(const uint4*)v;
}

// ---------------- K_ht: ht[bt][d][m] = bf16(hidden[b][m][t][d])  (transposed, padded to HTM)
__global__ __launch_bounds__(256) void k_ht(const float* __restrict__ hidden,
                                            unsigned short* __restrict__ ht) {
    int bt = blockIdx.x;          // b*TT + t
    int b = bt / TT, t = bt % TT;
    int m0 = blockIdx.y * 64;
    __shared__ float s[64][67];
    int tid = threadIdx.x;
#pragma unroll
    for (int i = 0; i < 4; ++i) {
        int idx = tid + i * 256;
        int mm = idx >> 4, q = idx & 15;
        int m = m0 + mm;
        float4 v = make_float4(0.f, 0.f, 0.f, 0.f);
        if (m < NN) v = *(const float4*)&hidden[((size_t)(b * NN + m) * TT + t) * DD + q * 4];
        s[mm][q * 4 + 0] = v.x; s[mm][q * 4 + 1] = v.y;
        s[mm][q * 4 + 2] = v.z; s[mm][q * 4 + 3] = v.w;
    }
    __syncthreads();
    size_t obase = (size_t)bt * DD * HTM;
    int jcap = HTM - m0;
#pragma unroll
    for (int i = 0; i < 16; ++i) {
        int idx = tid + i * 256;
        int d = idx >> 6, j = idx & 63;
        if (j < jcap) ht[obase + (size_t)d * HTM + m0 + j] = f2bf(s[j][d]);
    }
}

// ---------------- K2 (MFMA): S = matrix(b,t) @ H ; gcn_out = relu(S @ gcn_w + b)
__global__ __launch_bounds__(256) void k_gcn(const float* __restrict__ matrix,
                                             const unsigned short* __restrict__ ht,
                                             const float* __restrict__ gcn_w,
                                             const float* __restrict__ gcn_b,
                                             float* __restrict__ gcn_out) {
    int bt = blockIdx.x;
    int tile = blockIdx.y;
    int b = bt / TT, t = bt % TT;
    int n0 = tile * 64;
    int tid = threadIdx.x, lane = tid & 63, wid = tid >> 6;
    int cl = lane & 15, kg = lane >> 4;

    __shared__ unsigned short s_s[64][72];    // S bf16 [n][d]
    __shared__ unsigned short s_gw[64][72];   // gw^T bf16 [e][d]

#pragma unroll
    for (int i = 0; i < 4; ++i) {
        int idx = tid + i * 256;
        int d = idx >> 4, e0 = (idx & 15) * 4;
        float4 v = *(const float4*)&gcn_w[d * DD + e0];
        s_gw[e0 + 0][d] = f2bf(v.x); s_gw[e0 + 1][d] = f2bf(v.y);
        s_gw[e0 + 2][d] = f2bf(v.z); s_gw[e0 + 3][d] = f2bf(v.w);
    }
    __syncthreads();

    const float* mrow = matrix + (size_t)bt * NN * NN;
    const unsigned short* hbase = ht + (size_t)bt * DD * HTM;
    int strip = wid * 16;
    int arow = n0 + strip + cl;
    bool avalid = arow < NN;
    const float* arp = mrow + (size_t)arow * NN;

    f32x4 acc[4];
#pragma unroll
    for (int nt = 0; nt < 4; ++nt) acc[nt] = (f32x4){0.f, 0.f, 0.f, 0.f};

#pragma unroll 1
    for (int ch = 0; ch < 5; ++ch) {
#pragma unroll
        for (int kk = 0; kk < 2; ++kk) {
            int m0 = ch * 64 + kk * 32 + kg * 8;
            bf16x8 af = {0, 0, 0, 0, 0, 0, 0, 0};
            if (avalid) {
                float4 lo, hi;
                lo.x = arp[m0];     lo.y = arp[m0 + 1]; lo.z = arp[m0 + 2]; lo.w = arp[m0 + 3];
                hi.x = arp[m0 + 4]; hi.y = arp[m0 + 5]; hi.z = arp[m0 + 6]; hi.w = arp[m0 + 7];
                af = pack_bf8(lo, hi);
            }
#pragma unroll
            for (int nt = 0; nt < 4; ++nt) {
                union { uint4 u4; bf16x8 v; } bf;
                bf.u4 = *(const uint4*)&hbase[(size_t)(nt * 16 + cl) * HTM + m0];
                acc[nt] = __builtin_amdgcn_mfma_f32_16x16x32_bf16(af, bf.v, acc[nt], 0, 0, 0);
            }
        }
    }
    {
        int m0 = 320 + kg * 8;
        float v[8];
#pragma unroll
        for (int j = 0; j < 8; ++j)
            v[j] = (avalid && (m0 + j) < NN) ? arp[m0 + j] : 0.f;
        bf16x8 af = pack_bf8(make_float4(v[0], v[1], v[2], v[3]),
                             make_float4(v[4], v[5], v[6], v[7]));
#pragma unroll
        for (int nt = 0; nt < 4; ++nt) {
            union { uint4 u4; bf16x8 v4; } bf;
            bf.u4 = *(const uint4*)&hbase[(size_t)(nt * 16 + cl) * HTM + m0];
            acc[nt] = __builtin_amdgcn_mfma_f32_16x16x32_bf16(af, bf.v4, acc[nt], 0, 0, 0);
        }
    }

#pragma unroll
    for (int nt = 0; nt < 4; ++nt)
#pragma unroll
        for (int r = 0; r < 4; ++r)
            s_s[strip + kg * 4 + r][nt * 16 + cl] = f2bf(acc[nt][r]);

    f32x4 g[4];
#pragma unroll
    for (int nt = 0; nt < 4; ++nt) g[nt] = (f32x4){0.f, 0.f, 0.f, 0.f};
#pragma unroll
    for (int kk = 0; kk < 2; ++kk) {
        union { uint4 u4; bf16x8 v; } sa;
        sa.u4 = *(const uint4*)&s_s[strip + cl][kk * 32 + kg * 8];
#pragma unroll
        for (int nt = 0; nt < 4; ++nt) {
            union { uint4 u4; bf16x8 v; } bf;
            bf.u4 = *(const uint4*)&s_gw[nt * 16 + cl][kk * 32 + kg * 8];
            g[nt] = __builtin_amdgcn_mfma_f32_16x16x32_bf16(sa.v, bf.v, g[nt], 0, 0, 0);
        }
    }

#pragma unroll
    for (int nt = 0; nt < 4; ++nt) {
        float bias = gcn_b[nt * 16 + cl];
#pragma unroll
        for (int r = 0; r < 4; ++r) {
            int n = n0 + strip + kg * 4 + r;
            if (n < NN) {
                float v = g[nt][r] + bias;
                v = (v > 0.f) ? v : 0.f;
                gcn_out[((size_t)(b * NN + n) * TT + t) * DD + nt * 16 + cl] = v;
            }
        }
    }
}

// ---------------- K3a (MFMA): Wp[u] = e_u-weighted sum of W, via C = A(W-frags) x B(e).
// Block (16 nodes, chunk): p = chunk>>4, tr = chunk&15; wave wid owns tiles T = tr*64+wid*16+t16.
// C row = n = T*16 + (lane>>4)*4 + r (4 consecutive i at fixed k); C col = node = lane&15.
// Each lane packs its 4 results into ONE aligned uint2 and writes global directly — no LDS.
__global__ __launch_bounds__(256) void k_wp(
    const float* __restrict__ node_emb, const float* __restrict__ tfeat,
    const unsigned short* __restrict__ wb, unsigned short* __restrict__ wp,
    int u0, int Uc) {
    int un0 = blockIdx.x * 16;
    int chunk = blockIdx.y;                 // 0..47
    int p = chunk >> 4, tr = chunk & 15;
    int tid = threadIdx.x, lane = tid & 63, wid = tid >> 6;

    __shared__ float s_e[16][MM];
    {
        int nn = tid >> 4, m = tid & 15;    // 256 = 16*16 exactly
        int us = un0 + nn;
        float e = 0.f;
        if (us < Uc) {
            int u = u0 + us;
            int b = u / NN, n = u % NN;
            e = node_emb[n * MM + m] * tfeat[b * MM + m];
        }
        s_e[nn][m] = e;
    }
    __syncthreads();

    int node = lane & 15;
    int mb = (lane >> 4) * 8;
    bf16x8 ef = {0, 0, 0, 0, 0, 0, 0, 0};
    if (mb < MM) {
#pragma unroll
        for (int j = 0; j < 8; ++j) ef[j] = (short)f2bf(s_e[node][mb + j]);
    }
    int us = un0 + node;
    bool valid = us < Uc;
    unsigned short* wdst = wp + (size_t)us * 49152 + (size_t)p * 16384;
    const unsigned short* wsrc = wb + (size_t)p * 1024 * 512;

#pragma unroll 1
    for (int t16 = 0; t16 < 16; ++t16) {
        int T = tr * 64 + wid * 16 + t16;
        union { uint4 u4; bf16x8 v; } af;
        af.u4 = *(const uint4*)&wsrc[((size_t)T * 64 + lane) * 8];
        f32x4 acc = {0.f, 0.f, 0.f, 0.f};
        acc = __builtin_amdgcn_mfma_f32_16x16x32_bf16(af.v, ef, acc, 0, 0, 0);
        int k = T >> 3;
        int i0 = (T & 7) * 16 + (lane >> 4) * 4;
        int nt = k >> 4, ks = i0 >> 5;
        int lanef = (k & 15) | (((i0 >> 3) & 3) << 4);
        size_t g = ((size_t)(nt * 4 + ks) * 64 + lanef) * 8 + (i0 & 7);
        if (valid) {
            uint2 pk;
            pk.x = packbf(acc[0], acc[1]);
            pk.y = packbf(acc[2], acc[3]);
            *(uint2*)&wdst[g] = pk;
        }
    }
}

// ---------------- K3b: per node MFMA proj -> lrelu -> qkv bf16 to workspace.
__global__ __launch_bounds__(256) void k_proj(
    const float* __restrict__ hidden, const float* __restrict__ tXin,
    const unsigned short* __restrict__ wp, unsigned short* __restrict__ qkv,
    int u0) {
    int us = blockIdx.x;
    int u = u0 + us;
    int tid = threadIdx.x;
    int lane = tid & 63, wid = tid >> 6;
    int trow = lane & 15, kgrp = lane >> 4;

    size_t base = (size_t)u * TT * DD;

    bf16x8 afrag[2][4];
#pragma unroll
    for (int mt = 0; mt < 2; ++mt) {
        int t = mt * 16 + trow;
        bool valid = (t < TT);
#pragma unroll
        for (int ks = 0; ks < 4; ++ks) {
            int i0 = ks * 32 + kgrp * 8;
            float4 lo = make_float4(0.f, 0.f, 0.f, 0.f), hi = lo;
            if (valid) {
                const float* src = (i0 < DD) ? &hidden[base + t * DD + i0]
                                             : &tXin[base + t * DD + (i0 - DD)];
                lo = *(const float4*)src;
                hi = *(const float4*)(src + 4);
            }
            afrag[mt][ks] = pack_bf8(lo, hi);
        }
    }

    const unsigned short* wbase = wp + (size_t)us * 49152;
    unsigned short* qbase = qkv + (size_t)us * (3 * TT * E2);
    int rowg = kgrp * 4;
    int col0 = wid * 16 + trow;
    int col1 = (wid + 4) * 16 + trow;
#pragma unroll 1
    for (int p = 0; p < 3; ++p) {
        f32x4 acc00 = {0.f, 0.f, 0.f, 0.f}, acc01 = acc00, acc10 = acc00, acc11 = acc00;
#pragma unroll
        for (int ks = 0; ks < 4; ++ks) {
            union { uint4 u4; bf16x8 v; } c0, c1;
            c0.u4 = *(const uint4*)(wbase + (size_t)p * 16384 + (((wid) * 4 + ks) * 64 + lane) * 8);
            c1.u4 = *(const uint4*)(wbase + (size_t)p * 16384 + (((wid + 4) * 4 + ks) * 64 + lane) * 8);
            acc00 = __builtin_amdgcn_mfma_f32_16x16x32_bf16(afrag[0][ks], c0.v, acc00, 0, 0, 0);
            acc10 = __builtin_amdgcn_mfma_f32_16x16x32_bf16(afrag[1][ks], c0.v, acc10, 0, 0, 0);
            acc01 = __builtin_amdgcn_mfma_f32_16x16x32_bf16(afrag[0][ks], c1.v, acc01, 0, 0, 0);
            acc11 = __builtin_amdgcn_mfma_f32_16x16x32_bf16(afrag[1][ks], c1.v, acc11, 0, 0, 0);
        }
#pragma unroll
        for (int r = 0; r < 4; ++r) {
            int t = rowg + r;
            float v0 = acc00[r]; v0 = (v0 >= 0.f) ? v0 : NEG * v0;
            float v1 = acc01[r]; v1 = (v1 >= 0.f) ? v1 : NEG * v1;
            qbase[(p * TT + t) * E2 + col0] = f2bf(v0);
            qbase[(p * TT + t) * E2 + col1] = f2bf(v1);
        }
        if (rowg < 8) {
#pragma unroll
            for (int r = 0; r < 4; ++r) {
                int t = 16 + rowg + r;
                float v0 = acc10[r]; v0 = (v0 >= 0.f) ? v0 : NEG * v0;
                float v1 = acc11[r]; v1 = (v1 >= 0.f) ? v1 : NEG * v1;
                qbase[(p * TT + t) * E2 + col0] = f2bf(v0);
                qbase[(p * TT + t) * E2 + col1] = f2bf(v1);
            }
        }
    }
}

// ---------------- K3c: per node: attention (scalar C1/C2) + MFMA out-proj/gate + residual
#define QKS 66
#define QKP (TT * QKS)
#define SC_OFF 4752
#define VAL_OFF 7248
#define VQS 68
__global__ __launch_bounds__(256) void k_attn2(
    const unsigned* __restrict__ qkv, const float* __restrict__ hidden,
    const unsigned short* __restrict__ cw,
    const float* __restrict__ out_b, const float* __restrict__ gate_b,
    const float* __restrict__ gcn_out, float* __restrict__ out,
    int u0) {
    int us = blockIdx.x;
    int u = u0 + us;
    int tid = threadIdx.x;

    __shared__ __align__(16) unsigned arena[8880];
    __shared__ float s_gcn[TT][VQS];
    __shared__ float s_value[TT][VQS];

    size_t base = (size_t)u * TT * DD;

    const unsigned* src = qkv + (size_t)us * (3 * TT * 64);
    for (int idx = tid; idx < 3 * TT * 64; idx += 256) {
        int p = idx / (TT * 64);
        int r = idx % (TT * 64);
        int t = r >> 6, kp = r & 63;
        arena[p * QKP + t * QKS + kp] = src[idx];
    }
    for (int idx = tid; idx < TT * DD; idx += 256)
        s_gcn[idx >> 6][idx & 63] = gcn_out[base + idx];
    unsigned* s_qkv = arena;
    __syncthreads();

    // ---- phase C1: scores (scalar)
    unsigned* s_sc = arena + SC_OFF;
    if (tid < HH * TT) {
        int h = tid / TT, t = tid % TT;
        const float scale = 0.25f;
        float qf[16];
#pragma unroll
        for (int j = 0; j < 8; ++j) {
            unsigned uq = s_qkv[0 * QKP + t * QKS + 8 * h + j];
            qf[2 * j] = bflo(uq); qf[2 * j + 1] = bfhi(uq);
        }
#pragma unroll
        for (int s2 = 0; s2 < 12; ++s2) {
            int s0 = 2 * s2;
            float d0 = 0.f, d1 = 0.f;
#pragma unroll
            for (int j = 0; j < 8; ++j) {
                unsigned ka = s_qkv[1 * QKP + s0 * QKS + 8 * h + j];
                unsigned kb = s_qkv[1 * QKP + (s0 + 1) * QKS + 8 * h + j];
                d0 += qf[2 * j] * bflo(ka) + qf[2 * j + 1] * bfhi(ka);
                d1 += qf[2 * j] * bflo(kb) + qf[2 * j + 1] * bfhi(kb);
            }
            float w0 = (s0 <= t) ? __expf(d0 * scale) : 0.f;
            float w1 = (s0 + 1 <= t) ? __expf(d1 * scale) : 0.f;
            s_sc[(h * TT + t) * 13 + s2] = packbf(w0, w1);
        }
    }
    __syncthreads();

    // ---- phase C2: normalize + PV -> packed val[24][VQS]
    unsigned* s_val = arena + VAL_OFF;
#pragma unroll
    for (int it = 0; it < 3; ++it) {
        int item = tid + it * 256;
        int h = item / 96;
        int r = item % 96;
        int t = r >> 2, d4 = r & 3;
        int kg0 = 8 * h + 2 * d4;
        float sum = 0.f, v0 = 0.f, v1 = 0.f, v2 = 0.f, v3 = 0.f;
#pragma unroll
        for (int s2 = 0; s2 < 12; ++s2) {
            unsigned uw = s_sc[(h * TT + t) * 13 + s2];
            float w0 = bflo(uw), w1 = bfhi(uw);
            sum += w0 + w1;
            unsigned ua = s_qkv[2 * QKP + (2 * s2) * QKS + kg0];
            unsigned ub = s_qkv[2 * QKP + (2 * s2) * QKS + kg0 + 1];
            v0 += w0 * bflo(ua); v1 += w0 * bfhi(ua);
            v2 += w0 * bflo(ub); v3 += w0 * bfhi(ub);
            unsigned uc = s_qkv[2 * QKP + (2 * s2 + 1) * QKS + kg0];
            unsigned ud = s_qkv[2 * QKP + (2 * s2 + 1) * QKS + kg0 + 1];
            v0 += w1 * bflo(uc); v1 += w1 * bfhi(uc);
            v2 += w1 * bflo(ud); v3 += w1 * bfhi(ud);
        }
        float inv = 1.f / sum;
        s_val[t * VQS + kg0]     = packbf(v0 * inv, v1 * inv);
        s_val[t * VQS + kg0 + 1] = packbf(v2 * inv, v3 * inv);
    }
    __syncthreads();

    // ---- phase D (MFMA): value = lrelu(val @ out_w + out_b)
    int lane = tid & 63, wid = tid >> 6;
    int cl = lane & 15, kg = lane >> 4;
    {
        f32x4 d0 = {0.f, 0.f, 0.f, 0.f}, d1 = d0;
#pragma unroll
        for (int ks = 0; ks < 4; ++ks) {
            union { uint4 u4; bf16x8 v; } a0, a1, bw;
            a0.u4 = *(const uint4*)&s_val[cl * VQS + ks * 16 + kg * 4];
            if (cl < 8) a1.u4 = *(const uint4*)&s_val[(16 + cl) * VQS + ks * 16 + kg * 4];
            else a1.u4 = make_uint4(0, 0, 0, 0);
            bw.u4 = *(const uint4*)&cw[((size_t)(wid * 4 + ks) * 64 + lane) * 8];
            d0 = __builtin_amdgcn_mfma_f32_16x16x32_bf16(a0.v, bw.v, d0, 0, 0, 0);
            d1 = __builtin_amdgcn_mfma_f32_16x16x32_bf16(a1.v, bw.v, d1, 0, 0, 0);
        }
        int col = wid * 16 + cl;
        float bias = out_b[col];
#pragma unroll
        for (int r = 0; r < 4; ++r) {
            int t = kg * 4 + r;
            float v = d0[r] + bias; v = (v >= 0.f) ? v : NEG * v;
            s_value[t][col] = v;
        }
        if (kg < 2) {
#pragma unroll
            for (int r = 0; r < 4; ++r) {
                int t = 16 + kg * 4 + r;
                float v = d1[r] + bias; v = (v >= 0.f) ? v : NEG * v;
                s_value[t][col] = v;
            }
        }
    }
    __syncthreads();

    // ---- phase E (MFMA): z = sigmoid([gcn|value] @ gate_w + gate_b); out = z*g + (1-z)*v + hidden
    {
        f32x4 g0 = {0.f, 0.f, 0.f, 0.f}, g1 = g0;
#pragma unroll
        for (int ks = 0; ks < 4; ++ks) {
            int i0 = ks * 32 + kg * 8;
            const float* src0 = (i0 < DD) ? &s_gcn[cl][i0] : &s_value[cl][i0 - DD];
            float4 lo = *(const float4*)src0;
            float4 hi = *(const float4*)(src0 + 4);
            bf16x8 a0 = pack_bf8(lo, hi);
            bf16x8 a1 = {0, 0, 0, 0, 0, 0, 0, 0};
            if (cl < 8) {
                const float* src1 = (i0 < DD) ? &s_gcn[16 + cl][i0] : &s_value[16 + cl][i0 - DD];
                float4 lo1 = *(const float4*)src1;
                float4 hi1 = *(const float4*)(src1 + 4);
                a1 = pack_bf8(lo1, hi1);
            }
            union { uint4 u4; bf16x8 v; } bw;
            bw.u4 = *(const uint4*)&cw[8192 + ((size_t)(wid * 4 + ks) * 64 + lane) * 8];
            g0 = __builtin_amdgcn_mfma_f32_16x16x32_bf16(a0, bw.v, g0, 0, 0, 0);
            g1 = __builtin_amdgcn_mfma_f32_16x16x32_bf16(a1, bw.v, g1, 0, 0, 0);
        }
        int col = wid * 16 + cl;
        float gb = gate_b[col];
#pragma unroll
        for (int r = 0; r < 4; ++r) {
            int t = kg * 4 + r;
            float z = 1.f / (1.f + __expf(-(g0[r] + gb)));
            float gv = s_gcn[t][col], vv = s_value[t][col];
            size_t ob = base + (size_t)t * DD + col;
            out[ob] = z * gv + (1.f - z) * vv + hidden[ob];
        }
        if (kg < 2) {
#pragma unroll
            for (int r = 0; r < 4; ++r) {
                int t = 16 + kg * 4 + r;
                float z = 1.f / (1.f + __expf(-(g1[r] + gb)));
                float gv = s_gcn[t][col], vv = s_value[t][col];
                size_t ob = base + (size_t)t * DD + col;
                out[ob] = z * gv + (1.f - z) * vv + hidden[ob];
            }
        }
    }
}

extern "C" void kernel_launch(void* const* d_in, const int* in_sizes, int n_in,
                              void* d_out, int out_size, void* d_ws, size_t ws_size,
                              hipStream_t stream) {
    const float* hidden   = (const float*)d_in[0];
    const float* tXin     = (const float*)d_in[1];
    const float* matrix   = (const float*)d_in[2];
    const float* gcn_w    = (const float*)d_in[3];
    const float* gcn_b    = (const float*)d_in[4];
    const float* node_emb = (const float*)d_in[5];
    const float* tproj_w  = (const float*)d_in[6];
    const float* tproj_b  = (const float*)d_in[7];
    const float* WK_      = (const float*)d_in[8];   // dict order: WK, WQ, WV
    const float* WQ_      = (const float*)d_in[9];
    const float* WV_      = (const float*)d_in[10];
    const float* out_w    = (const float*)d_in[11];
    const float* out_b    = (const float*)d_in[12];
    const float* gate_w   = (const float*)d_in[13];
    const float* gate_b   = (const float*)d_in[14];
    float* out = (float*)d_out;

    char* ws = (char*)d_ws;
    float* tfeat   = (float*)ws;                         // 512 B
    float* gcn_out = (float*)(ws + 512);                 // 15,974,400 B
    size_t off_ht  = 512 + (size_t)BB * NN * TT * DD * 4;
    size_t ht_size = (size_t)BB * TT * DD * HTM * 2 + 4096;
    size_t off_cw  = off_ht + ht_size;
    size_t off_wb  = off_cw + 32768;
    size_t wb_size = (size_t)3 * 1024 * 64 * 8 * 2;      // 3,145,728 B
    size_t off_wp  = off_wb + wb_size;

    const size_t per_wp  = 3 * (size_t)E2 * E2 * 2;      // 98304 B per node (bf16)
    const size_t per_qkv = 3 * (size_t)TT * E2 * 2;      // 18432 B per node (bf16)
    long long avail = (long long)ws_size - (long long)off_wp;
    long long Ull = avail / (long long)(per_wp + per_qkv);
    int U = (Ull < 1) ? 1 : ((Ull > NNODE) ? NNODE : (int)Ull);
    // NOTE: no UCAP — R14's 384-node chunking made 7 serial small-grid passes (+70 us).

    unsigned short* ht_buf  = (unsigned short*)(ws + off_ht);
    unsigned short* cw_buf  = (unsigned short*)(ws + off_cw);
    unsigned short* wb_buf  = (unsigned short*)(ws + off_wb);
    unsigned short* wp_buf  = (unsigned short*)(ws + off_wp);
    unsigned short* qkv_buf = (unsigned short*)(ws + off_wp + (size_t)U * per_wp);

    k_tfeat<<<BB, DD, 0, stream>>>(tXin, tproj_w, tproj_b, tfeat);
    k_cw<<<1, 256, 0, stream>>>(out_w, gate_w, cw_buf);
    k_wconv<<<768, 256, 0, stream>>>(WQ_, WK_, WV_, wb_buf);
    k_ht<<<dim3(BB * TT, 6), 256, 0, stream>>>(hidden, ht_buf);
    k_gcn<<<dim3(BB * TT, 6), 256, 0, stream>>>(matrix, ht_buf, gcn_w, gcn_b, gcn_out);

    for (int u0 = 0; u0 < NNODE; u0 += U) {
        int Uc = (NNODE - u0 < U) ? (NNODE - u0) : U;
        k_wp<<<dim3((Uc + 15) / 16, 48), 256, 0, stream>>>(node_emb, tfeat, wb_buf,
                                                           wp_buf, u0, Uc);
        k_proj<<<Uc, 256, 0, stream>>>(hidden, tXin, wp_buf, qkv_buf, u0);
        k_attn2<<<Uc, 256, 0, stream>>>((const unsigned*)qkv_buf, hidden, cw_buf,
                                        out_b, gate_b, gcn_out, out, u0);
    }
}

// Round 16
// 325.418 us; speedup vs baseline: 1.2669x; 1.2669x over previous
//
#include <hip/hip_runtime.h>
#include <math.h>

#define BB 8
#define NN 325
#define TT 24
#define DD 64
#define HH 8
#define MM 16
#define E2 128
#define DK 16
#define NEG 0.1f
#define NNODE (BB * NN)          // 2600
#define HTM 328                  // padded m-extent of ht rows

typedef short bf16x8 __attribute__((ext_vector_type(8)));
typedef float f32x4 __attribute__((ext_vector_type(4)));

__device__ __forceinline__ unsigned short f2bf(float f) {
    union { float f; unsigned u; } v; v.f = f;
    unsigned r = v.u + 0x7fffu + ((v.u >> 16) & 1u);   // RNE
    return (unsigned short)(r >> 16);
}
__device__ __forceinline__ unsigned packbf(float a, float b) {
    return (unsigned)f2bf(a) | ((unsigned)f2bf(b) << 16);
}
__device__ __forceinline__ float bflo(unsigned u) { return __uint_as_float(u << 16); }
__device__ __forceinline__ float bfhi(unsigned u) { return __uint_as_float(u & 0xffff0000u); }

__device__ __forceinline__ bf16x8 pack_bf8(float4 lo, float4 hi) {
    bf16x8 r;
    r[0] = (short)f2bf(lo.x); r[1] = (short)f2bf(lo.y);
    r[2] = (short)f2bf(lo.z); r[3] = (short)f2bf(lo.w);
    r[4] = (short)f2bf(hi.x); r[5] = (short)f2bf(hi.y);
    r[6] = (short)f2bf(hi.z); r[7] = (short)f2bf(hi.w);
    return r;
}

// ---------------- K1: tfeat[b][m] = tanh(mean_t(tXin[b,0,t,:]) @ tproj_w + tproj_b)
__global__ void k_tfeat(const float* __restrict__ tXin, const float* __restrict__ tproj_w,
                        const float* __restrict__ tproj_b, float* __restrict__ tfeat) {
    int b = blockIdx.x;
    int d = threadIdx.x;  // 64 threads
    __shared__ float mv[DD];
    float a = 0.f;
    for (int t = 0; t < TT; ++t)
        a += tXin[((size_t)(b * NN + 0) * TT + t) * DD + d];
    mv[d] = a * (1.f / (float)TT);
    __syncthreads();
    if (d < MM) {
        float acc = tproj_b[d];
        for (int j = 0; j < DD; ++j) acc += mv[j] * tproj_w[j * MM + d];
        tfeat[b * MM + d] = tanhf(acc);
    }
}

// ---------------- K_cw: out_w/gate_w -> bf16 B-fragment layout (once, 1 block)
__global__ __launch_bounds__(256) void k_cw(const float* __restrict__ out_w,
                                            const float* __restrict__ gate_w,
                                            unsigned short* __restrict__ cw) {
    int tid = threadIdx.x;
    for (int idx = tid; idx < 8192; idx += 256) {
        int i = idx >> 6, k = idx & 63;
        int nt = k >> 4, ks = i >> 5;
        int lane = (k & 15) | (((i >> 3) & 3) << 4);
        int off = (nt * 4 + ks) * 512 + lane * 8 + (i & 7);
        cw[off] = f2bf(out_w[i * 64 + k]);
        cw[8192 + off] = f2bf(gate_w[i * 64 + k]);
    }
}

// ---------------- K_wconv: W (fp32) -> bf16 A-fragment tensor over n = k*128 + i ordering.
__global__ __launch_bounds__(256) void k_wconv(const float* __restrict__ WQ,
                                               const float* __restrict__ WK,
                                               const float* __restrict__ WV,
                                               unsigned short* __restrict__ wb) {
    int idx = blockIdx.x * 256 + threadIdx.x;   // 3*1024*64 = 196608
    int lane = idx & 63;
    int pt = idx >> 6;
    int T = pt & 1023, p = pt >> 10;
    const float* __restrict__ W = (p == 0) ? WQ : ((p == 1) ? WK : WV);
    int n = T * 16 + (lane & 15);
    int i = n & 127, k = n >> 7;
    int mb = (lane >> 4) * 8;
    unsigned short v[8];
#pragma unroll
    for (int j = 0; j < 8; ++j) {
        int m = mb + j;
        v[j] = (m < MM) ? f2bf(W[(size_t)m * 16384 + i * 128 + k]) : (unsigned short)0;
    }
    *(uint4*)&wb[(size_t)idx * 8] = *(const uint4*)v;
}

// ---------------- K_ht: ht[bt][d][m] = bf16(hidden[b][m][t][d])  (transposed, padded to HTM)
__global__ __launch_bounds__(256) void k_ht(const float* __restrict__ hidden,
                                            unsigned short* __restrict__ ht) {
    int bt = blockIdx.x;          // b*TT + t
    int b = bt / TT, t = bt % TT;
    int m0 = blockIdx.y * 64;
    __shared__ float s[64][67];
    int tid = threadIdx.x;
#pragma unroll
    for (int i = 0; i < 4; ++i) {
        int idx = tid + i * 256;
        int mm = idx >> 4, q = idx & 15;
        int m = m0 + mm;
        float4 v = make_float4(0.f, 0.f, 0.f, 0.f);
        if (m < NN) v = *(const float4*)&hidden[((size_t)(b * NN + m) * TT + t) * DD + q * 4];
        s[mm][q * 4 + 0] = v.x; s[mm][q * 4 + 1] = v.y;
        s[mm][q * 4 + 2] = v.z; s[mm][q * 4 + 3] = v.w;
    }
    __syncthreads();
    size_t obase = (size_t)bt * DD * HTM;
    int jcap = HTM - m0;
#pragma unroll
    for (int i = 0; i < 16; ++i) {
        int idx = tid + i * 256;
        int d = idx >> 6, j = idx & 63;
        if (j < jcap) ht[obase + (size_t)d * HTM + m0 + j] = f2bf(s[j][d]);
    }
}

// ---------------- K2 (MFMA): S = matrix(b,t) @ H ; gcn_out = relu(S @ gcn_w + b)
__global__ __launch_bounds__(256) void k_gcn(const float* __restrict__ matrix,
                                             const unsigned short* __restrict__ ht,
                                             const float* __restrict__ gcn_w,
                                             const float* __restrict__ gcn_b,
                                             float* __restrict__ gcn_out) {
    int bt = blockIdx.x;
    int tile = blockIdx.y;
    int b = bt / TT, t = bt % TT;
    int n0 = tile * 64;
    int tid = threadIdx.x, lane = tid & 63, wid = tid >> 6;
    int cl = lane & 15, kg = lane >> 4;

    __shared__ unsigned short s_s[64][72];    // S bf16 [n][d]
    __shared__ unsigned short s_gw[64][72];   // gw^T bf16 [e][d]

#pragma unroll
    for (int i = 0; i < 4; ++i) {
        int idx = tid + i * 256;
        int d = idx >> 4, e0 = (idx & 15) * 4;
        float4 v = *(const float4*)&gcn_w[d * DD + e0];
        s_gw[e0 + 0][d] = f2bf(v.x); s_gw[e0 + 1][d] = f2bf(v.y);
        s_gw[e0 + 2][d] = f2bf(v.z); s_gw[e0 + 3][d] = f2bf(v.w);
    }
    __syncthreads();

    const float* mrow = matrix + (size_t)bt * NN * NN;
    const unsigned short* hbase = ht + (size_t)bt * DD * HTM;
    int strip = wid * 16;
    int arow = n0 + strip + cl;
    bool avalid = arow < NN;
    const float* arp = mrow + (size_t)arow * NN;

    f32x4 acc[4];
#pragma unroll
    for (int nt = 0; nt < 4; ++nt) acc[nt] = (f32x4){0.f, 0.f, 0.f, 0.f};

#pragma unroll 1
    for (int ch = 0; ch < 5; ++ch) {
#pragma unroll
        for (int kk = 0; kk < 2; ++kk) {
            int m0 = ch * 64 + kk * 32 + kg * 8;
            bf16x8 af = {0, 0, 0, 0, 0, 0, 0, 0};
            if (avalid) {
                float4 lo, hi;
                lo.x = arp[m0];     lo.y = arp[m0 + 1]; lo.z = arp[m0 + 2]; lo.w = arp[m0 + 3];
                hi.x = arp[m0 + 4]; hi.y = arp[m0 + 5]; hi.z = arp[m0 + 6]; hi.w = arp[m0 + 7];
                af = pack_bf8(lo, hi);
            }
#pragma unroll
            for (int nt = 0; nt < 4; ++nt) {
                union { uint4 u4; bf16x8 v; } bf;
                bf.u4 = *(const uint4*)&hbase[(size_t)(nt * 16 + cl) * HTM + m0];
                acc[nt] = __builtin_amdgcn_mfma_f32_16x16x32_bf16(af, bf.v, acc[nt], 0, 0, 0);
            }
        }
    }
    {
        int m0 = 320 + kg * 8;
        float v[8];
#pragma unroll
        for (int j = 0; j < 8; ++j)
            v[j] = (avalid && (m0 + j) < NN) ? arp[m0 + j] : 0.f;
        bf16x8 af = pack_bf8(make_float4(v[0], v[1], v[2], v[3]),
                             make_float4(v[4], v[5], v[6], v[7]));
#pragma unroll
        for (int nt = 0; nt < 4; ++nt) {
            union { uint4 u4; bf16x8 v4; } bf;
            bf.u4 = *(const uint4*)&hbase[(size_t)(nt * 16 + cl) * HTM + m0];
            acc[nt] = __builtin_amdgcn_mfma_f32_16x16x32_bf16(af, bf.v4, acc[nt], 0, 0, 0);
        }
    }

#pragma unroll
    for (int nt = 0; nt < 4; ++nt)
#pragma unroll
        for (int r = 0; r < 4; ++r)
            s_s[strip + kg * 4 + r][nt * 16 + cl] = f2bf(acc[nt][r]);

    f32x4 g[4];
#pragma unroll
    for (int nt = 0; nt < 4; ++nt) g[nt] = (f32x4){0.f, 0.f, 0.f, 0.f};
#pragma unroll
    for (int kk = 0; kk < 2; ++kk) {
        union { uint4 u4; bf16x8 v; } sa;
        sa.u4 = *(const uint4*)&s_s[strip + cl][kk * 32 + kg * 8];
#pragma unroll
        for (int nt = 0; nt < 4; ++nt) {
            union { uint4 u4; bf16x8 v; } bf;
            bf.u4 = *(const uint4*)&s_gw[nt * 16 + cl][kk * 32 + kg * 8];
            g[nt] = __builtin_amdgcn_mfma_f32_16x16x32_bf16(sa.v, bf.v, g[nt], 0, 0, 0);
        }
    }

#pragma unroll
    for (int nt = 0; nt < 4; ++nt) {
        float bias = gcn_b[nt * 16 + cl];
#pragma unroll
        for (int r = 0; r < 4; ++r) {
            int n = n0 + strip + kg * 4 + r;
            if (n < NN) {
                float v = g[nt][r] + bias;
                v = (v > 0.f) ? v : 0.f;
                gcn_out[((size_t)(b * NN + n) * TT + t) * DD + nt * 16 + cl] = v;
            }
        }
    }
}

// ---------------- K3a (MFMA): Wp[u] = e_u-weighted sum of W.
// MFMA compute (C col = node, C rows = 4 consecutive i at fixed k), results staged in LDS
// (node stride 1032 u16 = 2064 B == 16 mod 128 -> 4-bank rotation/node, <=2-way store conflict),
// then fully-coalesced uint4 writeout in 128 B runs per (node, ks, L). Block covers
// k in [tr*8, tr*8+8) (nt = tr>>1 const, c1 = tr&1), all i.
__global__ __launch_bounds__(256) void k_wp(
    const float* __restrict__ node_emb, const float* __restrict__ tfeat,
    const unsigned short* __restrict__ wb, unsigned short* __restrict__ wp,
    int u0, int Uc) {
    int un0 = blockIdx.x * 16;
    int chunk = blockIdx.y;                 // 0..47
    int p = chunk >> 4, tr = chunk & 15;
    int tid = threadIdx.x, lane = tid & 63, wid = tid >> 6;

    __shared__ float s_e[16][MM];
    __shared__ __align__(16) unsigned short s_out[16 * 1032];   // ~33 KB

    {
        int nn = tid >> 4, m = tid & 15;    // 256 = 16*16 exactly
        int us = un0 + nn;
        float e = 0.f;
        if (us < Uc) {
            int u = u0 + us;
            int b = u / NN, n = u % NN;
            e = node_emb[n * MM + m] * tfeat[b * MM + m];
        }
        s_e[nn][m] = e;
    }
    __syncthreads();

    int node = lane & 15;
    int mb = (lane >> 4) * 8;
    bf16x8 ef = {0, 0, 0, 0, 0, 0, 0, 0};
    if (mb < MM) {
#pragma unroll
        for (int j = 0; j < 8; ++j) ef[j] = (short)f2bf(s_e[node][mb + j]);
    }
    const unsigned short* wsrc = wb + (size_t)p * 1024 * 512;

#pragma unroll 1
    for (int t16 = 0; t16 < 16; ++t16) {
        int T = tr * 64 + wid * 16 + t16;
        union { uint4 u4; bf16x8 v; } af;
        af.u4 = *(const uint4*)&wsrc[((size_t)T * 64 + lane) * 8];
        f32x4 acc = {0.f, 0.f, 0.f, 0.f};
        acc = __builtin_amdgcn_mfma_f32_16x16x32_bf16(af.v, ef, acc, 0, 0, 0);
        int k = T >> 3;
        int i0 = (T & 7) * 16 + (lane >> 4) * 4;
        int ksl = i0 >> 5, Ll = (i0 >> 3) & 3, jf0 = i0 & 7, kk = k & 7;
        int loc = node * 1032 + ((ksl * 4 + Ll) * 8 + kk) * 8 + jf0;
        uint2 pk;
        pk.x = packbf(acc[0], acc[1]);
        pk.y = packbf(acc[2], acc[3]);
        *(uint2*)&s_out[loc] = pk;
    }
    __syncthreads();

    // coalesced writeout: 2048 uint4, 8/thread; 8-lane groups write 128 B contiguous runs
    int nt = tr >> 1, c1 = tr & 1;
    size_t gbase = (size_t)p * 16384 + (size_t)nt * 2048 + (size_t)c1 * 64;
#pragma unroll
    for (int step = 0; step < 8; ++step) {
        int idx = step * 256 + tid;
        int nd = idx >> 7, rem = idx & 127;
        int ksw = rem >> 5, Lw = (rem >> 3) & 3, q = rem & 7;
        int us = un0 + nd;
        if (us < Uc) {
            uint4 v = *(const uint4*)&s_out[nd * 1032 + ((ksw * 4 + Lw) * 8 + q) * 8];
            *(uint4*)&wp[(size_t)us * 49152 + gbase + (size_t)ksw * 512 + Lw * 128 + q * 8] = v;
        }
    }
}

// ---------------- K3b: per node MFMA proj -> lrelu -> qkv bf16 to workspace.
__global__ __launch_bounds__(256) void k_proj(
    const float* __restrict__ hidden, const float* __restrict__ tXin,
    const unsigned short* __restrict__ wp, unsigned short* __restrict__ qkv,
    int u0) {
    int us = blockIdx.x;
    int u = u0 + us;
    int tid = threadIdx.x;
    int lane = tid & 63, wid = tid >> 6;
    int trow = lane & 15, kgrp = lane >> 4;

    size_t base = (size_t)u * TT * DD;

    bf16x8 afrag[2][4];
#pragma unroll
    for (int mt = 0; mt < 2; ++mt) {
        int t = mt * 16 + trow;
        bool valid = (t < TT);
#pragma unroll
        for (int ks = 0; ks < 4; ++ks) {
            int i0 = ks * 32 + kgrp * 8;
            float4 lo = make_float4(0.f, 0.f, 0.f, 0.f), hi = lo;
            if (valid) {
                const float* src = (i0 < DD) ? &hidden[base + t * DD + i0]
                                             : &tXin[base + t * DD + (i0 - DD)];
                lo = *(const float4*)src;
                hi = *(const float4*)(src + 4);
            }
            afrag[mt][ks] = pack_bf8(lo, hi);
        }
    }

    const unsigned short* wbase = wp + (size_t)us * 49152;
    unsigned short* qbase = qkv + (size_t)us * (3 * TT * E2);
    int rowg = kgrp * 4;
    int col0 = wid * 16 + trow;
    int col1 = (wid + 4) * 16 + trow;
#pragma unroll 1
    for (int p = 0; p < 3; ++p) {
        f32x4 acc00 = {0.f, 0.f, 0.f, 0.f}, acc01 = acc00, acc10 = acc00, acc11 = acc00;
#pragma unroll
        for (int ks = 0; ks < 4; ++ks) {
            union { uint4 u4; bf16x8 v; } c0, c1;
            c0.u4 = *(const uint4*)(wbase + (size_t)p * 16384 + (((wid) * 4 + ks) * 64 + lane) * 8);
            c1.u4 = *(const uint4*)(wbase + (size_t)p * 16384 + (((wid + 4) * 4 + ks) * 64 + lane) * 8);
            acc00 = __builtin_amdgcn_mfma_f32_16x16x32_bf16(afrag[0][ks], c0.v, acc00, 0, 0, 0);
            acc10 = __builtin_amdgcn_mfma_f32_16x16x32_bf16(afrag[1][ks], c0.v, acc10, 0, 0, 0);
            acc01 = __builtin_amdgcn_mfma_f32_16x16x32_bf16(afrag[0][ks], c1.v, acc01, 0, 0, 0);
            acc11 = __builtin_amdgcn_mfma_f32_16x16x32_bf16(afrag[1][ks], c1.v, acc11, 0, 0, 0);
        }
#pragma unroll
        for (int r = 0; r < 4; ++r) {
            int t = rowg + r;
            float v0 = acc00[r]; v0 = (v0 >= 0.f) ? v0 : NEG * v0;
            float v1 = acc01[r]; v1 = (v1 >= 0.f) ? v1 : NEG * v1;
            qbase[(p * TT + t) * E2 + col0] = f2bf(v0);
            qbase[(p * TT + t) * E2 + col1] = f2bf(v1);
        }
        if (rowg < 8) {
#pragma unroll
            for (int r = 0; r < 4; ++r) {
                int t = 16 + rowg + r;
                float v0 = acc10[r]; v0 = (v0 >= 0.f) ? v0 : NEG * v0;
                float v1 = acc11[r]; v1 = (v1 >= 0.f) ? v1 : NEG * v1;
                qbase[(p * TT + t) * E2 + col0] = f2bf(v0);
                qbase[(p * TT + t) * E2 + col1] = f2bf(v1);
            }
        }
    }
}

// ---------------- K3c: per node: attention (scalar C1/C2) + MFMA out-proj/gate + residual
#define QKS 66
#define QKP (TT * QKS)
#define SC_OFF 4752
#define VAL_OFF 7248
#define VQS 68
__global__ __launch_bounds__(256) void k_attn2(
    const unsigned* __restrict__ qkv, const float* __restrict__ hidden,
    const unsigned short* __restrict__ cw,
    const float* __restrict__ out_b, const float* __restrict__ gate_b,
    const float* __restrict__ gcn_out, float* __restrict__ out,
    int u0) {
    int us = blockIdx.x;
    int u = u0 + us;
    int tid = threadIdx.x;

    __shared__ __align__(16) unsigned arena[8880];
    __shared__ float s_gcn[TT][VQS];
    __shared__ float s_value[TT][VQS];

    size_t base = (size_t)u * TT * DD;

    const unsigned* src = qkv + (size_t)us * (3 * TT * 64);
    for (int idx = tid; idx < 3 * TT * 64; idx += 256) {
        int p = idx / (TT * 64);
        int r = idx % (TT * 64);
        int t = r >> 6, kp = r & 63;
        arena[p * QKP + t * QKS + kp] = src[idx];
    }
    for (int idx = tid; idx < TT * DD; idx += 256)
        s_gcn[idx >> 6][idx & 63] = gcn_out[base + idx];
    unsigned* s_qkv = arena;
    __syncthreads();

    // ---- phase C1: scores (scalar)
    unsigned* s_sc = arena + SC_OFF;
    if (tid < HH * TT) {
        int h = tid / TT, t = tid % TT;
        const float scale = 0.25f;
        float qf[16];
#pragma unroll
        for (int j = 0; j < 8; ++j) {
            unsigned uq = s_qkv[0 * QKP + t * QKS + 8 * h + j];
            qf[2 * j] = bflo(uq); qf[2 * j + 1] = bfhi(uq);
        }
#pragma unroll
        for (int s2 = 0; s2 < 12; ++s2) {
            int s0 = 2 * s2;
            float d0 = 0.f, d1 = 0.f;
#pragma unroll
            for (int j = 0; j < 8; ++j) {
                unsigned ka = s_qkv[1 * QKP + s0 * QKS + 8 * h + j];
                unsigned kb = s_qkv[1 * QKP + (s0 + 1) * QKS + 8 * h + j];
                d0 += qf[2 * j] * bflo(ka) + qf[2 * j + 1] * bfhi(ka);
                d1 += qf[2 * j] * bflo(kb) + qf[2 * j + 1] * bfhi(kb);
            }
            float w0 = (s0 <= t) ? __expf(d0 * scale) : 0.f;
            float w1 = (s0 + 1 <= t) ? __expf(d1 * scale) : 0.f;
            s_sc[(h * TT + t) * 13 + s2] = packbf(w0, w1);
        }
    }
    __syncthreads();

    // ---- phase C2: normalize + PV -> packed val[24][VQS]
    unsigned* s_val = arena + VAL_OFF;
#pragma unroll
    for (int it = 0; it < 3; ++it) {
        int item = tid + it * 256;
        int h = item / 96;
        int r = item % 96;
        int t = r >> 2, d4 = r & 3;
        int kg0 = 8 * h + 2 * d4;
        float sum = 0.f, v0 = 0.f, v1 = 0.f, v2 = 0.f, v3 = 0.f;
#pragma unroll
        for (int s2 = 0; s2 < 12; ++s2) {
            unsigned uw = s_sc[(h * TT + t) * 13 + s2];
            float w0 = bflo(uw), w1 = bfhi(uw);
            sum += w0 + w1;
            unsigned ua = s_qkv[2 * QKP + (2 * s2) * QKS + kg0];
            unsigned ub = s_qkv[2 * QKP + (2 * s2) * QKS + kg0 + 1];
            v0 += w0 * bflo(ua); v1 += w0 * bfhi(ua);
            v2 += w0 * bflo(ub); v3 += w0 * bfhi(ub);
            unsigned uc = s_qkv[2 * QKP + (2 * s2 + 1) * QKS + kg0];
            unsigned ud = s_qkv[2 * QKP + (2 * s2 + 1) * QKS + kg0 + 1];
            v0 += w1 * bflo(uc); v1 += w1 * bfhi(uc);
            v2 += w1 * bflo(ud); v3 += w1 * bfhi(ud);
        }
        float inv = 1.f / sum;
        s_val[t * VQS + kg0]     = packbf(v0 * inv, v1 * inv);
        s_val[t * VQS + kg0 + 1] = packbf(v2 * inv, v3 * inv);
    }
    __syncthreads();

    // ---- phase D (MFMA): value = lrelu(val @ out_w + out_b)
    int lane = tid & 63, wid = tid >> 6;
    int cl = lane & 15, kg = lane >> 4;
    {
        f32x4 d0 = {0.f, 0.f, 0.f, 0.f}, d1 = d0;
#pragma unroll
        for (int ks = 0; ks < 4; ++ks) {
            union { uint4 u4; bf16x8 v; } a0, a1, bw;
            a0.u4 = *(const uint4*)&s_val[cl * VQS + ks * 16 + kg * 4];
            if (cl < 8) a1.u4 = *(const uint4*)&s_val[(16 + cl) * VQS + ks * 16 + kg * 4];
            else a1.u4 = make_uint4(0, 0, 0, 0);
            bw.u4 = *(const uint4*)&cw[((size_t)(wid * 4 + ks) * 64 + lane) * 8];
            d0 = __builtin_amdgcn_mfma_f32_16x16x32_bf16(a0.v, bw.v, d0, 0, 0, 0);
            d1 = __builtin_amdgcn_mfma_f32_16x16x32_bf16(a1.v, bw.v, d1, 0, 0, 0);
        }
        int col = wid * 16 + cl;
        float bias = out_b[col];
#pragma unroll
        for (int r = 0; r < 4; ++r) {
            int t = kg * 4 + r;
            float v = d0[r] + bias; v = (v >= 0.f) ? v : NEG * v;
            s_value[t][col] = v;
        }
        if (kg < 2) {
#pragma unroll
            for (int r = 0; r < 4; ++r) {
                int t = 16 + kg * 4 + r;
                float v = d1[r] + bias; v = (v >= 0.f) ? v : NEG * v;
                s_value[t][col] = v;
            }
        }
    }
    __syncthreads();

    // ---- phase E (MFMA): z = sigmoid([gcn|value] @ gate_w + gate_b); out = z*g + (1-z)*v + hidden
    {
        f32x4 g0 = {0.f, 0.f, 0.f, 0.f}, g1 = g0;
#pragma unroll
        for (int ks = 0; ks < 4; ++ks) {
            int i0 = ks * 32 + kg * 8;
            const float* src0 = (i0 < DD) ? &s_gcn[cl][i0] : &s_value[cl][i0 - DD];
            float4 lo = *(const float4*)src0;
            float4 hi = *(const float4*)(src0 + 4);
            bf16x8 a0 = pack_bf8(lo, hi);
            bf16x8 a1 = {0, 0, 0, 0, 0, 0, 0, 0};
            if (cl < 8) {
                const float* src1 = (i0 < DD) ? &s_gcn[16 + cl][i0] : &s_value[16 + cl][i0 - DD];
                float4 lo1 = *(const float4*)src1;
                float4 hi1 = *(const float4*)(src1 + 4);
                a1 = pack_bf8(lo1, hi1);
            }
            union { uint4 u4; bf16x8 v; } bw;
            bw.u4 = *(const uint4*)&cw[8192 + ((size_t)(wid * 4 + ks) * 64 + lane) * 8];
            g0 = __builtin_amdgcn_mfma_f32_16x16x32_bf16(a0, bw.v, g0, 0, 0, 0);
            g1 = __builtin_amdgcn_mfma_f32_16x16x32_bf16(a1, bw.v, g1, 0, 0, 0);
        }
        int col = wid * 16 + cl;
        float gb = gate_b[col];
#pragma unroll
        for (int r = 0; r < 4; ++r) {
            int t = kg * 4 + r;
            float z = 1.f / (1.f + __expf(-(g0[r] + gb)));
            float gv = s_gcn[t][col], vv = s_value[t][col];
            size_t ob = base + (size_t)t * DD + col;
            out[ob] = z * gv + (1.f - z) * vv + hidden[ob];
        }
        if (kg < 2) {
#pragma unroll
            for (int r = 0; r < 4; ++r) {
                int t = 16 + kg * 4 + r;
                float z = 1.f / (1.f + __expf(-(g1[r] + gb)));
                float gv = s_gcn[t][col], vv = s_value[t][col];
                size_t ob = base + (size_t)t * DD + col;
                out[ob] = z * gv + (1.f - z) * vv + hidden[ob];
            }
        }
    }
}

extern "C" void kernel_launch(void* const* d_in, const int* in_sizes, int n_in,
                              void* d_out, int out_size, void* d_ws, size_t ws_size,
                              hipStream_t stream) {
    const float* hidden   = (const float*)d_in[0];
    const float* tXin     = (const float*)d_in[1];
    const float* matrix   = (const float*)d_in[2];
    const float* gcn_w    = (const float*)d_in[3];
    const float* gcn_b    = (const float*)d_in[4];
    const float* node_emb = (const float*)d_in[5];
    const float* tproj_w  = (const float*)d_in[6];
    const float* tproj_b  = (const float*)d_in[7];
    const float* WK_      = (const float*)d_in[8];   // dict order: WK, WQ, WV
    const float* WQ_      = (const float*)d_in[9];
    const float* WV_      = (const float*)d_in[10];
    const float* out_w    = (const float*)d_in[11];
    const float* out_b    = (const float*)d_in[12];
    const float* gate_w   = (const float*)d_in[13];
    const float* gate_b   = (const float*)d_in[14];
    float* out = (float*)d_out;

    char* ws = (char*)d_ws;
    float* tfeat   = (float*)ws;                         // 512 B
    float* gcn_out = (float*)(ws + 512);                 // 15,974,400 B
    size_t off_ht  = 512 + (size_t)BB * NN * TT * DD * 4;
    size_t ht_size = (size_t)BB * TT * DD * HTM * 2 + 4096;
    size_t off_cw  = off_ht + ht_size;
    size_t off_wb  = off_cw + 32768;
    size_t wb_size = (size_t)3 * 1024 * 64 * 8 * 2;      // 3,145,728 B
    size_t off_wp  = off_wb + wb_size;

    const size_t per_wp  = 3 * (size_t)E2 * E2 * 2;      // 98304 B per node (bf16)
    const size_t per_qkv = 3 * (size_t)TT * E2 * 2;      // 18432 B per node (bf16)
    long long avail = (long long)ws_size - (long long)off_wp;
    long long Ull = avail / (long long)(per_wp + per_qkv);
    int U = (Ull < 1) ? 1 : ((Ull > NNODE) ? NNODE : (int)Ull);

    unsigned short* ht_buf  = (unsigned short*)(ws + off_ht);
    unsigned short* cw_buf  = (unsigned short*)(ws + off_cw);
    unsigned short* wb_buf  = (unsigned short*)(ws + off_wb);
    unsigned short* wp_buf  = (unsigned short*)(ws + off_wp);
    unsigned short* qkv_buf = (unsigned short*)(ws + off_wp + (size_t)U * per_wp);

    k_tfeat<<<BB, DD, 0, stream>>>(tXin, tproj_w, tproj_b, tfeat);
    k_cw<<<1, 256, 0, stream>>>(out_w, gate_w, cw_buf);
    k_wconv<<<768, 256, 0, stream>>>(WQ_, WK_, WV_, wb_buf);
    k_ht<<<dim3(BB * TT, 6), 256, 0, stream>>>(hidden, ht_buf);
    k_gcn<<<dim3(BB * TT, 6), 256, 0, stream>>>(matrix, ht_buf, gcn_w, gcn_b, gcn_out);

    for (int u0 = 0; u0 < NNODE; u0 += U) {
        int Uc = (NNODE - u0 < U) ? (NNODE - u0) : U;
        k_wp<<<dim3((Uc + 15) / 16, 48), 256, 0, stream>>>(node_emb, tfeat, wb_buf,
                                                           wp_buf, u0, Uc);
        k_proj<<<Uc, 256, 0, stream>>>(hidden, tXin, wp_buf, qkv_buf, u0);
        k_attn2<<<Uc, 256, 0, stream>>>((const unsigned*)qkv_buf, hidden, cw_buf,
                                        out_b, gate_b, gcn_out, out, u0);
    }
}

// Round 17
// 287.412 us; speedup vs baseline: 1.4344x; 1.1322x over previous
//
#include <hip/hip_runtime.h>
#include <math.h>

#define BB 8
#define NN 325
#define TT 24
#define DD 64
#define HH 8
#define MM 16
#define E2 128
#define DK 16
#define NEG 0.1f
#define NNODE (BB * NN)          // 2600
#define HTM 328                  // padded m-extent of ht rows
#define UCAP 1312                // 2 passes; 129 MB wp chunk stays L3-resident, grids stay large

typedef short bf16x8 __attribute__((ext_vector_type(8)));
typedef float f32x4 __attribute__((ext_vector_type(4)));

__device__ __forceinline__ unsigned short f2bf(float f) {
    union { float f; unsigned u; } v; v.f = f;
    unsigned r = v.u + 0x7fffu + ((v.u >> 16) & 1u);   // RNE
    return (unsigned short)(r >> 16);
}
__device__ __forceinline__ unsigned packbf(float a, float b) {
    return (unsigned)f2bf(a) | ((unsigned)f2bf(b) << 16);
}
__device__ __forceinline__ float bflo(unsigned u) { return __uint_as_float(u << 16); }
__device__ __forceinline__ float bfhi(unsigned u) { return __uint_as_float(u & 0xffff0000u); }

__device__ __forceinline__ bf16x8 pack_bf8(float4 lo, float4 hi) {
    bf16x8 r;
    r[0] = (short)f2bf(lo.x); r[1] = (short)f2bf(lo.y);
    r[2] = (short)f2bf(lo.z); r[3] = (short)f2bf(lo.w);
    r[4] = (short)f2bf(hi.x); r[5] = (short)f2bf(hi.y);
    r[6] = (short)f2bf(hi.z); r[7] = (short)f2bf(hi.w);
    return r;
}

// ---------------- K1: tfeat[b][m] = tanh(mean_t(tXin[b,0,t,:]) @ tproj_w + tproj_b)
__global__ void k_tfeat(const float* __restrict__ tXin, const float* __restrict__ tproj_w,
                        const float* __restrict__ tproj_b, float* __restrict__ tfeat) {
    int b = blockIdx.x;
    int d = threadIdx.x;  // 64 threads
    __shared__ float mv[DD];
    float a = 0.f;
    for (int t = 0; t < TT; ++t)
        a += tXin[((size_t)(b * NN + 0) * TT + t) * DD + d];
    mv[d] = a * (1.f / (float)TT);
    __syncthreads();
    if (d < MM) {
        float acc = tproj_b[d];
        for (int j = 0; j < DD; ++j) acc += mv[j] * tproj_w[j * MM + d];
        tfeat[b * MM + d] = tanhf(acc);
    }
}

// ---------------- K_cw: out_w/gate_w -> bf16 B-fragment layout (once, 1 block)
__global__ __launch_bounds__(256) void k_cw(const float* __restrict__ out_w,
                                            const float* __restrict__ gate_w,
                                            unsigned short* __restrict__ cw) {
    int tid = threadIdx.x;
    for (int idx = tid; idx < 8192; idx += 256) {
        int i = idx >> 6, k = idx & 63;
        int nt = k >> 4, ks = i >> 5;
        int lane = (k & 15) | (((i >> 3) & 3) << 4);
        int off = (nt * 4 + ks) * 512 + lane * 8 + (i & 7);
        cw[off] = f2bf(out_w[i * 64 + k]);
        cw[8192 + off] = f2bf(gate_w[i * 64 + k]);
    }
}

// ---------------- K_wconv: W (fp32) -> bf16 A-fragment tensor over n = k*128 + i ordering.
__global__ __launch_bounds__(256) void k_wconv(const float* __restrict__ WQ,
                                               const float* __restrict__ WK,
                                               const float* __restrict__ WV,
                                               unsigned short* __restrict__ wb) {
    int idx = blockIdx.x * 256 + threadIdx.x;   // 3*1024*64 = 196608
    int lane = idx & 63;
    int pt = idx >> 6;
    int T = pt & 1023, p = pt >> 10;
    const float* __restrict__ W = (p == 0) ? WQ : ((p == 1) ? WK : WV);
    int n = T * 16 + (lane & 15);
    int i = n & 127, k = n >> 7;
    int mb = (lane >> 4) * 8;
    unsigned short v[8];
#pragma unroll
    for (int j = 0; j < 8; ++j) {
        int m = mb + j;
        v[j] = (m < MM) ? f2bf(W[(size_t)m * 16384 + i * 128 + k]) : (unsigned short)0;
    }
    *(uint4*)&wb[(size_t)idx * 8] = *(const uint4*)v;
}

// ---------------- K_ht: ht[bt][d][m] = bf16(hidden[b][m][t][d])  (transposed, padded to HTM)
__global__ __launch_bounds__(256) void k_ht(const float* __restrict__ hidden,
                                            unsigned short* __restrict__ ht) {
    int bt = blockIdx.x;          // b*TT + t
    int b = bt / TT, t = bt % TT;
    int m0 = blockIdx.y * 64;
    __shared__ float s[64][67];
    int tid = threadIdx.x;
#pragma unroll
    for (int i = 0; i < 4; ++i) {
        int idx = tid + i * 256;
        int mm = idx >> 4, q = idx & 15;
        int m = m0 + mm;
        float4 v = make_float4(0.f, 0.f, 0.f, 0.f);
        if (m < NN) v = *(const float4*)&hidden[((size_t)(b * NN + m) * TT + t) * DD + q * 4];
        s[mm][q * 4 + 0] = v.x; s[mm][q * 4 + 1] = v.y;
        s[mm][q * 4 + 2] = v.z; s[mm][q * 4 + 3] = v.w;
    }
    __syncthreads();
    size_t obase = (size_t)bt * DD * HTM;
    int jcap = HTM - m0;
#pragma unroll
    for (int i = 0; i < 16; ++i) {
        int idx = tid + i * 256;
        int d = idx >> 6, j = idx & 63;
        if (j < jcap) ht[obase + (size_t)d * HTM + m0 + j] = f2bf(s[j][d]);
    }
}

// ---------------- K2 (MFMA): S = matrix(b,t) @ H ; gcn_out = relu(S @ gcn_w + b)
__global__ __launch_bounds__(256) void k_gcn(const float* __restrict__ matrix,
                                             const unsigned short* __restrict__ ht,
                                             const float* __restrict__ gcn_w,
                                             const float* __restrict__ gcn_b,
                                             float* __restrict__ gcn_out) {
    int bt = blockIdx.x;
    int tile = blockIdx.y;
    int b = bt / TT, t = bt % TT;
    int n0 = tile * 64;
    int tid = threadIdx.x, lane = tid & 63, wid = tid >> 6;
    int cl = lane & 15, kg = lane >> 4;

    __shared__ unsigned short s_s[64][72];    // S bf16 [n][d]
    __shared__ unsigned short s_gw[64][72];   // gw^T bf16 [e][d]

#pragma unroll
    for (int i = 0; i < 4; ++i) {
        int idx = tid + i * 256;
        int d = idx >> 4, e0 = (idx & 15) * 4;
        float4 v = *(const float4*)&gcn_w[d * DD + e0];
        s_gw[e0 + 0][d] = f2bf(v.x); s_gw[e0 + 1][d] = f2bf(v.y);
        s_gw[e0 + 2][d] = f2bf(v.z); s_gw[e0 + 3][d] = f2bf(v.w);
    }
    __syncthreads();

    const float* mrow = matrix + (size_t)bt * NN * NN;
    const unsigned short* hbase = ht + (size_t)bt * DD * HTM;
    int strip = wid * 16;
    int arow = n0 + strip + cl;
    bool avalid = arow < NN;
    const float* arp = mrow + (size_t)arow * NN;

    f32x4 acc[4];
#pragma unroll
    for (int nt = 0; nt < 4; ++nt) acc[nt] = (f32x4){0.f, 0.f, 0.f, 0.f};

#pragma unroll 1
    for (int ch = 0; ch < 5; ++ch) {
#pragma unroll
        for (int kk = 0; kk < 2; ++kk) {
            int m0 = ch * 64 + kk * 32 + kg * 8;
            bf16x8 af = {0, 0, 0, 0, 0, 0, 0, 0};
            if (avalid) {
                float4 lo = *(const float4*)&arp[m0];      // vectorized (was 8 scalar loads)
                float4 hi = *(const float4*)&arp[m0 + 4];
                af = pack_bf8(lo, hi);
            }
#pragma unroll
            for (int nt = 0; nt < 4; ++nt) {
                union { uint4 u4; bf16x8 v; } bf;
                bf.u4 = *(const uint4*)&hbase[(size_t)(nt * 16 + cl) * HTM + m0];
                acc[nt] = __builtin_amdgcn_mfma_f32_16x16x32_bf16(af, bf.v, acc[nt], 0, 0, 0);
            }
        }
    }
    {
        int m0 = 320 + kg * 8;
        float v[8];
#pragma unroll
        for (int j = 0; j < 8; ++j)
            v[j] = (avalid && (m0 + j) < NN) ? arp[m0 + j] : 0.f;
        bf16x8 af = pack_bf8(make_float4(v[0], v[1], v[2], v[3]),
                             make_float4(v[4], v[5], v[6], v[7]));
#pragma unroll
        for (int nt = 0; nt < 4; ++nt) {
            union { uint4 u4; bf16x8 v4; } bf;
            bf.u4 = *(const uint4*)&hbase[(size_t)(nt * 16 + cl) * HTM + m0];
            acc[nt] = __builtin_amdgcn_mfma_f32_16x16x32_bf16(af, bf.v4, acc[nt], 0, 0, 0);
        }
    }

#pragma unroll
    for (int nt = 0; nt < 4; ++nt)
#pragma unroll
        for (int r = 0; r < 4; ++r)
            s_s[strip + kg * 4 + r][nt * 16 + cl] = f2bf(acc[nt][r]);

    f32x4 g[4];
#pragma unroll
    for (int nt = 0; nt < 4; ++nt) g[nt] = (f32x4){0.f, 0.f, 0.f, 0.f};
#pragma unroll
    for (int kk = 0; kk < 2; ++kk) {
        union { uint4 u4; bf16x8 v; } sa;
        sa.u4 = *(const uint4*)&s_s[strip + cl][kk * 32 + kg * 8];
#pragma unroll
        for (int nt = 0; nt < 4; ++nt) {
            union { uint4 u4; bf16x8 v; } bf;
            bf.u4 = *(const uint4*)&s_gw[nt * 16 + cl][kk * 32 + kg * 8];
            g[nt] = __builtin_amdgcn_mfma_f32_16x16x32_bf16(sa.v, bf.v, g[nt], 0, 0, 0);
        }
    }

#pragma unroll
    for (int nt = 0; nt < 4; ++nt) {
        float bias = gcn_b[nt * 16 + cl];
#pragma unroll
        for (int r = 0; r < 4; ++r) {
            int n = n0 + strip + kg * 4 + r;
            if (n < NN) {
                float v = g[nt][r] + bias;
                v = (v > 0.f) ? v : 0.f;
                gcn_out[((size_t)(b * NN + n) * TT + t) * DD + nt * 16 + cl] = v;
            }
        }
    }
}

// ---------------- K3a (MFMA): Wp[u] = e_u-weighted sum of W; LDS-staged coalesced writeout.
__global__ __launch_bounds__(256) void k_wp(
    const float* __restrict__ node_emb, const float* __restrict__ tfeat,
    const unsigned short* __restrict__ wb, unsigned short* __restrict__ wp,
    int u0, int Uc) {
    int un0 = blockIdx.x * 16;
    int chunk = blockIdx.y;                 // 0..47
    int p = chunk >> 4, tr = chunk & 15;
    int tid = threadIdx.x, lane = tid & 63, wid = tid >> 6;

    __shared__ float s_e[16][MM];
    __shared__ __align__(16) unsigned short s_out[16 * 1032];   // ~33 KB

    {
        int nn = tid >> 4, m = tid & 15;    // 256 = 16*16 exactly
        int us = un0 + nn;
        float e = 0.f;
        if (us < Uc) {
            int u = u0 + us;
            int b = u / NN, n = u % NN;
            e = node_emb[n * MM + m] * tfeat[b * MM + m];
        }
        s_e[nn][m] = e;
    }
    __syncthreads();

    int node = lane & 15;
    int mb = (lane >> 4) * 8;
    bf16x8 ef = {0, 0, 0, 0, 0, 0, 0, 0};
    if (mb < MM) {
#pragma unroll
        for (int j = 0; j < 8; ++j) ef[j] = (short)f2bf(s_e[node][mb + j]);
    }
    const unsigned short* wsrc = wb + (size_t)p * 1024 * 512;

#pragma unroll 1
    for (int t16 = 0; t16 < 16; ++t16) {
        int T = tr * 64 + wid * 16 + t16;
        union { uint4 u4; bf16x8 v; } af;
        af.u4 = *(const uint4*)&wsrc[((size_t)T * 64 + lane) * 8];
        f32x4 acc = {0.f, 0.f, 0.f, 0.f};
        acc = __builtin_amdgcn_mfma_f32_16x16x32_bf16(af.v, ef, acc, 0, 0, 0);
        int k = T >> 3;
        int i0 = (T & 7) * 16 + (lane >> 4) * 4;
        int ksl = i0 >> 5, Ll = (i0 >> 3) & 3, jf0 = i0 & 7, kk = k & 7;
        int loc = node * 1032 + ((ksl * 4 + Ll) * 8 + kk) * 8 + jf0;
        uint2 pk;
        pk.x = packbf(acc[0], acc[1]);
        pk.y = packbf(acc[2], acc[3]);
        *(uint2*)&s_out[loc] = pk;
    }
    __syncthreads();

    // coalesced writeout: 2048 uint4, 8/thread; 8-lane groups write 128 B contiguous runs
    int nt = tr >> 1, c1 = tr & 1;
    size_t gbase = (size_t)p * 16384 + (size_t)nt * 2048 + (size_t)c1 * 64;
#pragma unroll
    for (int step = 0; step < 8; ++step) {
        int idx = step * 256 + tid;
        int nd = idx >> 7, rem = idx & 127;
        int ksw = rem >> 5, Lw = (rem >> 3) & 3, q = rem & 7;
        int us = un0 + nd;
        if (us < Uc) {
            uint4 v = *(const uint4*)&s_out[nd * 1032 + ((ksw * 4 + Lw) * 8 + q) * 8];
            *(uint4*)&wp[(size_t)us * 49152 + gbase + (size_t)ksw * 512 + Lw * 128 + q * 8] = v;
        }
    }
}

// ---------------- K3b: per node MFMA proj -> lrelu -> qkv bf16 to workspace.
__global__ __launch_bounds__(256) void k_proj(
    const float* __restrict__ hidden, const float* __restrict__ tXin,
    const unsigned short* __restrict__ wp, unsigned short* __restrict__ qkv,
    int u0) {
    int us = blockIdx.x;
    int u = u0 + us;
    int tid = threadIdx.x;
    int lane = tid & 63, wid = tid >> 6;
    int trow = lane & 15, kgrp = lane >> 4;

    size_t base = (size_t)u * TT * DD;

    bf16x8 afrag[2][4];
#pragma unroll
    for (int mt = 0; mt < 2; ++mt) {
        int t = mt * 16 + trow;
        bool valid = (t < TT);
#pragma unroll
        for (int ks = 0; ks < 4; ++ks) {
            int i0 = ks * 32 + kgrp * 8;
            float4 lo = make_float4(0.f, 0.f, 0.f, 0.f), hi = lo;
            if (valid) {
                const float* src = (i0 < DD) ? &hidden[base + t * DD + i0]
                                             : &tXin[base + t * DD + (i0 - DD)];
                lo = *(const float4*)src;
                hi = *(const float4*)(src + 4);
            }
            afrag[mt][ks] = pack_bf8(lo, hi);
        }
    }

    const unsigned short* wbase = wp + (size_t)us * 49152;
    unsigned short* qbase = qkv + (size_t)us * (3 * TT * E2);
    int rowg = kgrp * 4;
    int col0 = wid * 16 + trow;
    int col1 = (wid + 4) * 16 + trow;
#pragma unroll 1
    for (int p = 0; p < 3; ++p) {
        f32x4 acc00 = {0.f, 0.f, 0.f, 0.f}, acc01 = acc00, acc10 = acc00, acc11 = acc00;
#pragma unroll
        for (int ks = 0; ks < 4; ++ks) {
            union { uint4 u4; bf16x8 v; } c0, c1;
            c0.u4 = *(const uint4*)(wbase + (size_t)p * 16384 + (((wid) * 4 + ks) * 64 + lane) * 8);
            c1.u4 = *(const uint4*)(wbase + (size_t)p * 16384 + (((wid + 4) * 4 + ks) * 64 + lane) * 8);
            acc00 = __builtin_amdgcn_mfma_f32_16x16x32_bf16(afrag[0][ks], c0.v, acc00, 0, 0, 0);
            acc10 = __builtin_amdgcn_mfma_f32_16x16x32_bf16(afrag[1][ks], c0.v, acc10, 0, 0, 0);
            acc01 = __builtin_amdgcn_mfma_f32_16x16x32_bf16(afrag[0][ks], c1.v, acc01, 0, 0, 0);
            acc11 = __builtin_amdgcn_mfma_f32_16x16x32_bf16(afrag[1][ks], c1.v, acc11, 0, 0, 0);
        }
#pragma unroll
        for (int r = 0; r < 4; ++r) {
            int t = rowg + r;
            float v0 = acc00[r]; v0 = (v0 >= 0.f) ? v0 : NEG * v0;
            float v1 = acc01[r]; v1 = (v1 >= 0.f) ? v1 : NEG * v1;
            qbase[(p * TT + t) * E2 + col0] = f2bf(v0);
            qbase[(p * TT + t) * E2 + col1] = f2bf(v1);
        }
        if (rowg < 8) {
#pragma unroll
            for (int r = 0; r < 4; ++r) {
                int t = 16 + rowg + r;
                float v0 = acc10[r]; v0 = (v0 >= 0.f) ? v0 : NEG * v0;
                float v1 = acc11[r]; v1 = (v1 >= 0.f) ? v1 : NEG * v1;
                qbase[(p * TT + t) * E2 + col0] = f2bf(v0);
                qbase[(p * TT + t) * E2 + col1] = f2bf(v1);
            }
        }
    }
}

// ---------------- K3c: per node: attention (scalar C1/C2) + MFMA out-proj/gate + residual
#define QKS 66
#define QKP (TT * QKS)
#define SC_OFF 4752
#define VAL_OFF 7248
#define VQS 68
__global__ __launch_bounds__(256) void k_attn2(
    const unsigned* __restrict__ qkv, const float* __restrict__ hidden,
    const unsigned short* __restrict__ cw,
    const float* __restrict__ out_b, const float* __restrict__ gate_b,
    const float* __restrict__ gcn_out, float* __restrict__ out,
    int u0) {
    int us = blockIdx.x;
    int u = u0 + us;
    int tid = threadIdx.x;

    __shared__ __align__(16) unsigned arena[8880];
    __shared__ float s_gcn[TT][VQS];
    __shared__ float s_value[TT][VQS];

    size_t base = (size_t)u * TT * DD;

    const unsigned* src = qkv + (size_t)us * (3 * TT * 64);
    for (int idx = tid; idx < 3 * TT * 64; idx += 256) {
        int p = idx / (TT * 64);
        int r = idx % (TT * 64);
        int t = r >> 6, kp = r & 63;
        arena[p * QKP + t * QKS + kp] = src[idx];
    }
    for (int idx = tid; idx < TT * DD; idx += 256)
        s_gcn[idx >> 6][idx & 63] = gcn_out[base + idx];
    unsigned* s_qkv = arena;
    __syncthreads();

    // ---- phase C1: scores (scalar)
    unsigned* s_sc = arena + SC_OFF;
    if (tid < HH * TT) {
        int h = tid / TT, t = tid % TT;
        const float scale = 0.25f;
        float qf[16];
#pragma unroll
        for (int j = 0; j < 8; ++j) {
            unsigned uq = s_qkv[0 * QKP + t * QKS + 8 * h + j];
            qf[2 * j] = bflo(uq); qf[2 * j + 1] = bfhi(uq);
        }
#pragma unroll
        for (int s2 = 0; s2 < 12; ++s2) {
            int s0 = 2 * s2;
            float d0 = 0.f, d1 = 0.f;
#pragma unroll
            for (int j = 0; j < 8; ++j) {
                unsigned ka = s_qkv[1 * QKP + s0 * QKS + 8 * h + j];
                unsigned kb = s_qkv[1 * QKP + (s0 + 1) * QKS + 8 * h + j];
                d0 += qf[2 * j] * bflo(ka) + qf[2 * j + 1] * bfhi(ka);
                d1 += qf[2 * j] * bflo(kb) + qf[2 * j + 1] * bfhi(kb);
            }
            float w0 = (s0 <= t) ? __expf(d0 * scale) : 0.f;
            float w1 = (s0 + 1 <= t) ? __expf(d1 * scale) : 0.f;
            s_sc[(h * TT + t) * 13 + s2] = packbf(w0, w1);
        }
    }
    __syncthreads();

    // ---- phase C2: normalize + PV -> packed val[24][VQS]
    unsigned* s_val = arena + VAL_OFF;
#pragma unroll
    for (int it = 0; it < 3; ++it) {
        int item = tid + it * 256;
        int h = item / 96;
        int r = item % 96;
        int t = r >> 2, d4 = r & 3;
        int kg0 = 8 * h + 2 * d4;
        float sum = 0.f, v0 = 0.f, v1 = 0.f, v2 = 0.f, v3 = 0.f;
#pragma unroll
        for (int s2 = 0; s2 < 12; ++s2) {
            unsigned uw = s_sc[(h * TT + t) * 13 + s2];
            float w0 = bflo(uw), w1 = bfhi(uw);
            sum += w0 + w1;
            unsigned ua = s_qkv[2 * QKP + (2 * s2) * QKS + kg0];
            unsigned ub = s_qkv[2 * QKP + (2 * s2) * QKS + kg0 + 1];
            v0 += w0 * bflo(ua); v1 += w0 * bfhi(ua);
            v2 += w0 * bflo(ub); v3 += w0 * bfhi(ub);
            unsigned uc = s_qkv[2 * QKP + (2 * s2 + 1) * QKS + kg0];
            unsigned ud = s_qkv[2 * QKP + (2 * s2 + 1) * QKS + kg0 + 1];
            v0 += w1 * bflo(uc); v1 += w1 * bfhi(uc);
            v2 += w1 * bflo(ud); v3 += w1 * bfhi(ud);
        }
        float inv = 1.f / sum;
        s_val[t * VQS + kg0]     = packbf(v0 * inv, v1 * inv);
        s_val[t * VQS + kg0 + 1] = packbf(v2 * inv, v3 * inv);
    }
    __syncthreads();

    // ---- phase D (MFMA): value = lrelu(val @ out_w + out_b)
    int lane = tid & 63, wid = tid >> 6;
    int cl = lane & 15, kg = lane >> 4;
    {
        f32x4 d0 = {0.f, 0.f, 0.f, 0.f}, d1 = d0;
#pragma unroll
        for (int ks = 0; ks < 4; ++ks) {
            union { uint4 u4; bf16x8 v; } a0, a1, bw;
            a0.u4 = *(const uint4*)&s_val[cl * VQS + ks * 16 + kg * 4];
            if (cl < 8) a1.u4 = *(const uint4*)&s_val[(16 + cl) * VQS + ks * 16 + kg * 4];
            else a1.u4 = make_uint4(0, 0, 0, 0);
            bw.u4 = *(const uint4*)&cw[((size_t)(wid * 4 + ks) * 64 + lane) * 8];
            d0 = __builtin_amdgcn_mfma_f32_16x16x32_bf16(a0.v, bw.v, d0, 0, 0, 0);
            d1 = __builtin_amdgcn_mfma_f32_16x16x32_bf16(a1.v, bw.v, d1, 0, 0, 0);
        }
        int col = wid * 16 + cl;
        float bias = out_b[col];
#pragma unroll
        for (int r = 0; r < 4; ++r) {
            int t = kg * 4 + r;
            float v = d0[r] + bias; v = (v >= 0.f) ? v : NEG * v;
            s_value[t][col] = v;
        }
        if (kg < 2) {
#pragma unroll
            for (int r = 0; r < 4; ++r) {
                int t = 16 + kg * 4 + r;
                float v = d1[r] + bias; v = (v >= 0.f) ? v : NEG * v;
                s_value[t][col] = v;
            }
        }
    }
    __syncthreads();

    // ---- phase E (MFMA): z = sigmoid([gcn|value] @ gate_w + gate_b); out = z*g + (1-z)*v + hidden
    {
        f32x4 g0 = {0.f, 0.f, 0.f, 0.f}, g1 = g0;
#pragma unroll
        for (int ks = 0; ks < 4; ++ks) {
            int i0 = ks * 32 + kg * 8;
            const float* src0 = (i0 < DD) ? &s_gcn[cl][i0] : &s_value[cl][i0 - DD];
            float4 lo = *(const float4*)src0;
            float4 hi = *(const float4*)(src0 + 4);
            bf16x8 a0 = pack_bf8(lo, hi);
            bf16x8 a1 = {0, 0, 0, 0, 0, 0, 0, 0};
            if (cl < 8) {
                const float* src1 = (i0 < DD) ? &s_gcn[16 + cl][i0] : &s_value[16 + cl][i0 - DD];
                float4 lo1 = *(const float4*)src1;
                float4 hi1 = *(const float4*)(src1 + 4);
                a1 = pack_bf8(lo1, hi1);
            }
            union { uint4 u4; bf16x8 v; } bw;
            bw.u4 = *(const uint4*)&cw[8192 + ((size_t)(wid * 4 + ks) * 64 + lane) * 8];
            g0 = __builtin_amdgcn_mfma_f32_16x16x32_bf16(a0, bw.v, g0, 0, 0, 0);
            g1 = __builtin_amdgcn_mfma_f32_16x16x32_bf16(a1, bw.v, g1, 0, 0, 0);
        }
        int col = wid * 16 + cl;
        float gb = gate_b[col];
#pragma unroll
        for (int r = 0; r < 4; ++r) {
            int t = kg * 4 + r;
            float z = 1.f / (1.f + __expf(-(g0[r] + gb)));
            float gv = s_gcn[t][col], vv = s_value[t][col];
            size_t ob = base + (size_t)t * DD + col;
            out[ob] = z * gv + (1.f - z) * vv + hidden[ob];
        }
        if (kg < 2) {
#pragma unroll
            for (int r = 0; r < 4; ++r) {
                int t = 16 + kg * 4 + r;
                float z = 1.f / (1.f + __expf(-(g1[r] + gb)));
                float gv = s_gcn[t][col], vv = s_value[t][col];
                size_t ob = base + (size_t)t * DD + col;
                out[ob] = z * gv + (1.f - z) * vv + hidden[ob];
            }
        }
    }
}

extern "C" void kernel_launch(void* const* d_in, const int* in_sizes, int n_in,
                              void* d_out, int out_size, void* d_ws, size_t ws_size,
                              hipStream_t stream) {
    const float* hidden   = (const float*)d_in[0];
    const float* tXin     = (const float*)d_in[1];
    const float* matrix   = (const float*)d_in[2];
    const float* gcn_w    = (const float*)d_in[3];
    const float* gcn_b    = (const float*)d_in[4];
    const float* node_emb = (const float*)d_in[5];
    const float* tproj_w  = (const float*)d_in[6];
    const float* tproj_b  = (const float*)d_in[7];
    const float* WK_      = (const float*)d_in[8];   // dict order: WK, WQ, WV
    const float* WQ_      = (const float*)d_in[9];
    const float* WV_      = (const float*)d_in[10];
    const float* out_w    = (const float*)d_in[11];
    const float* out_b    = (const float*)d_in[12];
    const float* gate_w   = (const float*)d_in[13];
    const float* gate_b   = (const float*)d_in[14];
    float* out = (float*)d_out;

    char* ws = (char*)d_ws;
    float* tfeat   = (float*)ws;                         // 512 B
    float* gcn_out = (float*)(ws + 512);                 // 15,974,400 B
    size_t off_ht  = 512 + (size_t)BB * NN * TT * DD * 4;
    size_t ht_size = (size_t)BB * TT * DD * HTM * 2 + 4096;
    size_t off_cw  = off_ht + ht_size;
    size_t off_wb  = off_cw + 32768;
    size_t wb_size = (size_t)3 * 1024 * 64 * 8 * 2;      // 3,145,728 B
    size_t off_wp  = off_wb + wb_size;

    const size_t per_wp  = 3 * (size_t)E2 * E2 * 2;      // 98304 B per node (bf16)
    const size_t per_qkv = 3 * (size_t)TT * E2 * 2;      // 18432 B per node (bf16)
    long long avail = (long long)ws_size - (long long)off_wp;
    long long Ull = avail / (long long)(per_wp + per_qkv);
    int U = (Ull < 1) ? 1 : ((Ull > NNODE) ? NNODE : (int)Ull);
    if (U > UCAP) U = UCAP;   // 2 passes, 129 MB wp chunk (L3-resident); grids stay >=1300 blocks

    unsigned short* ht_buf  = (unsigned short*)(ws + off_ht);
    unsigned short* cw_buf  = (unsigned short*)(ws + off_cw);
    unsigned short* wb_buf  = (unsigned short*)(ws + off_wb);
    unsigned short* wp_buf  = (unsigned short*)(ws + off_wp);
    unsigned short* qkv_buf = (unsigned short*)(ws + off_wp + (size_t)U * per_wp);

    k_tfeat<<<BB, DD, 0, stream>>>(tXin, tproj_w, tproj_b, tfeat);
    k_cw<<<1, 256, 0, stream>>>(out_w, gate_w, cw_buf);
    k_wconv<<<768, 256, 0, stream>>>(WQ_, WK_, WV_, wb_buf);
    k_ht<<<dim3(BB * TT, 6), 256, 0, stream>>>(hidden, ht_buf);
    k_gcn<<<dim3(BB * TT, 6), 256, 0, stream>>>(matrix, ht_buf, gcn_w, gcn_b, gcn_out);

    for (int u0 = 0; u0 < NNODE; u0 += U) {
        int Uc = (NNODE - u0 < U) ? (NNODE - u0) : U;
        k_wp<<<dim3((Uc + 15) / 16, 48), 256, 0, stream>>>(node_emb, tfeat, wb_buf,
                                                           wp_buf, u0, Uc);
        k_proj<<<Uc, 256, 0, stream>>>(hidden, tXin, wp_buf, qkv_buf, u0);
        k_attn2<<<Uc, 256, 0, stream>>>((const unsigned*)qkv_buf, hidden, cw_buf,
                                        out_b, gate_b, gcn_out, out, u0);
    }
}

// Round 18
// 286.308 us; speedup vs baseline: 1.4400x; 1.0039x over previous
//
#include <hip/hip_runtime.h>
#include <math.h>

#define BB 8
#define NN 325
#define TT 24
#define DD 64
#define HH 8
#define MM 16
#define E2 128
#define DK 16
#define NEG 0.1f
#define NNODE (BB * NN)          // 2600
#define HTM 328                  // padded m-extent of ht rows
#define UCAP 1312                // 2 passes; 129 MB wp chunk stays L3-resident, grids stay large

typedef short bf16x8 __attribute__((ext_vector_type(8)));
typedef float f32x4 __attribute__((ext_vector_type(4)));

__device__ __forceinline__ unsigned short f2bf(float f) {
    union { float f; unsigned u; } v; v.f = f;
    unsigned r = v.u + 0x7fffu + ((v.u >> 16) & 1u);   // RNE
    return (unsigned short)(r >> 16);
}
__device__ __forceinline__ unsigned packbf(float a, float b) {
    return (unsigned)f2bf(a) | ((unsigned)f2bf(b) << 16);
}
__device__ __forceinline__ float bflo(unsigned u) { return __uint_as_float(u << 16); }
__device__ __forceinline__ float bfhi(unsigned u) { return __uint_as_float(u & 0xffff0000u); }

__device__ __forceinline__ bf16x8 pack_bf8(float4 lo, float4 hi) {
    bf16x8 r;
    r[0] = (short)f2bf(lo.x); r[1] = (short)f2bf(lo.y);
    r[2] = (short)f2bf(lo.z); r[3] = (short)f2bf(lo.w);
    r[4] = (short)f2bf(hi.x); r[5] = (short)f2bf(hi.y);
    r[6] = (short)f2bf(hi.z); r[7] = (short)f2bf(hi.w);
    return r;
}

// ---------------- K1: tfeat[b][m] = tanh(mean_t(tXin[b,0,t,:]) @ tproj_w + tproj_b)
__global__ void k_tfeat(const float* __restrict__ tXin, const float* __restrict__ tproj_w,
                        const float* __restrict__ tproj_b, float* __restrict__ tfeat) {
    int b = blockIdx.x;
    int d = threadIdx.x;  // 64 threads
    __shared__ float mv[DD];
    float a = 0.f;
    for (int t = 0; t < TT; ++t)
        a += tXin[((size_t)(b * NN + 0) * TT + t) * DD + d];
    mv[d] = a * (1.f / (float)TT);
    __syncthreads();
    if (d < MM) {
        float acc = tproj_b[d];
        for (int j = 0; j < DD; ++j) acc += mv[j] * tproj_w[j * MM + d];
        tfeat[b * MM + d] = tanhf(acc);
    }
}

// ---------------- K_cw: out_w/gate_w -> bf16 B-fragment layout (once, 1 block)
__global__ __launch_bounds__(256) void k_cw(const float* __restrict__ out_w,
                                            const float* __restrict__ gate_w,
                                            unsigned short* __restrict__ cw) {
    int tid = threadIdx.x;
    for (int idx = tid; idx < 8192; idx += 256) {
        int i = idx >> 6, k = idx & 63;
        int nt = k >> 4, ks = i >> 5;
        int lane = (k & 15) | (((i >> 3) & 3) << 4);
        int off = (nt * 4 + ks) * 512 + lane * 8 + (i & 7);
        cw[off] = f2bf(out_w[i * 64 + k]);
        cw[8192 + off] = f2bf(gate_w[i * 64 + k]);
    }
}

// ---------------- K_wconv: W (fp32) -> bf16 A-fragment tensor over n = k*128 + i ordering.
__global__ __launch_bounds__(256) void k_wconv(const float* __restrict__ WQ,
                                               const float* __restrict__ WK,
                                               const float* __restrict__ WV,
                                               unsigned short* __restrict__ wb) {
    int idx = blockIdx.x * 256 + threadIdx.x;   // 3*1024*64 = 196608
    int lane = idx & 63;
    int pt = idx >> 6;
    int T = pt & 1023, p = pt >> 10;
    const float* __restrict__ W = (p == 0) ? WQ : ((p == 1) ? WK : WV);
    int n = T * 16 + (lane & 15);
    int i = n & 127, k = n >> 7;
    int mb = (lane >> 4) * 8;
    unsigned short v[8];
#pragma unroll
    for (int j = 0; j < 8; ++j) {
        int m = mb + j;
        v[j] = (m < MM) ? f2bf(W[(size_t)m * 16384 + i * 128 + k]) : (unsigned short)0;
    }
    *(uint4*)&wb[(size_t)idx * 8] = *(const uint4*)v;
}

// ---------------- K_ht: ht[bt][d][m] = bf16(hidden[b][m][t][d])  (transposed, padded to HTM)
__global__ __launch_bounds__(256) void k_ht(const float* __restrict__ hidden,
                                            unsigned short* __restrict__ ht) {
    int bt = blockIdx.x;          // b*TT + t
    int b = bt / TT, t = bt % TT;
    int m0 = blockIdx.y * 64;
    __shared__ float s[64][67];
    int tid = threadIdx.x;
#pragma unroll
    for (int i = 0; i < 4; ++i) {
        int idx = tid + i * 256;
        int mm = idx >> 4, q = idx & 15;
        int m = m0 + mm;
        float4 v = make_float4(0.f, 0.f, 0.f, 0.f);
        if (m < NN) v = *(const float4*)&hidden[((size_t)(b * NN + m) * TT + t) * DD + q * 4];
        s[mm][q * 4 + 0] = v.x; s[mm][q * 4 + 1] = v.y;
        s[mm][q * 4 + 2] = v.z; s[mm][q * 4 + 3] = v.w;
    }
    __syncthreads();
    size_t obase = (size_t)bt * DD * HTM;
    int jcap = HTM - m0;
#pragma unroll
    for (int i = 0; i < 16; ++i) {
        int idx = tid + i * 256;
        int d = idx >> 6, j = idx & 63;
        if (j < jcap) ht[obase + (size_t)d * HTM + m0 + j] = f2bf(s[j][d]);
    }
}

// ---------------- K2 (MFMA): S = matrix(b,t) @ H ; gcn_out = relu(S @ gcn_w + b)
// K-loop FULLY UNROLLED (R17 was latency-bound at unroll 1: VALU 8%, MFMA 2%, HBM 13%
// all idle -> serialize 11 load->MFMA chains; unroll puts all loads in one latency window).
__global__ __launch_bounds__(256) void k_gcn(const float* __restrict__ matrix,
                                             const unsigned short* __restrict__ ht,
                                             const float* __restrict__ gcn_w,
                                             const float* __restrict__ gcn_b,
                                             float* __restrict__ gcn_out) {
    int bt = blockIdx.x;
    int tile = blockIdx.y;
    int b = bt / TT, t = bt % TT;
    int n0 = tile * 64;
    int tid = threadIdx.x, lane = tid & 63, wid = tid >> 6;
    int cl = lane & 15, kg = lane >> 4;

    __shared__ unsigned short s_s[64][72];    // S bf16 [n][d]
    __shared__ unsigned short s_gw[64][72];   // gw^T bf16 [e][d]

#pragma unroll
    for (int i = 0; i < 4; ++i) {
        int idx = tid + i * 256;
        int d = idx >> 4, e0 = (idx & 15) * 4;
        float4 v = *(const float4*)&gcn_w[d * DD + e0];
        s_gw[e0 + 0][d] = f2bf(v.x); s_gw[e0 + 1][d] = f2bf(v.y);
        s_gw[e0 + 2][d] = f2bf(v.z); s_gw[e0 + 3][d] = f2bf(v.w);
    }
    __syncthreads();

    const float* mrow = matrix + (size_t)bt * NN * NN;
    const unsigned short* hbase = ht + (size_t)bt * DD * HTM;
    int strip = wid * 16;
    int arow = n0 + strip + cl;
    bool avalid = arow < NN;
    const float* arp = mrow + (size_t)arow * NN;

    f32x4 acc[4];
#pragma unroll
    for (int nt = 0; nt < 4; ++nt) acc[nt] = (f32x4){0.f, 0.f, 0.f, 0.f};

#pragma unroll
    for (int ch = 0; ch < 5; ++ch) {
#pragma unroll
        for (int kk = 0; kk < 2; ++kk) {
            int m0 = ch * 64 + kk * 32 + kg * 8;
            bf16x8 af = {0, 0, 0, 0, 0, 0, 0, 0};
            if (avalid) {
                float4 lo = *(const float4*)&arp[m0];
                float4 hi = *(const float4*)&arp[m0 + 4];
                af = pack_bf8(lo, hi);
            }
#pragma unroll
            for (int nt = 0; nt < 4; ++nt) {
                union { uint4 u4; bf16x8 v; } bf;
                bf.u4 = *(const uint4*)&hbase[(size_t)(nt * 16 + cl) * HTM + m0];
                acc[nt] = __builtin_amdgcn_mfma_f32_16x16x32_bf16(af, bf.v, acc[nt], 0, 0, 0);
            }
        }
    }
    {
        int m0 = 320 + kg * 8;
        float v[8];
#pragma unroll
        for (int j = 0; j < 8; ++j)
            v[j] = (avalid && (m0 + j) < NN) ? arp[m0 + j] : 0.f;
        bf16x8 af = pack_bf8(make_float4(v[0], v[1], v[2], v[3]),
                             make_float4(v[4], v[5], v[6], v[7]));
#pragma unroll
        for (int nt = 0; nt < 4; ++nt) {
            union { uint4 u4; bf16x8 v4; } bf;
            bf.u4 = *(const uint4*)&hbase[(size_t)(nt * 16 + cl) * HTM + m0];
            acc[nt] = __builtin_amdgcn_mfma_f32_16x16x32_bf16(af, bf.v4, acc[nt], 0, 0, 0);
        }
    }

#pragma unroll
    for (int nt = 0; nt < 4; ++nt)
#pragma unroll
        for (int r = 0; r < 4; ++r)
            s_s[strip + kg * 4 + r][nt * 16 + cl] = f2bf(acc[nt][r]);

    f32x4 g[4];
#pragma unroll
    for (int nt = 0; nt < 4; ++nt) g[nt] = (f32x4){0.f, 0.f, 0.f, 0.f};
#pragma unroll
    for (int kk = 0; kk < 2; ++kk) {
        union { uint4 u4; bf16x8 v; } sa;
        sa.u4 = *(const uint4*)&s_s[strip + cl][kk * 32 + kg * 8];
#pragma unroll
        for (int nt = 0; nt < 4; ++nt) {
            union { uint4 u4; bf16x8 v; } bf;
            bf.u4 = *(const uint4*)&s_gw[nt * 16 + cl][kk * 32 + kg * 8];
            g[nt] = __builtin_amdgcn_mfma_f32_16x16x32_bf16(sa.v, bf.v, g[nt], 0, 0, 0);
        }
    }

#pragma unroll
    for (int nt = 0; nt < 4; ++nt) {
        float bias = gcn_b[nt * 16 + cl];
#pragma unroll
        for (int r = 0; r < 4; ++r) {
            int n = n0 + strip + kg * 4 + r;
            if (n < NN) {
                float v = g[nt][r] + bias;
                v = (v > 0.f) ? v : 0.f;
                gcn_out[((size_t)(b * NN + n) * TT + t) * DD + nt * 16 + cl] = v;
            }
        }
    }
}

// ---------------- K3a (MFMA): Wp[u] = e_u-weighted sum of W; LDS-staged coalesced writeout.
__global__ __launch_bounds__(256) void k_wp(
    const float* __restrict__ node_emb, const float* __restrict__ tfeat,
    const unsigned short* __restrict__ wb, unsigned short* __restrict__ wp,
    int u0, int Uc) {
    int un0 = blockIdx.x * 16;
    int chunk = blockIdx.y;                 // 0..47
    int p = chunk >> 4, tr = chunk & 15;
    int tid = threadIdx.x, lane = tid & 63, wid = tid >> 6;

    __shared__ float s_e[16][MM];
    __shared__ __align__(16) unsigned short s_out[16 * 1032];   // ~33 KB

    {
        int nn = tid >> 4, m = tid & 15;    // 256 = 16*16 exactly
        int us = un0 + nn;
        float e = 0.f;
        if (us < Uc) {
            int u = u0 + us;
            int b = u / NN, n = u % NN;
            e = node_emb[n * MM + m] * tfeat[b * MM + m];
        }
        s_e[nn][m] = e;
    }
    __syncthreads();

    int node = lane & 15;
    int mb = (lane >> 4) * 8;
    bf16x8 ef = {0, 0, 0, 0, 0, 0, 0, 0};
    if (mb < MM) {
#pragma unroll
        for (int j = 0; j < 8; ++j) ef[j] = (short)f2bf(s_e[node][mb + j]);
    }
    const unsigned short* wsrc = wb + (size_t)p * 1024 * 512;

#pragma unroll 1
    for (int t16 = 0; t16 < 16; ++t16) {
        int T = tr * 64 + wid * 16 + t16;
        union { uint4 u4; bf16x8 v; } af;
        af.u4 = *(const uint4*)&wsrc[((size_t)T * 64 + lane) * 8];
        f32x4 acc = {0.f, 0.f, 0.f, 0.f};
        acc = __builtin_amdgcn_mfma_f32_16x16x32_bf16(af.v, ef, acc, 0, 0, 0);
        int k = T >> 3;
        int i0 = (T & 7) * 16 + (lane >> 4) * 4;
        int ksl = i0 >> 5, Ll = (i0 >> 3) & 3, jf0 = i0 & 7, kk = k & 7;
        int loc = node * 1032 + ((ksl * 4 + Ll) * 8 + kk) * 8 + jf0;
        uint2 pk;
        pk.x = packbf(acc[0], acc[1]);
        pk.y = packbf(acc[2], acc[3]);
        *(uint2*)&s_out[loc] = pk;
    }
    __syncthreads();

    // coalesced writeout: 2048 uint4, 8/thread; 8-lane groups write 128 B contiguous runs
    int nt = tr >> 1, c1 = tr & 1;
    size_t gbase = (size_t)p * 16384 + (size_t)nt * 2048 + (size_t)c1 * 64;
#pragma unroll
    for (int step = 0; step < 8; ++step) {
        int idx = step * 256 + tid;
        int nd = idx >> 7, rem = idx & 127;
        int ksw = rem >> 5, Lw = (rem >> 3) & 3, q = rem & 7;
        int us = un0 + nd;
        if (us < Uc) {
            uint4 v = *(const uint4*)&s_out[nd * 1032 + ((ksw * 4 + Lw) * 8 + q) * 8];
            *(uint4*)&wp[(size_t)us * 49152 + gbase + (size_t)ksw * 512 + Lw * 128 + q * 8] = v;
        }
    }
}

// ---------------- K3b: per node MFMA proj -> lrelu -> qkv bf16 to workspace.
__global__ __launch_bounds__(256) void k_proj(
    const float* __restrict__ hidden, const float* __restrict__ tXin,
    const unsigned short* __restrict__ wp, unsigned short* __restrict__ qkv,
    int u0) {
    int us = blockIdx.x;
    int u = u0 + us;
    int tid = threadIdx.x;
    int lane = tid & 63, wid = tid >> 6;
    int trow = lane & 15, kgrp = lane >> 4;

    size_t base = (size_t)u * TT * DD;

    bf16x8 afrag[2][4];
#pragma unroll
    for (int mt = 0; mt < 2; ++mt) {
        int t = mt * 16 + trow;
        bool valid = (t < TT);
#pragma unroll
        for (int ks = 0; ks < 4; ++ks) {
            int i0 = ks * 32 + kgrp * 8;
            float4 lo = make_float4(0.f, 0.f, 0.f, 0.f), hi = lo;
            if (valid) {
                const float* src = (i0 < DD) ? &hidden[base + t * DD + i0]
                                             : &tXin[base + t * DD + (i0 - DD)];
                lo = *(const float4*)src;
                hi = *(const float4*)(src + 4);
            }
            afrag[mt][ks] = pack_bf8(lo, hi);
        }
    }

    const unsigned short* wbase = wp + (size_t)us * 49152;
    unsigned short* qbase = qkv + (size_t)us * (3 * TT * E2);
    int rowg = kgrp * 4;
    int col0 = wid * 16 + trow;
    int col1 = (wid + 4) * 16 + trow;
#pragma unroll 1
    for (int p = 0; p < 3; ++p) {
        f32x4 acc00 = {0.f, 0.f, 0.f, 0.f}, acc01 = acc00, acc10 = acc00, acc11 = acc00;
#pragma unroll
        for (int ks = 0; ks < 4; ++ks) {
            union { uint4 u4; bf16x8 v; } c0, c1;
            c0.u4 = *(const uint4*)(wbase + (size_t)p * 16384 + (((wid) * 4 + ks) * 64 + lane) * 8);
            c1.u4 = *(const uint4*)(wbase + (size_t)p * 16384 + (((wid + 4) * 4 + ks) * 64 + lane) * 8);
            acc00 = __builtin_amdgcn_mfma_f32_16x16x32_bf16(afrag[0][ks], c0.v, acc00, 0, 0, 0);
            acc10 = __builtin_amdgcn_mfma_f32_16x16x32_bf16(afrag[1][ks], c0.v, acc10, 0, 0, 0);
            acc01 = __builtin_amdgcn_mfma_f32_16x16x32_bf16(afrag[0][ks], c1.v, acc01, 0, 0, 0);
            acc11 = __builtin_amdgcn_mfma_f32_16x16x32_bf16(afrag[1][ks], c1.v, acc11, 0, 0, 0);
        }
#pragma unroll
        for (int r = 0; r < 4; ++r) {
            int t = rowg + r;
            float v0 = acc00[r]; v0 = (v0 >= 0.f) ? v0 : NEG * v0;
            float v1 = acc01[r]; v1 = (v1 >= 0.f) ? v1 : NEG * v1;
            qbase[(p * TT + t) * E2 + col0] = f2bf(v0);
            qbase[(p * TT + t) * E2 + col1] = f2bf(v1);
        }
        if (rowg < 8) {
#pragma unroll
            for (int r = 0; r < 4; ++r) {
                int t = 16 + rowg + r;
                float v0 = acc10[r]; v0 = (v0 >= 0.f) ? v0 : NEG * v0;
                float v1 = acc11[r]; v1 = (v1 >= 0.f) ? v1 : NEG * v1;
                qbase[(p * TT + t) * E2 + col0] = f2bf(v0);
                qbase[(p * TT + t) * E2 + col1] = f2bf(v1);
            }
        }
    }
}

// ---------------- K3c: per node: attention (scalar C1/C2) + MFMA out-proj/gate + residual
#define QKS 66
#define QKP (TT * QKS)
#define SC_OFF 4752
#define VAL_OFF 7248
#define VQS 68
__global__ __launch_bounds__(256) void k_attn2(
    const unsigned* __restrict__ qkv, const float* __restrict__ hidden,
    const unsigned short* __restrict__ cw,
    const float* __restrict__ out_b, const float* __restrict__ gate_b,
    const float* __restrict__ gcn_out, float* __restrict__ out,
    int u0) {
    int us = blockIdx.x;
    int u = u0 + us;
    int tid = threadIdx.x;

    __shared__ __align__(16) unsigned arena[8880];
    __shared__ float s_gcn[TT][VQS];
    __shared__ float s_value[TT][VQS];

    size_t base = (size_t)u * TT * DD;

    const unsigned* src = qkv + (size_t)us * (3 * TT * 64);
    for (int idx = tid; idx < 3 * TT * 64; idx += 256) {
        int p = idx / (TT * 64);
        int r = idx % (TT * 64);
        int t = r >> 6, kp = r & 63;
        arena[p * QKP + t * QKS + kp] = src[idx];
    }
    for (int idx = tid; idx < TT * DD; idx += 256)
        s_gcn[idx >> 6][idx & 63] = gcn_out[base + idx];
    unsigned* s_qkv = arena;
    __syncthreads();

    // ---- phase C1: scores (scalar)
    unsigned* s_sc = arena + SC_OFF;
    if (tid < HH * TT) {
        int h = tid / TT, t = tid % TT;
        const float scale = 0.25f;
        float qf[16];
#pragma unroll
        for (int j = 0; j < 8; ++j) {
            unsigned uq = s_qkv[0 * QKP + t * QKS + 8 * h + j];
            qf[2 * j] = bflo(uq); qf[2 * j + 1] = bfhi(uq);
        }
#pragma unroll
        for (int s2 = 0; s2 < 12; ++s2) {
            int s0 = 2 * s2;
            float d0 = 0.f, d1 = 0.f;
#pragma unroll
            for (int j = 0; j < 8; ++j) {
                unsigned ka = s_qkv[1 * QKP + s0 * QKS + 8 * h + j];
                unsigned kb = s_qkv[1 * QKP + (s0 + 1) * QKS + 8 * h + j];
                d0 += qf[2 * j] * bflo(ka) + qf[2 * j + 1] * bfhi(ka);
                d1 += qf[2 * j] * bflo(kb) + qf[2 * j + 1] * bfhi(kb);
            }
            float w0 = (s0 <= t) ? __expf(d0 * scale) : 0.f;
            float w1 = (s0 + 1 <= t) ? __expf(d1 * scale) : 0.f;
            s_sc[(h * TT + t) * 13 + s2] = packbf(w0, w1);
        }
    }
    __syncthreads();

    // ---- phase C2: normalize + PV -> packed val[24][VQS]
    unsigned* s_val = arena + VAL_OFF;
#pragma unroll
    for (int it = 0; it < 3; ++it) {
        int item = tid + it * 256;
        int h = item / 96;
        int r = item % 96;
        int t = r >> 2, d4 = r & 3;
        int kg0 = 8 * h + 2 * d4;
        float sum = 0.f, v0 = 0.f, v1 = 0.f, v2 = 0.f, v3 = 0.f;
#pragma unroll
        for (int s2 = 0; s2 < 12; ++s2) {
            unsigned uw = s_sc[(h * TT + t) * 13 + s2];
            float w0 = bflo(uw), w1 = bfhi(uw);
            sum += w0 + w1;
            unsigned ua = s_qkv[2 * QKP + (2 * s2) * QKS + kg0];
            unsigned ub = s_qkv[2 * QKP + (2 * s2) * QKS + kg0 + 1];
            v0 += w0 * bflo(ua); v1 += w0 * bfhi(ua);
            v2 += w0 * bflo(ub); v3 += w0 * bfhi(ub);
            unsigned uc = s_qkv[2 * QKP + (2 * s2 + 1) * QKS + kg0];
            unsigned ud = s_qkv[2 * QKP + (2 * s2 + 1) * QKS + kg0 + 1];
            v0 += w1 * bflo(uc); v1 += w1 * bfhi(uc);
            v2 += w1 * bflo(ud); v3 += w1 * bfhi(ud);
        }
        float inv = 1.f / sum;
        s_val[t * VQS + kg0]     = packbf(v0 * inv, v1 * inv);
        s_val[t * VQS + kg0 + 1] = packbf(v2 * inv, v3 * inv);
    }
    __syncthreads();

    // ---- phase D (MFMA): value = lrelu(val @ out_w + out_b)
    int lane = tid & 63, wid = tid >> 6;
    int cl = lane & 15, kg = lane >> 4;
    {
        f32x4 d0 = {0.f, 0.f, 0.f, 0.f}, d1 = d0;
#pragma unroll
        for (int ks = 0; ks < 4; ++ks) {
            union { uint4 u4; bf16x8 v; } a0, a1, bw;
            a0.u4 = *(const uint4*)&s_val[cl * VQS + ks * 16 + kg * 4];
            if (cl < 8) a1.u4 = *(const uint4*)&s_val[(16 + cl) * VQS + ks * 16 + kg * 4];
            else a1.u4 = make_uint4(0, 0, 0, 0);
            bw.u4 = *(const uint4*)&cw[((size_t)(wid * 4 + ks) * 64 + lane) * 8];
            d0 = __builtin_amdgcn_mfma_f32_16x16x32_bf16(a0.v, bw.v, d0, 0, 0, 0);
            d1 = __builtin_amdgcn_mfma_f32_16x16x32_bf16(a1.v, bw.v, d1, 0, 0, 0);
        }
        int col = wid * 16 + cl;
        float bias = out_b[col];
#pragma unroll
        for (int r = 0; r < 4; ++r) {
            int t = kg * 4 + r;
            float v = d0[r] + bias; v = (v >= 0.f) ? v : NEG * v;
            s_value[t][col] = v;
        }
        if (kg < 2) {
#pragma unroll
            for (int r = 0; r < 4; ++r) {
                int t = 16 + kg * 4 + r;
                float v = d1[r] + bias; v = (v >= 0.f) ? v : NEG * v;
                s_value[t][col] = v;
            }
        }
    }
    __syncthreads();

    // ---- phase E (MFMA): z = sigmoid([gcn|value] @ gate_w + gate_b); out = z*g + (1-z)*v + hidden
    {
        f32x4 g0 = {0.f, 0.f, 0.f, 0.f}, g1 = g0;
#pragma unroll
        for (int ks = 0; ks < 4; ++ks) {
            int i0 = ks * 32 + kg * 8;
            const float* src0 = (i0 < DD) ? &s_gcn[cl][i0] : &s_value[cl][i0 - DD];
            float4 lo = *(const float4*)src0;
            float4 hi = *(const float4*)(src0 + 4);
            bf16x8 a0 = pack_bf8(lo, hi);
            bf16x8 a1 = {0, 0, 0, 0, 0, 0, 0, 0};
            if (cl < 8) {
                const float* src1 = (i0 < DD) ? &s_gcn[16 + cl][i0] : &s_value[16 + cl][i0 - DD];
                float4 lo1 = *(const float4*)src1;
                float4 hi1 = *(const float4*)(src1 + 4);
                a1 = pack_bf8(lo1, hi1);
            }
            union { uint4 u4; bf16x8 v; } bw;
            bw.u4 = *(const uint4*)&cw[8192 + ((size_t)(wid * 4 + ks) * 64 + lane) * 8];
            g0 = __builtin_amdgcn_mfma_f32_16x16x32_bf16(a0, bw.v, g0, 0, 0, 0);
            g1 = __builtin_amdgcn_mfma_f32_16x16x32_bf16(a1, bw.v, g1, 0, 0, 0);
        }
        int col = wid * 16 + cl;
        float gb = gate_b[col];
#pragma unroll
        for (int r = 0; r < 4; ++r) {
            int t = kg * 4 + r;
            float z = 1.f / (1.f + __expf(-(g0[r] + gb)));
            float gv = s_gcn[t][col], vv = s_value[t][col];
            size_t ob = base + (size_t)t * DD + col;
            out[ob] = z * gv + (1.f - z) * vv + hidden[ob];
        }
        if (kg < 2) {
#pragma unroll
            for (int r = 0; r < 4; ++r) {
                int t = 16 + kg * 4 + r;
                float z = 1.f / (1.f + __expf(-(g1[r] + gb)));
                float gv = s_gcn[t][col], vv = s_value[t][col];
                size_t ob = base + (size_t)t * DD + col;
                out[ob] = z * gv + (1.f - z) * vv + hidden[ob];
            }
        }
    }
}

extern "C" void kernel_launch(void* const* d_in, const int* in_sizes, int n_in,
                              void* d_out, int out_size, void* d_ws, size_t ws_size,
                              hipStream_t stream) {
    const float* hidden   = (const float*)d_in[0];
    const float* tXin     = (const float*)d_in[1];
    const float* matrix   = (const float*)d_in[2];
    const float* gcn_w    = (const float*)d_in[3];
    const float* gcn_b    = (const float*)d_in[4];
    const float* node_emb = (const float*)d_in[5];
    const float* tproj_w  = (const float*)d_in[6];
    const float* tproj_b  = (const float*)d_in[7];
    const float* WK_      = (const float*)d_in[8];   // dict order: WK, WQ, WV
    const float* WQ_      = (const float*)d_in[9];
    const float* WV_      = (const float*)d_in[10];
    const float* out_w    = (const float*)d_in[11];
    const float* out_b    = (const float*)d_in[12];
    const float* gate_w   = (const float*)d_in[13];
    const float* gate_b   = (const float*)d_in[14];
    float* out = (float*)d_out;

    char* ws = (char*)d_ws;
    float* tfeat   = (float*)ws;                         // 512 B
    float* gcn_out = (float*)(ws + 512);                 // 15,974,400 B
    size_t off_ht  = 512 + (size_t)BB * NN * TT * DD * 4;
    size_t ht_size = (size_t)BB * TT * DD * HTM * 2 + 4096;
    size_t off_cw  = off_ht + ht_size;
    size_t off_wb  = off_cw + 32768;
    size_t wb_size = (size_t)3 * 1024 * 64 * 8 * 2;      // 3,145,728 B
    size_t off_wp  = off_wb + wb_size;

    const size_t per_wp  = 3 * (size_t)E2 * E2 * 2;      // 98304 B per node (bf16)
    const size_t per_qkv = 3 * (size_t)TT * E2 * 2;      // 18432 B per node (bf16)
    long long avail = (long long)ws_size - (long long)off_wp;
    long long Ull = avail / (long long)(per_wp + per_qkv);
    int U = (Ull < 1) ? 1 : ((Ull > NNODE) ? NNODE : (int)Ull);
    if (U > UCAP) U = UCAP;   // 2 passes, 129 MB wp chunk (L3-resident); grids stay >=1300 blocks

    unsigned short* ht_buf  = (unsigned short*)(ws + off_ht);
    unsigned short* cw_buf  = (unsigned short*)(ws + off_cw);
    unsigned short* wb_buf  = (unsigned short*)(ws + off_wb);
    unsigned short* wp_buf  = (unsigned short*)(ws + off_wp);
    unsigned short* qkv_buf = (unsigned short*)(ws + off_wp + (size_t)U * per_wp);

    k_tfeat<<<BB, DD, 0, stream>>>(tXin, tproj_w, tproj_b, tfeat);
    k_cw<<<1, 256, 0, stream>>>(out_w, gate_w, cw_buf);
    k_wconv<<<768, 256, 0, stream>>>(WQ_, WK_, WV_, wb_buf);
    k_ht<<<dim3(BB * TT, 6), 256, 0, stream>>>(hidden, ht_buf);
    k_gcn<<<dim3(BB * TT, 6), 256, 0, stream>>>(matrix, ht_buf, gcn_w, gcn_b, gcn_out);

    for (int u0 = 0; u0 < NNODE; u0 += U) {
        int Uc = (NNODE - u0 < U) ? (NNODE - u0) : U;
        k_wp<<<dim3((Uc + 15) / 16, 48), 256, 0, stream>>>(node_emb, tfeat, wb_buf,
                                                           wp_buf, u0, Uc);
        k_proj<<<Uc, 256, 0, stream>>>(hidden, tXin, wp_buf, qkv_buf, u0);
        k_attn2<<<Uc, 256, 0, stream>>>((const unsigned*)qkv_buf, hidden, cw_buf,
                                        out_b, gate_b, gcn_out, out, u0);
    }
}

// Round 19
// 279.511 us; speedup vs baseline: 1.4750x; 1.0243x over previous
//
#include <hip/hip_runtime.h>
#include <math.h>

#define BB 8
#define NN 325
#define TT 24
#define DD 64
#define HH 8
#define MM 16
#define E2 128
#define DK 16
#define NEG 0.1f
#define NNODE (BB * NN)          // 2600
#define HTM 328                  // padded m-extent of ht rows
#define UCAP 1312                // 2 passes; 129 MB wp chunk stays L3-resident, grids stay large

typedef short bf16x8 __attribute__((ext_vector_type(8)));
typedef float f32x4 __attribute__((ext_vector_type(4)));

__device__ __forceinline__ unsigned short f2bf(float f) {
    union { float f; unsigned u; } v; v.f = f;
    unsigned r = v.u + 0x7fffu + ((v.u >> 16) & 1u);   // RNE
    return (unsigned short)(r >> 16);
}
__device__ __forceinline__ unsigned packbf(float a, float b) {
    return (unsigned)f2bf(a) | ((unsigned)f2bf(b) << 16);
}
__device__ __forceinline__ float bflo(unsigned u) { return __uint_as_float(u << 16); }
__device__ __forceinline__ float bfhi(unsigned u) { return __uint_as_float(u & 0xffff0000u); }

__device__ __forceinline__ bf16x8 pack_bf8(float4 lo, float4 hi) {
    bf16x8 r;
    r[0] = (short)f2bf(lo.x); r[1] = (short)f2bf(lo.y);
    r[2] = (short)f2bf(lo.z); r[3] = (short)f2bf(lo.w);
    r[4] = (short)f2bf(hi.x); r[5] = (short)f2bf(hi.y);
    r[6] = (short)f2bf(hi.z); r[7] = (short)f2bf(hi.w);
    return r;
}

// ---------------- K1: tfeat[b][m] = tanh(mean_t(tXin[b,0,t,:]) @ tproj_w + tproj_b)
__global__ void k_tfeat(const float* __restrict__ tXin, const float* __restrict__ tproj_w,
                        const float* __restrict__ tproj_b, float* __restrict__ tfeat) {
    int b = blockIdx.x;
    int d = threadIdx.x;  // 64 threads
    __shared__ float mv[DD];
    float a = 0.f;
    for (int t = 0; t < TT; ++t)
        a += tXin[((size_t)(b * NN + 0) * TT + t) * DD + d];
    mv[d] = a * (1.f / (float)TT);
    __syncthreads();
    if (d < MM) {
        float acc = tproj_b[d];
        for (int j = 0; j < DD; ++j) acc += mv[j] * tproj_w[j * MM + d];
        tfeat[b * MM + d] = tanhf(acc);
    }
}

// ---------------- K_cw: out_w/gate_w -> bf16 B-fragment layout (once, 1 block)
__global__ __launch_bounds__(256) void k_cw(const float* __restrict__ out_w,
                                            const float* __restrict__ gate_w,
                                            unsigned short* __restrict__ cw) {
    int tid = threadIdx.x;
    for (int idx = tid; idx < 8192; idx += 256) {
        int i = idx >> 6, k = idx & 63;
        int nt = k >> 4, ks = i >> 5;
        int lane = (k & 15) | (((i >> 3) & 3) << 4);
        int off = (nt * 4 + ks) * 512 + lane * 8 + (i & 7);
        cw[off] = f2bf(out_w[i * 64 + k]);
        cw[8192 + off] = f2bf(gate_w[i * 64 + k]);
    }
}

// ---------------- K_wconv: W (fp32) -> bf16 A-fragment tensor over n = k*128 + i ordering.
__global__ __launch_bounds__(256) void k_wconv(const float* __restrict__ WQ,
                                               const float* __restrict__ WK,
                                               const float* __restrict__ WV,
                                               unsigned short* __restrict__ wb) {
    int idx = blockIdx.x * 256 + threadIdx.x;   // 3*1024*64 = 196608
    int lane = idx & 63;
    int pt = idx >> 6;
    int T = pt & 1023, p = pt >> 10;
    const float* __restrict__ W = (p == 0) ? WQ : ((p == 1) ? WK : WV);
    int n = T * 16 + (lane & 15);
    int i = n & 127, k = n >> 7;
    int mb = (lane >> 4) * 8;
    unsigned short v[8];
#pragma unroll
    for (int j = 0; j < 8; ++j) {
        int m = mb + j;
        v[j] = (m < MM) ? f2bf(W[(size_t)m * 16384 + i * 128 + k]) : (unsigned short)0;
    }
    *(uint4*)&wb[(size_t)idx * 8] = *(const uint4*)v;
}

// ---------------- K_ht: ht[bt][d][m] = bf16(hidden[b][m][t][d])  (transposed, padded to HTM)
__global__ __launch_bounds__(256) void k_ht(const float* __restrict__ hidden,
                                            unsigned short* __restrict__ ht) {
    int bt = blockIdx.x;          // b*TT + t
    int b = bt / TT, t = bt % TT;
    int m0 = blockIdx.y * 64;
    __shared__ float s[64][67];
    int tid = threadIdx.x;
#pragma unroll
    for (int i = 0; i < 4; ++i) {
        int idx = tid + i * 256;
        int mm = idx >> 4, q = idx & 15;
        int m = m0 + mm;
        float4 v = make_float4(0.f, 0.f, 0.f, 0.f);
        if (m < NN) v = *(const float4*)&hidden[((size_t)(b * NN + m) * TT + t) * DD + q * 4];
        s[mm][q * 4 + 0] = v.x; s[mm][q * 4 + 1] = v.y;
        s[mm][q * 4 + 2] = v.z; s[mm][q * 4 + 3] = v.w;
    }
    __syncthreads();
    size_t obase = (size_t)bt * DD * HTM;
    int jcap = HTM - m0;
#pragma unroll
    for (int i = 0; i < 16; ++i) {
        int idx = tid + i * 256;
        int d = idx >> 6, j = idx & 63;
        if (j < jcap) ht[obase + (size_t)d * HTM + m0 + j] = f2bf(s[j][d]);
    }
}

// ---------------- K2 (MFMA): S = matrix(b,t) @ H ; gcn_out = relu(S @ gcn_w + b)
// A-rows PREFETCHED into a named register array in a separate loop BEFORE any MFMA
// (R18: full unroll alone left VGPR=32 — allocator re-serialized the chains; this
// restructure exposes one HBM-latency window per block instead of 11).
__global__ __launch_bounds__(256) void k_gcn(const float* __restrict__ matrix,
                                             const unsigned short* __restrict__ ht,
                                             const float* __restrict__ gcn_w,
                                             const float* __restrict__ gcn_b,
                                             float* __restrict__ gcn_out) {
    int bt = blockIdx.x;
    int tile = blockIdx.y;
    int b = bt / TT, t = bt % TT;
    int n0 = tile * 64;
    int tid = threadIdx.x, lane = tid & 63, wid = tid >> 6;
    int cl = lane & 15, kg = lane >> 4;

    __shared__ unsigned short s_s[64][72];    // S bf16 [n][d]
    __shared__ unsigned short s_gw[64][72];   // gw^T bf16 [e][d]

#pragma unroll
    for (int i = 0; i < 4; ++i) {
        int idx = tid + i * 256;
        int d = idx >> 4, e0 = (idx & 15) * 4;
        float4 v = *(const float4*)&gcn_w[d * DD + e0];
        s_gw[e0 + 0][d] = f2bf(v.x); s_gw[e0 + 1][d] = f2bf(v.y);
        s_gw[e0 + 2][d] = f2bf(v.z); s_gw[e0 + 3][d] = f2bf(v.w);
    }
    __syncthreads();

    const float* mrow = matrix + (size_t)bt * NN * NN;
    const unsigned short* hbase = ht + (size_t)bt * DD * HTM;
    int strip = wid * 16;
    int arow = n0 + strip + cl;
    bool avalid = arow < NN;
    const float* arp = mrow + (size_t)arow * NN;

    // ---- phase 0: issue ALL 10 A-row segment loads (20 float4) up front
    float4 aA[10][2];
#pragma unroll
    for (int s = 0; s < 10; ++s) {
        int m0 = s * 32 + kg * 8;
        if (avalid) {
            aA[s][0] = *(const float4*)&arp[m0];
            aA[s][1] = *(const float4*)&arp[m0 + 4];
        } else {
            aA[s][0] = make_float4(0.f, 0.f, 0.f, 0.f);
            aA[s][1] = aA[s][0];
        }
    }
    float vtail[8];
    {
        int m0 = 320 + kg * 8;
#pragma unroll
        for (int j = 0; j < 8; ++j)
            vtail[j] = (avalid && (m0 + j) < NN) ? arp[m0 + j] : 0.f;
    }

    f32x4 acc[4];
#pragma unroll
    for (int nt = 0; nt < 4; ++nt) acc[nt] = (f32x4){0.f, 0.f, 0.f, 0.f};

    // ---- phase 1: pack + MFMA sweep (A already in registers; B is L2-resident)
#pragma unroll
    for (int s = 0; s < 10; ++s) {
        int m0 = s * 32 + kg * 8;
        bf16x8 af = pack_bf8(aA[s][0], aA[s][1]);
#pragma unroll
        for (int nt = 0; nt < 4; ++nt) {
            union { uint4 u4; bf16x8 v; } bf;
            bf.u4 = *(const uint4*)&hbase[(size_t)(nt * 16 + cl) * HTM + m0];
            acc[nt] = __builtin_amdgcn_mfma_f32_16x16x32_bf16(af, bf.v, acc[nt], 0, 0, 0);
        }
    }
    {
        int m0 = 320 + kg * 8;
        bf16x8 af = pack_bf8(make_float4(vtail[0], vtail[1], vtail[2], vtail[3]),
                             make_float4(vtail[4], vtail[5], vtail[6], vtail[7]));
#pragma unroll
        for (int nt = 0; nt < 4; ++nt) {
            union { uint4 u4; bf16x8 v4; } bf;
            bf.u4 = *(const uint4*)&hbase[(size_t)(nt * 16 + cl) * HTM + m0];
            acc[nt] = __builtin_amdgcn_mfma_f32_16x16x32_bf16(af, bf.v4, acc[nt], 0, 0, 0);
        }
    }

#pragma unroll
    for (int nt = 0; nt < 4; ++nt)
#pragma unroll
        for (int r = 0; r < 4; ++r)
            s_s[strip + kg * 4 + r][nt * 16 + cl] = f2bf(acc[nt][r]);

    f32x4 g[4];
#pragma unroll
    for (int nt = 0; nt < 4; ++nt) g[nt] = (f32x4){0.f, 0.f, 0.f, 0.f};
#pragma unroll
    for (int kk = 0; kk < 2; ++kk) {
        union { uint4 u4; bf16x8 v; } sa;
        sa.u4 = *(const uint4*)&s_s[strip + cl][kk * 32 + kg * 8];
#pragma unroll
        for (int nt = 0; nt < 4; ++nt) {
            union { uint4 u4; bf16x8 v; } bf;
            bf.u4 = *(const uint4*)&s_gw[nt * 16 + cl][kk * 32 + kg * 8];
            g[nt] = __builtin_amdgcn_mfma_f32_16x16x32_bf16(sa.v, bf.v, g[nt], 0, 0, 0);
        }
    }

#pragma unroll
    for (int nt = 0; nt < 4; ++nt) {
        float bias = gcn_b[nt * 16 + cl];
#pragma unroll
        for (int r = 0; r < 4; ++r) {
            int n = n0 + strip + kg * 4 + r;
            if (n < NN) {
                float v = g[nt][r] + bias;
                v = (v > 0.f) ? v : 0.f;
                gcn_out[((size_t)(b * NN + n) * TT + t) * DD + nt * 16 + cl] = v;
            }
        }
    }
}

// ---------------- K3a (MFMA): Wp[u] = e_u-weighted sum of W; LDS-staged coalesced writeout.
__global__ __launch_bounds__(256) void k_wp(
    const float* __restrict__ node_emb, const float* __restrict__ tfeat,
    const unsigned short* __restrict__ wb, unsigned short* __restrict__ wp,
    int u0, int Uc) {
    int un0 = blockIdx.x * 16;
    int chunk = blockIdx.y;                 // 0..47
    int p = chunk >> 4, tr = chunk & 15;
    int tid = threadIdx.x, lane = tid & 63, wid = tid >> 6;

    __shared__ float s_e[16][MM];
    __shared__ __align__(16) unsigned short s_out[16 * 1032];   // ~33 KB

    {
        int nn = tid >> 4, m = tid & 15;    // 256 = 16*16 exactly
        int us = un0 + nn;
        float e = 0.f;
        if (us < Uc) {
            int u = u0 + us;
            int b = u / NN, n = u % NN;
            e = node_emb[n * MM + m] * tfeat[b * MM + m];
        }
        s_e[nn][m] = e;
    }
    __syncthreads();

    int node = lane & 15;
    int mb = (lane >> 4) * 8;
    bf16x8 ef = {0, 0, 0, 0, 0, 0, 0, 0};
    if (mb < MM) {
#pragma unroll
        for (int j = 0; j < 8; ++j) ef[j] = (short)f2bf(s_e[node][mb + j]);
    }
    const unsigned short* wsrc = wb + (size_t)p * 1024 * 512;

#pragma unroll 1
    for (int t16 = 0; t16 < 16; ++t16) {
        int T = tr * 64 + wid * 16 + t16;
        union { uint4 u4; bf16x8 v; } af;
        af.u4 = *(const uint4*)&wsrc[((size_t)T * 64 + lane) * 8];
        f32x4 acc = {0.f, 0.f, 0.f, 0.f};
        acc = __builtin_amdgcn_mfma_f32_16x16x32_bf16(af.v, ef, acc, 0, 0, 0);
        int k = T >> 3;
        int i0 = (T & 7) * 16 + (lane >> 4) * 4;
        int ksl = i0 >> 5, Ll = (i0 >> 3) & 3, jf0 = i0 & 7, kk = k & 7;
        int loc = node * 1032 + ((ksl * 4 + Ll) * 8 + kk) * 8 + jf0;
        uint2 pk;
        pk.x = packbf(acc[0], acc[1]);
        pk.y = packbf(acc[2], acc[3]);
        *(uint2*)&s_out[loc] = pk;
    }
    __syncthreads();

    // coalesced writeout: 2048 uint4, 8/thread; 8-lane groups write 128 B contiguous runs
    int nt = tr >> 1, c1 = tr & 1;
    size_t gbase = (size_t)p * 16384 + (size_t)nt * 2048 + (size_t)c1 * 64;
#pragma unroll
    for (int step = 0; step < 8; ++step) {
        int idx = step * 256 + tid;
        int nd = idx >> 7, rem = idx & 127;
        int ksw = rem >> 5, Lw = (rem >> 3) & 3, q = rem & 7;
        int us = un0 + nd;
        if (us < Uc) {
            uint4 v = *(const uint4*)&s_out[nd * 1032 + ((ksw * 4 + Lw) * 8 + q) * 8];
            *(uint4*)&wp[(size_t)us * 49152 + gbase + (size_t)ksw * 512 + Lw * 128 + q * 8] = v;
        }
    }
}

// ---------------- K3b: per node MFMA proj -> lrelu -> qkv bf16 to workspace.
__global__ __launch_bounds__(256) void k_proj(
    const float* __restrict__ hidden, const float* __restrict__ tXin,
    const unsigned short* __restrict__ wp, unsigned short* __restrict__ qkv,
    int u0) {
    int us = blockIdx.x;
    int u = u0 + us;
    int tid = threadIdx.x;
    int lane = tid & 63, wid = tid >> 6;
    int trow = lane & 15, kgrp = lane >> 4;

    size_t base = (size_t)u * TT * DD;

    bf16x8 afrag[2][4];
#pragma unroll
    for (int mt = 0; mt < 2; ++mt) {
        int t = mt * 16 + trow;
        bool valid = (t < TT);
#pragma unroll
        for (int ks = 0; ks < 4; ++ks) {
            int i0 = ks * 32 + kgrp * 8;
            float4 lo = make_float4(0.f, 0.f, 0.f, 0.f), hi = lo;
            if (valid) {
                const float* src = (i0 < DD) ? &hidden[base + t * DD + i0]
                                             : &tXin[base + t * DD + (i0 - DD)];
                lo = *(const float4*)src;
                hi = *(const float4*)(src + 4);
            }
            afrag[mt][ks] = pack_bf8(lo, hi);
        }
    }

    const unsigned short* wbase = wp + (size_t)us * 49152;
    unsigned short* qbase = qkv + (size_t)us * (3 * TT * E2);
    int rowg = kgrp * 4;
    int col0 = wid * 16 + trow;
    int col1 = (wid + 4) * 16 + trow;
#pragma unroll 1
    for (int p = 0; p < 3; ++p) {
        f32x4 acc00 = {0.f, 0.f, 0.f, 0.f}, acc01 = acc00, acc10 = acc00, acc11 = acc00;
#pragma unroll
        for (int ks = 0; ks < 4; ++ks) {
            union { uint4 u4; bf16x8 v; } c0, c1;
            c0.u4 = *(const uint4*)(wbase + (size_t)p * 16384 + (((wid) * 4 + ks) * 64 + lane) * 8);
            c1.u4 = *(const uint4*)(wbase + (size_t)p * 16384 + (((wid + 4) * 4 + ks) * 64 + lane) * 8);
            acc00 = __builtin_amdgcn_mfma_f32_16x16x32_bf16(afrag[0][ks], c0.v, acc00, 0, 0, 0);
            acc10 = __builtin_amdgcn_mfma_f32_16x16x32_bf16(afrag[1][ks], c0.v, acc10, 0, 0, 0);
            acc01 = __builtin_amdgcn_mfma_f32_16x16x32_bf16(afrag[0][ks], c1.v, acc01, 0, 0, 0);
            acc11 = __builtin_amdgcn_mfma_f32_16x16x32_bf16(afrag[1][ks], c1.v, acc11, 0, 0, 0);
        }
#pragma unroll
        for (int r = 0; r < 4; ++r) {
            int t = rowg + r;
            float v0 = acc00[r]; v0 = (v0 >= 0.f) ? v0 : NEG * v0;
            float v1 = acc01[r]; v1 = (v1 >= 0.f) ? v1 : NEG * v1;
            qbase[(p * TT + t) * E2 + col0] = f2bf(v0);
            qbase[(p * TT + t) * E2 + col1] = f2bf(v1);
        }
        if (rowg < 8) {
#pragma unroll
            for (int r = 0; r < 4; ++r) {
                int t = 16 + rowg + r;
                float v0 = acc10[r]; v0 = (v0 >= 0.f) ? v0 : NEG * v0;
                float v1 = acc11[r]; v1 = (v1 >= 0.f) ? v1 : NEG * v1;
                qbase[(p * TT + t) * E2 + col0] = f2bf(v0);
                qbase[(p * TT + t) * E2 + col1] = f2bf(v1);
            }
        }
    }
}

// ---------------- K3c: per node: attention (scalar C1/C2) + MFMA out-proj/gate + residual
#define QKS 66
#define QKP (TT * QKS)
#define SC_OFF 4752
#define VAL_OFF 7248
#define VQS 68
__global__ __launch_bounds__(256) void k_attn2(
    const unsigned* __restrict__ qkv, const float* __restrict__ hidden,
    const unsigned short* __restrict__ cw,
    const float* __restrict__ out_b, const float* __restrict__ gate_b,
    const float* __restrict__ gcn_out, float* __restrict__ out,
    int u0) {
    int us = blockIdx.x;
    int u = u0 + us;
    int tid = threadIdx.x;

    __shared__ __align__(16) unsigned arena[8880];
    __shared__ float s_gcn[TT][VQS];
    __shared__ float s_value[TT][VQS];

    size_t base = (size_t)u * TT * DD;

    const unsigned* src = qkv + (size_t)us * (3 * TT * 64);
    for (int idx = tid; idx < 3 * TT * 64; idx += 256) {
        int p = idx / (TT * 64);
        int r = idx % (TT * 64);
        int t = r >> 6, kp = r & 63;
        arena[p * QKP + t * QKS + kp] = src[idx];
    }
    for (int idx = tid; idx < TT * DD; idx += 256)
        s_gcn[idx >> 6][idx & 63] = gcn_out[base + idx];
    unsigned* s_qkv = arena;
    __syncthreads();

    // ---- phase C1: scores (scalar)
    unsigned* s_sc = arena + SC_OFF;
    if (tid < HH * TT) {
        int h = tid / TT, t = tid % TT;
        const float scale = 0.25f;
        float qf[16];
#pragma unroll
        for (int j = 0; j < 8; ++j) {
            unsigned uq = s_qkv[0 * QKP + t * QKS + 8 * h + j];
            qf[2 * j] = bflo(uq); qf[2 * j + 1] = bfhi(uq);
        }
#pragma unroll
        for (int s2 = 0; s2 < 12; ++s2) {
            int s0 = 2 * s2;
            float d0 = 0.f, d1 = 0.f;
#pragma unroll
            for (int j = 0; j < 8; ++j) {
                unsigned ka = s_qkv[1 * QKP + s0 * QKS + 8 * h + j];
                unsigned kb = s_qkv[1 * QKP + (s0 + 1) * QKS + 8 * h + j];
                d0 += qf[2 * j] * bflo(ka) + qf[2 * j + 1] * bfhi(ka);
                d1 += qf[2 * j] * bflo(kb) + qf[2 * j + 1] * bfhi(kb);
            }
            float w0 = (s0 <= t) ? __expf(d0 * scale) : 0.f;
            float w1 = (s0 + 1 <= t) ? __expf(d1 * scale) : 0.f;
            s_sc[(h * TT + t) * 13 + s2] = packbf(w0, w1);
        }
    }
    __syncthreads();

    // ---- phase C2: normalize + PV -> packed val[24][VQS]
    unsigned* s_val = arena + VAL_OFF;
#pragma unroll
    for (int it = 0; it < 3; ++it) {
        int item = tid + it * 256;
        int h = item / 96;
        int r = item % 96;
        int t = r >> 2, d4 = r & 3;
        int kg0 = 8 * h + 2 * d4;
        float sum = 0.f, v0 = 0.f, v1 = 0.f, v2 = 0.f, v3 = 0.f;
#pragma unroll
        for (int s2 = 0; s2 < 12; ++s2) {
            unsigned uw = s_sc[(h * TT + t) * 13 + s2];
            float w0 = bflo(uw), w1 = bfhi(uw);
            sum += w0 + w1;
            unsigned ua = s_qkv[2 * QKP + (2 * s2) * QKS + kg0];
            unsigned ub = s_qkv[2 * QKP + (2 * s2) * QKS + kg0 + 1];
            v0 += w0 * bflo(ua); v1 += w0 * bfhi(ua);
            v2 += w0 * bflo(ub); v3 += w0 * bfhi(ub);
            unsigned uc = s_qkv[2 * QKP + (2 * s2 + 1) * QKS + kg0];
            unsigned ud = s_qkv[2 * QKP + (2 * s2 + 1) * QKS + kg0 + 1];
            v0 += w1 * bflo(uc); v1 += w1 * bfhi(uc);
            v2 += w1 * bflo(ud); v3 += w1 * bfhi(ud);
        }
        float inv = 1.f / sum;
        s_val[t * VQS + kg0]     = packbf(v0 * inv, v1 * inv);
        s_val[t * VQS + kg0 + 1] = packbf(v2 * inv, v3 * inv);
    }
    __syncthreads();

    // ---- phase D (MFMA): value = lrelu(val @ out_w + out_b)
    int lane = tid & 63, wid = tid >> 6;
    int cl = lane & 15, kg = lane >> 4;
    {
        f32x4 d0 = {0.f, 0.f, 0.f, 0.f}, d1 = d0;
#pragma unroll
        for (int ks = 0; ks < 4; ++ks) {
            union { uint4 u4; bf16x8 v; } a0, a1, bw;
            a0.u4 = *(const uint4*)&s_val[cl * VQS + ks * 16 + kg * 4];
            if (cl < 8) a1.u4 = *(const uint4*)&s_val[(16 + cl) * VQS + ks * 16 + kg * 4];
            else a1.u4 = make_uint4(0, 0, 0, 0);
            bw.u4 = *(const uint4*)&cw[((size_t)(wid * 4 + ks) * 64 + lane) * 8];
            d0 = __builtin_amdgcn_mfma_f32_16x16x32_bf16(a0.v, bw.v, d0, 0, 0, 0);
            d1 = __builtin_amdgcn_mfma_f32_16x16x32_bf16(a1.v, bw.v, d1, 0, 0, 0);
        }
        int col = wid * 16 + cl;
        float bias = out_b[col];
#pragma unroll
        for (int r = 0; r < 4; ++r) {
            int t = kg * 4 + r;
            float v = d0[r] + bias; v = (v >= 0.f) ? v : NEG * v;
            s_value[t][col] = v;
        }
        if (kg < 2) {
#pragma unroll
            for (int r = 0; r < 4; ++r) {
                int t = 16 + kg * 4 + r;
                float v = d1[r] + bias; v = (v >= 0.f) ? v : NEG * v;
                s_value[t][col] = v;
            }
        }
    }
    __syncthreads();

    // ---- phase E (MFMA): z = sigmoid([gcn|value] @ gate_w + gate_b); out = z*g + (1-z)*v + hidden
    {
        f32x4 g0 = {0.f, 0.f, 0.f, 0.f}, g1 = g0;
#pragma unroll
        for (int ks = 0; ks < 4; ++ks) {
            int i0 = ks * 32 + kg * 8;
            const float* src0 = (i0 < DD) ? &s_gcn[cl][i0] : &s_value[cl][i0 - DD];
            float4 lo = *(const float4*)src0;
            float4 hi = *(const float4*)(src0 + 4);
            bf16x8 a0 = pack_bf8(lo, hi);
            bf16x8 a1 = {0, 0, 0, 0, 0, 0, 0, 0};
            if (cl < 8) {
                const float* src1 = (i0 < DD) ? &s_gcn[16 + cl][i0] : &s_value[16 + cl][i0 - DD];
                float4 lo1 = *(const float4*)src1;
                float4 hi1 = *(const float4*)(src1 + 4);
                a1 = pack_bf8(lo1, hi1);
            }
            union { uint4 u4; bf16x8 v; } bw;
            bw.u4 = *(const uint4*)&cw[8192 + ((size_t)(wid * 4 + ks) * 64 + lane) * 8];
            g0 = __builtin_amdgcn_mfma_f32_16x16x32_bf16(a0, bw.v, g0, 0, 0, 0);
            g1 = __builtin_amdgcn_mfma_f32_16x16x32_bf16(a1, bw.v, g1, 0, 0, 0);
        }
        int col = wid * 16 + cl;
        float gb = gate_b[col];
#pragma unroll
        for (int r = 0; r < 4; ++r) {
            int t = kg * 4 + r;
            float z = 1.f / (1.f + __expf(-(g0[r] + gb)));
            float gv = s_gcn[t][col], vv = s_value[t][col];
            size_t ob = base + (size_t)t * DD + col;
            out[ob] = z * gv + (1.f - z) * vv + hidden[ob];
        }
        if (kg < 2) {
#pragma unroll
            for (int r = 0; r < 4; ++r) {
                int t = 16 + kg * 4 + r;
                float z = 1.f / (1.f + __expf(-(g1[r] + gb)));
                float gv = s_gcn[t][col], vv = s_value[t][col];
                size_t ob = base + (size_t)t * DD + col;
                out[ob] = z * gv + (1.f - z) * vv + hidden[ob];
            }
        }
    }
}

extern "C" void kernel_launch(void* const* d_in, const int* in_sizes, int n_in,
                              void* d_out, int out_size, void* d_ws, size_t ws_size,
                              hipStream_t stream) {
    const float* hidden   = (const float*)d_in[0];
    const float* tXin     = (const float*)d_in[1];
    const float* matrix   = (const float*)d_in[2];
    const float* gcn_w    = (const float*)d_in[3];
    const float* gcn_b    = (const float*)d_in[4];
    const float* node_emb = (const float*)d_in[5];
    const float* tproj_w  = (const float*)d_in[6];
    const float* tproj_b  = (const float*)d_in[7];
    const float* WK_      = (const float*)d_in[8];   // dict order: WK, WQ, WV
    const float* WQ_      = (const float*)d_in[9];
    const float* WV_      = (const float*)d_in[10];
    const float* out_w    = (const float*)d_in[11];
    const float* out_b    = (const float*)d_in[12];
    const float* gate_w   = (const float*)d_in[13];
    const float* gate_b   = (const float*)d_in[14];
    float* out = (float*)d_out;

    char* ws = (char*)d_ws;
    float* tfeat   = (float*)ws;                         // 512 B
    float* gcn_out = (float*)(ws + 512);                 // 15,974,400 B
    size_t off_ht  = 512 + (size_t)BB * NN * TT * DD * 4;
    size_t ht_size = (size_t)BB * TT * DD * HTM * 2 + 4096;
    size_t off_cw  = off_ht + ht_size;
    size_t off_wb  = off_cw + 32768;
    size_t wb_size = (size_t)3 * 1024 * 64 * 8 * 2;      // 3,145,728 B
    size_t off_wp  = off_wb + wb_size;

    const size_t per_wp  = 3 * (size_t)E2 * E2 * 2;      // 98304 B per node (bf16)
    const size_t per_qkv = 3 * (size_t)TT * E2 * 2;      // 18432 B per node (bf16)
    long long avail = (long long)ws_size - (long long)off_wp;
    long long Ull = avail / (long long)(per_wp + per_qkv);
    int U = (Ull < 1) ? 1 : ((Ull > NNODE) ? NNODE : (int)Ull);
    if (U > UCAP) U = UCAP;   // 2 passes, 129 MB wp chunk (L3-resident); grids stay >=1300 blocks

    unsigned short* ht_buf  = (unsigned short*)(ws + off_ht);
    unsigned short* cw_buf  = (unsigned short*)(ws + off_cw);
    unsigned short* wb_buf  = (unsigned short*)(ws + off_wb);
    unsigned short* wp_buf  = (unsigned short*)(ws + off_wp);
    unsigned short* qkv_buf = (unsigned short*)(ws + off_wp + (size_t)U * per_wp);

    k_tfeat<<<BB, DD, 0, stream>>>(tXin, tproj_w, tproj_b, tfeat);
    k_cw<<<1, 256, 0, stream>>>(out_w, gate_w, cw_buf);
    k_wconv<<<768, 256, 0, stream>>>(WQ_, WK_, WV_, wb_buf);
    k_ht<<<dim3(BB * TT, 6), 256, 0, stream>>>(hidden, ht_buf);
    k_gcn<<<dim3(BB * TT, 6), 256, 0, stream>>>(matrix, ht_buf, gcn_w, gcn_b, gcn_out);

    for (int u0 = 0; u0 < NNODE; u0 += U) {
        int Uc = (NNODE - u0 < U) ? (NNODE - u0) : U;
        k_wp<<<dim3((Uc + 15) / 16, 48), 256, 0, stream>>>(node_emb, tfeat, wb_buf,
                                                           wp_buf, u0, Uc);
        k_proj<<<Uc, 256, 0, stream>>>(hidden, tXin, wp_buf, qkv_buf, u0);
        k_attn2<<<Uc, 256, 0, stream>>>((const unsigned*)qkv_buf, hidden, cw_buf,
                                        out_b, gate_b, gcn_out, out, u0);
    }
}

// Round 21
// 278.954 us; speedup vs baseline: 1.4779x; 1.0020x over previous
//
#include <hip/hip_runtime.h>
#include <math.h>

#define BB 8
#define NN 325
#define TT 24
#define DD 64
#define HH 8
#define MM 16
#define E2 128
#define DK 16
#define NEG 0.1f
#define NNODE (BB * NN)          // 2600
#define HTM 328                  // padded m-extent of ht rows
#define UCAP 1312                // 2 passes; 129 MB wp chunk stays L3-resident, grids stay large

typedef short bf16x8 __attribute__((ext_vector_type(8)));
typedef float f32x4 __attribute__((ext_vector_type(4)));

__device__ __forceinline__ unsigned short f2bf(float f) {
    union { float f; unsigned u; } v; v.f = f;
    unsigned r = v.u + 0x7fffu + ((v.u >> 16) & 1u);   // RNE
    return (unsigned short)(r >> 16);
}
__device__ __forceinline__ unsigned packbf(float a, float b) {
    return (unsigned)f2bf(a) | ((unsigned)f2bf(b) << 16);
}
__device__ __forceinline__ float bflo(unsigned u) { return __uint_as_float(u << 16); }
__device__ __forceinline__ float bfhi(unsigned u) { return __uint_as_float(u & 0xffff0000u); }

__device__ __forceinline__ bf16x8 pack_bf8(float4 lo, float4 hi) {
    bf16x8 r;
    r[0] = (short)f2bf(lo.x); r[1] = (short)f2bf(lo.y);
    r[2] = (short)f2bf(lo.z); r[3] = (short)f2bf(lo.w);
    r[4] = (short)f2bf(hi.x); r[5] = (short)f2bf(hi.y);
    r[6] = (short)f2bf(hi.z); r[7] = (short)f2bf(hi.w);
    return r;
}

// ---------------- K1: tfeat[b][m] = tanh(mean_t(tXin[b,0,t,:]) @ tproj_w + tproj_b)
__global__ void k_tfeat(const float* __restrict__ tXin, const float* __restrict__ tproj_w,
                        const float* __restrict__ tproj_b, float* __restrict__ tfeat) {
    int b = blockIdx.x;
    int d = threadIdx.x;  // 64 threads
    __shared__ float mv[DD];
    float a = 0.f;
    for (int t = 0; t < TT; ++t)
        a += tXin[((size_t)(b * NN + 0) * TT + t) * DD + d];
    mv[d] = a * (1.f / (float)TT);
    __syncthreads();
    if (d < MM) {
        float acc = tproj_b[d];
        for (int j = 0; j < DD; ++j) acc += mv[j] * tproj_w[j * MM + d];
        tfeat[b * MM + d] = tanhf(acc);
    }
}

// ---------------- K_cw: out_w/gate_w -> bf16 B-fragment layout (once, 1 block)
__global__ __launch_bounds__(256) void k_cw(const float* __restrict__ out_w,
                                            const float* __restrict__ gate_w,
                                            unsigned short* __restrict__ cw) {
    int tid = threadIdx.x;
    for (int idx = tid; idx < 8192; idx += 256) {
        int i = idx >> 6, k = idx & 63;
        int nt = k >> 4, ks = i >> 5;
        int lane = (k & 15) | (((i >> 3) & 3) << 4);
        int off = (nt * 4 + ks) * 512 + lane * 8 + (i & 7);
        cw[off] = f2bf(out_w[i * 64 + k]);
        cw[8192 + off] = f2bf(gate_w[i * 64 + k]);
    }
}

// ---------------- K_wconv: W (fp32) -> bf16 A-fragment tensor over n = k*128 + i ordering.
__global__ __launch_bounds__(256) void k_wconv(const float* __restrict__ WQ,
                                               const float* __restrict__ WK,
                                               const float* __restrict__ WV,
                                               unsigned short* __restrict__ wb) {
    int idx = blockIdx.x * 256 + threadIdx.x;   // 3*1024*64 = 196608
    int lane = idx & 63;
    int pt = idx >> 6;
    int T = pt & 1023, p = pt >> 10;
    const float* __restrict__ W = (p == 0) ? WQ : ((p == 1) ? WK : WV);
    int n = T * 16 + (lane & 15);
    int i = n & 127, k = n >> 7;
    int mb = (lane >> 4) * 8;
    unsigned short v[8];
#pragma unroll
    for (int j = 0; j < 8; ++j) {
        int m = mb + j;
        v[j] = (m < MM) ? f2bf(W[(size_t)m * 16384 + i * 128 + k]) : (unsigned short)0;
    }
    *(uint4*)&wb[(size_t)idx * 8] = *(const uint4*)v;
}

// ---------------- K_ht: ht[bt][d][m] = bf16(hidden[b][m][t][d])  (transposed, padded to HTM)
__global__ __launch_bounds__(256) void k_ht(const float* __restrict__ hidden,
                                            unsigned short* __restrict__ ht) {
    int bt = blockIdx.x;          // b*TT + t
    int b = bt / TT, t = bt % TT;
    int m0 = blockIdx.y * 64;
    __shared__ float s[64][67];
    int tid = threadIdx.x;
#pragma unroll
    for (int i = 0; i < 4; ++i) {
        int idx = tid + i * 256;
        int mm = idx >> 4, q = idx & 15;
        int m = m0 + mm;
        float4 v = make_float4(0.f, 0.f, 0.f, 0.f);
        if (m < NN) v = *(const float4*)&hidden[((size_t)(b * NN + m) * TT + t) * DD + q * 4];
        s[mm][q * 4 + 0] = v.x; s[mm][q * 4 + 1] = v.y;
        s[mm][q * 4 + 2] = v.z; s[mm][q * 4 + 3] = v.w;
    }
    __syncthreads();
    size_t obase = (size_t)bt * DD * HTM;
    int jcap = HTM - m0;
#pragma unroll
    for (int i = 0; i < 16; ++i) {
        int idx = tid + i * 256;
        int d = idx >> 6, j = idx & 63;
        if (j < jcap) ht[obase + (size_t)d * HTM + m0 + j] = f2bf(s[j][d]);
    }
}

// ---------------- K2 (MFMA): S = matrix(b,t) @ H ; gcn_out = relu(S @ gcn_w + b)
// A-rows PREFETCHED into a named register array in a separate loop BEFORE any MFMA.
__global__ __launch_bounds__(256) void k_gcn(const float* __restrict__ matrix,
                                             const unsigned short* __restrict__ ht,
                                             const float* __restrict__ gcn_w,
                                             const float* __restrict__ gcn_b,
                                             float* __restrict__ gcn_out) {
    int bt = blockIdx.x;
    int tile = blockIdx.y;
    int b = bt / TT, t = bt % TT;
    int n0 = tile * 64;
    int tid = threadIdx.x, lane = tid & 63, wid = tid >> 6;
    int cl = lane & 15, kg = lane >> 4;

    __shared__ unsigned short s_s[64][72];    // S bf16 [n][d]
    __shared__ unsigned short s_gw[64][72];   // gw^T bf16 [e][d]

#pragma unroll
    for (int i = 0; i < 4; ++i) {
        int idx = tid + i * 256;
        int d = idx >> 4, e0 = (idx & 15) * 4;
        float4 v = *(const float4*)&gcn_w[d * DD + e0];
        s_gw[e0 + 0][d] = f2bf(v.x); s_gw[e0 + 1][d] = f2bf(v.y);
        s_gw[e0 + 2][d] = f2bf(v.z); s_gw[e0 + 3][d] = f2bf(v.w);
    }
    __syncthreads();

    const float* mrow = matrix + (size_t)bt * NN * NN;
    const unsigned short* hbase = ht + (size_t)bt * DD * HTM;
    int strip = wid * 16;
    int arow = n0 + strip + cl;
    bool avalid = arow < NN;
    const float* arp = mrow + (size_t)arow * NN;

    // ---- phase 0: issue ALL 10 A-row segment loads (20 float4) up front
    float4 aA[10][2];
#pragma unroll
    for (int s = 0; s < 10; ++s) {
        int m0 = s * 32 + kg * 8;
        if (avalid) {
            aA[s][0] = *(const float4*)&arp[m0];
            aA[s][1] = *(const float4*)&arp[m0 + 4];
        } else {
            aA[s][0] = make_float4(0.f, 0.f, 0.f, 0.f);
            aA[s][1] = aA[s][0];
        }
    }
    float vtail[8];
    {
        int m0 = 320 + kg * 8;
#pragma unroll
        for (int j = 0; j < 8; ++j)
            vtail[j] = (avalid && (m0 + j) < NN) ? arp[m0 + j] : 0.f;
    }

    f32x4 acc[4];
#pragma unroll
    for (int nt = 0; nt < 4; ++nt) acc[nt] = (f32x4){0.f, 0.f, 0.f, 0.f};

    // ---- phase 1: pack + MFMA sweep (A already in registers; B is L2-resident)
#pragma unroll
    for (int s = 0; s < 10; ++s) {
        int m0 = s * 32 + kg * 8;
        bf16x8 af = pack_bf8(aA[s][0], aA[s][1]);
#pragma unroll
        for (int nt = 0; nt < 4; ++nt) {
            union { uint4 u4; bf16x8 v; } bf;
            bf.u4 = *(const uint4*)&hbase[(size_t)(nt * 16 + cl) * HTM + m0];
            acc[nt] = __builtin_amdgcn_mfma_f32_16x16x32_bf16(af, bf.v, acc[nt], 0, 0, 0);
        }
    }
    {
        int m0 = 320 + kg * 8;
        bf16x8 af = pack_bf8(make_float4(vtail[0], vtail[1], vtail[2], vtail[3]),
                             make_float4(vtail[4], vtail[5], vtail[6], vtail[7]));
#pragma unroll
        for (int nt = 0; nt < 4; ++nt) {
            union { uint4 u4; bf16x8 v4; } bf;
            bf.u4 = *(const uint4*)&hbase[(size_t)(nt * 16 + cl) * HTM + m0];
            acc[nt] = __builtin_amdgcn_mfma_f32_16x16x32_bf16(af, bf.v4, acc[nt], 0, 0, 0);
        }
    }

#pragma unroll
    for (int nt = 0; nt < 4; ++nt)
#pragma unroll
        for (int r = 0; r < 4; ++r)
            s_s[strip + kg * 4 + r][nt * 16 + cl] = f2bf(acc[nt][r]);

    f32x4 g[4];
#pragma unroll
    for (int nt = 0; nt < 4; ++nt) g[nt] = (f32x4){0.f, 0.f, 0.f, 0.f};
#pragma unroll
    for (int kk = 0; kk < 2; ++kk) {
        union { uint4 u4; bf16x8 v; } sa;
        sa.u4 = *(const uint4*)&s_s[strip + cl][kk * 32 + kg * 8];
#pragma unroll
        for (int nt = 0; nt < 4; ++nt) {
            union { uint4 u4; bf16x8 v; } bf;
            bf.u4 = *(const uint4*)&s_gw[nt * 16 + cl][kk * 32 + kg * 8];
            g[nt] = __builtin_amdgcn_mfma_f32_16x16x32_bf16(sa.v, bf.v, g[nt], 0, 0, 0);
        }
    }

#pragma unroll
    for (int nt = 0; nt < 4; ++nt) {
        float bias = gcn_b[nt * 16 + cl];
#pragma unroll
        for (int r = 0; r < 4; ++r) {
            int n = n0 + strip + kg * 4 + r;
            if (n < NN) {
                float v = g[nt][r] + bias;
                v = (v > 0.f) ? v : 0.f;
                gcn_out[((size_t)(b * NN + n) * TT + t) * DD + nt * 16 + cl] = v;
            }
        }
    }
}

// ---------------- K3a (MFMA): Wp[u] = e_u-weighted sum of W; LDS-staged coalesced writeout.
__global__ __launch_bounds__(256) void k_wp(
    const float* __restrict__ node_emb, const float* __restrict__ tfeat,
    const unsigned short* __restrict__ wb, unsigned short* __restrict__ wp,
    int u0, int Uc) {
    int un0 = blockIdx.x * 16;
    int chunk = blockIdx.y;                 // 0..47
    int p = chunk >> 4, tr = chunk & 15;
    int tid = threadIdx.x, lane = tid & 63, wid = tid >> 6;

    __shared__ float s_e[16][MM];
    __shared__ __align__(16) unsigned short s_out[16 * 1032];   // ~33 KB

    {
        int nn = tid >> 4, m = tid & 15;    // 256 = 16*16 exactly
        int us = un0 + nn;
        float e = 0.f;
        if (us < Uc) {
            int u = u0 + us;
            int b = u / NN, n = u % NN;
            e = node_emb[n * MM + m] * tfeat[b * MM + m];
        }
        s_e[nn][m] = e;
    }
    __syncthreads();

    int node = lane & 15;
    int mb = (lane >> 4) * 8;
    bf16x8 ef = {0, 0, 0, 0, 0, 0, 0, 0};
    if (mb < MM) {
#pragma unroll
        for (int j = 0; j < 8; ++j) ef[j] = (short)f2bf(s_e[node][mb + j]);
    }
    const unsigned short* wsrc = wb + (size_t)p * 1024 * 512;

#pragma unroll 1
    for (int t16 = 0; t16 < 16; ++t16) {
        int T = tr * 64 + wid * 16 + t16;
        union { uint4 u4; bf16x8 v; } af;
        af.u4 = *(const uint4*)&wsrc[((size_t)T * 64 + lane) * 8];
        f32x4 acc = {0.f, 0.f, 0.f, 0.f};
        acc = __builtin_amdgcn_mfma_f32_16x16x32_bf16(af.v, ef, acc, 0, 0, 0);
        int k = T >> 3;
        int i0 = (T & 7) * 16 + (lane >> 4) * 4;
        int ksl = i0 >> 5, Ll = (i0 >> 3) & 3, jf0 = i0 & 7, kk = k & 7;
        int loc = node * 1032 + ((ksl * 4 + Ll) * 8 + kk) * 8 + jf0;
        uint2 pk;
        pk.x = packbf(acc[0], acc[1]);
        pk.y = packbf(acc[2], acc[3]);
        *(uint2*)&s_out[loc] = pk;
    }
    __syncthreads();

    // coalesced writeout: 2048 uint4, 8/thread; 8-lane groups write 128 B contiguous runs
    int nt = tr >> 1, c1 = tr & 1;
    size_t gbase = (size_t)p * 16384 + (size_t)nt * 2048 + (size_t)c1 * 64;
#pragma unroll
    for (int step = 0; step < 8; ++step) {
        int idx = step * 256 + tid;
        int nd = idx >> 7, rem = idx & 127;
        int ksw = rem >> 5, Lw = (rem >> 3) & 3, q = rem & 7;
        int us = un0 + nd;
        if (us < Uc) {
            uint4 v = *(const uint4*)&s_out[nd * 1032 + ((ksw * 4 + Lw) * 8 + q) * 8];
            *(uint4*)&wp[(size_t)us * 49152 + gbase + (size_t)ksw * 512 + Lw * 128 + q * 8] = v;
        }
    }
}

// ---------------- K3b: per node MFMA proj -> lrelu -> qkv bf16 to workspace.
__global__ __launch_bounds__(256) void k_proj(
    const float* __restrict__ hidden, const float* __restrict__ tXin,
    const unsigned short* __restrict__ wp, unsigned short* __restrict__ qkv,
    int u0) {
    int us = blockIdx.x;
    int u = u0 + us;
    int tid = threadIdx.x;
    int lane = tid & 63, wid = tid >> 6;
    int trow = lane & 15, kgrp = lane >> 4;

    size_t base = (size_t)u * TT * DD;

    bf16x8 afrag[2][4];
#pragma unroll
    for (int mt = 0; mt < 2; ++mt) {
        int t = mt * 16 + trow;
        bool valid = (t < TT);
#pragma unroll
        for (int ks = 0; ks < 4; ++ks) {
            int i0 = ks * 32 + kgrp * 8;
            float4 lo = make_float4(0.f, 0.f, 0.f, 0.f), hi = lo;
            if (valid) {
                const float* src = (i0 < DD) ? &hidden[base + t * DD + i0]
                                             : &tXin[base + t * DD + (i0 - DD)];
                lo = *(const float4*)src;
                hi = *(const float4*)(src + 4);
            }
            afrag[mt][ks] = pack_bf8(lo, hi);
        }
    }

    const unsigned short* wbase = wp + (size_t)us * 49152;
    unsigned short* qbase = qkv + (size_t)us * (3 * TT * E2);
    int rowg = kgrp * 4;
    int col0 = wid * 16 + trow;
    int col1 = (wid + 4) * 16 + trow;
#pragma unroll 1
    for (int p = 0; p < 3; ++p) {
        f32x4 acc00 = {0.f, 0.f, 0.f, 0.f}, acc01 = acc00, acc10 = acc00, acc11 = acc00;
#pragma unroll
        for (int ks = 0; ks < 4; ++ks) {
            union { uint4 u4; bf16x8 v; } c0, c1;
            c0.u4 = *(const uint4*)(wbase + (size_t)p * 16384 + (((wid) * 4 + ks) * 64 + lane) * 8);
            c1.u4 = *(const uint4*)(wbase + (size_t)p * 16384 + (((wid + 4) * 4 + ks) * 64 + lane) * 8);
            acc00 = __builtin_amdgcn_mfma_f32_16x16x32_bf16(afrag[0][ks], c0.v, acc00, 0, 0, 0);
            acc10 = __builtin_amdgcn_mfma_f32_16x16x32_bf16(afrag[1][ks], c0.v, acc10, 0, 0, 0);
            acc01 = __builtin_amdgcn_mfma_f32_16x16x32_bf16(afrag[0][ks], c1.v, acc01, 0, 0, 0);
            acc11 = __builtin_amdgcn_mfma_f32_16x16x32_bf16(afrag[1][ks], c1.v, acc11, 0, 0, 0);
        }
#pragma unroll
        for (int r = 0; r < 4; ++r) {
            int t = rowg + r;
            float v0 = acc00[r]; v0 = (v0 >= 0.f) ? v0 : NEG * v0;
            float v1 = acc01[r]; v1 = (v1 >= 0.f) ? v1 : NEG * v1;
            qbase[(p * TT + t) * E2 + col0] = f2bf(v0);
            qbase[(p * TT + t) * E2 + col1] = f2bf(v1);
        }
        if (rowg < 8) {
#pragma unroll
            for (int r = 0; r < 4; ++r) {
                int t = 16 + rowg + r;
                float v0 = acc10[r]; v0 = (v0 >= 0.f) ? v0 : NEG * v0;
                float v1 = acc11[r]; v1 = (v1 >= 0.f) ? v1 : NEG * v1;
                qbase[(p * TT + t) * E2 + col0] = f2bf(v0);
                qbase[(p * TT + t) * E2 + col1] = f2bf(v1);
            }
        }
    }
}

// ---------------- K3c: per node: attention (scalar C1/C2) + MFMA out-proj/gate + residual
#define QKS 66
#define QKP (TT * QKS)
#define SC_OFF 4752
#define VAL_OFF 7248
#define VQS 68
__global__ __launch_bounds__(256) void k_attn2(
    const unsigned* __restrict__ qkv, const float* __restrict__ hidden,
    const unsigned short* __restrict__ cw,
    const float* __restrict__ out_b, const float* __restrict__ gate_b,
    const float* __restrict__ gcn_out, float* __restrict__ out,
    int u0) {
    int us = blockIdx.x;
    int u = u0 + us;
    int tid = threadIdx.x;

    __shared__ __align__(16) unsigned arena[8880];
    __shared__ float s_gcn[TT][VQS];
    __shared__ float s_value[TT][VQS];

    size_t base = (size_t)u * TT * DD;

    const unsigned* src = qkv + (size_t)us * (3 * TT * 64);
    for (int idx = tid; idx < 3 * TT * 64; idx += 256) {
        int p = idx / (TT * 64);
        int r = idx % (TT * 64);
        int t = r >> 6, kp = r & 63;
        arena[p * QKP + t * QKS + kp] = src[idx];
    }
    for (int idx = tid; idx < TT * DD; idx += 256)
        s_gcn[idx >> 6][idx & 63] = gcn_out[base + idx];
    unsigned* s_qkv = arena;
    __syncthreads();

    // ---- phase C1: scores (scalar)
    unsigned* s_sc = arena + SC_OFF;
    if (tid < HH * TT) {
        int h = tid / TT, t = tid % TT;
        const float scale = 0.25f;
        float qf[16];
#pragma unroll
        for (int j = 0; j < 8; ++j) {
            unsigned uq = s_qkv[0 * QKP + t * QKS + 8 * h + j];
            qf[2 * j] = bflo(uq); qf[2 * j + 1] = bfhi(uq);
        }
#pragma unroll
        for (int s2 = 0; s2 < 12; ++s2) {
            int s0 = 2 * s2;
            float d0 = 0.f, d1 = 0.f;
#pragma unroll
            for (int j = 0; j < 8; ++j) {
                unsigned ka = s_qkv[1 * QKP + s0 * QKS + 8 * h + j];
                unsigned kb = s_qkv[1 * QKP + (s0 + 1) * QKS + 8 * h + j];
                d0 += qf[2 * j] * bflo(ka) + qf[2 * j + 1] * bfhi(ka);
                d1 += qf[2 * j] * bflo(kb) + qf[2 * j + 1] * bfhi(kb);
            }
            float w0 = (s0 <= t) ? __expf(d0 * scale) : 0.f;
            float w1 = (s0 + 1 <= t) ? __expf(d1 * scale) : 0.f;
            s_sc[(h * TT + t) * 13 + s2] = packbf(w0, w1);
        }
    }
    __syncthreads();

    // ---- phase C2: normalize + PV -> packed val[24][VQS]
    unsigned* s_val = arena + VAL_OFF;
#pragma unroll
    for (int it = 0; it < 3; ++it) {
        int item = tid + it * 256;
        int h = item / 96;
        int r = item % 96;
        int t = r >> 2, d4 = r & 3;
        int kg0 = 8 * h + 2 * d4;
        float sum = 0.f, v0 = 0.f, v1 = 0.f, v2 = 0.f, v3 = 0.f;
#pragma unroll
        for (int s2 = 0; s2 < 12; ++s2) {
            unsigned uw = s_sc[(h * TT + t) * 13 + s2];
            float w0 = bflo(uw), w1 = bfhi(uw);
            sum += w0 + w1;
            unsigned ua = s_qkv[2 * QKP + (2 * s2) * QKS + kg0];
            unsigned ub = s_qkv[2 * QKP + (2 * s2) * QKS + kg0 + 1];
            v0 += w0 * bflo(ua); v1 += w0 * bfhi(ua);
            v2 += w0 * bflo(ub); v3 += w0 * bfhi(ub);
            unsigned uc = s_qkv[2 * QKP + (2 * s2 + 1) * QKS + kg0];
            unsigned ud = s_qkv[2 * QKP + (2 * s2 + 1) * QKS + kg0 + 1];
            v0 += w1 * bflo(uc); v1 += w1 * bfhi(uc);
            v2 += w1 * bflo(ud); v3 += w1 * bfhi(ud);
        }
        float inv = 1.f / sum;
        s_val[t * VQS + kg0]     = packbf(v0 * inv, v1 * inv);
        s_val[t * VQS + kg0 + 1] = packbf(v2 * inv, v3 * inv);
    }
    __syncthreads();

    // ---- phase D (MFMA): value = lrelu(val @ out_w + out_b)
    int lane = tid & 63, wid = tid >> 6;
    int cl = lane & 15, kg = lane >> 4;
    {
        f32x4 d0 = {0.f, 0.f, 0.f, 0.f}, d1 = d0;
#pragma unroll
        for (int ks = 0; ks < 4; ++ks) {
            union { uint4 u4; bf16x8 v; } a0, a1, bw;
            a0.u4 = *(const uint4*)&s_val[cl * VQS + ks * 16 + kg * 4];
            if (cl < 8) a1.u4 = *(const uint4*)&s_val[(16 + cl) * VQS + ks * 16 + kg * 4];
            else a1.u4 = make_uint4(0, 0, 0, 0);
            bw.u4 = *(const uint4*)&cw[((size_t)(wid * 4 + ks) * 64 + lane) * 8];
            d0 = __builtin_amdgcn_mfma_f32_16x16x32_bf16(a0.v, bw.v, d0, 0, 0, 0);
            d1 = __builtin_amdgcn_mfma_f32_16x16x32_bf16(a1.v, bw.v, d1, 0, 0, 0);
        }
        int col = wid * 16 + cl;
        float bias = out_b[col];
#pragma unroll
        for (int r = 0; r < 4; ++r) {
            int t = kg * 4 + r;
            float v = d0[r] + bias; v = (v >= 0.f) ? v : NEG * v;
            s_value[t][col] = v;
        }
        if (kg < 2) {
#pragma unroll
            for (int r = 0; r < 4; ++r) {
                int t = 16 + kg * 4 + r;
                float v = d1[r] + bias; v = (v >= 0.f) ? v : NEG * v;
                s_value[t][col] = v;
            }
        }
    }
    __syncthreads();

    // ---- phase E (MFMA): z = sigmoid([gcn|value] @ gate_w + gate_b); out = z*g + (1-z)*v + hidden
    {
        f32x4 g0 = {0.f, 0.f, 0.f, 0.f}, g1 = g0;
#pragma unroll
        for (int ks = 0; ks < 4; ++ks) {
            int i0 = ks * 32 + kg * 8;
            const float* src0 = (i0 < DD) ? &s_gcn[cl][i0] : &s_value[cl][i0 - DD];
            float4 lo = *(const float4*)src0;
            float4 hi = *(const float4*)(src0 + 4);
            bf16x8 a0 = pack_bf8(lo, hi);
            bf16x8 a1 = {0, 0, 0, 0, 0, 0, 0, 0};
            if (cl < 8) {
                const float* src1 = (i0 < DD) ? &s_gcn[16 + cl][i0] : &s_value[16 + cl][i0 - DD];
                float4 lo1 = *(const float4*)src1;
                float4 hi1 = *(const float4*)(src1 + 4);
                a1 = pack_bf8(lo1, hi1);
            }
            union { uint4 u4; bf16x8 v; } bw;
            bw.u4 = *(const uint4*)&cw[8192 + ((size_t)(wid * 4 + ks) * 64 + lane) * 8];
            g0 = __builtin_amdgcn_mfma_f32_16x16x32_bf16(a0, bw.v, g0, 0, 0, 0);
            g1 = __builtin_amdgcn_mfma_f32_16x16x32_bf16(a1, bw.v, g1, 0, 0, 0);
        }
        int col = wid * 16 + cl;
        float gb = gate_b[col];
#pragma unroll
        for (int r = 0; r < 4; ++r) {
            int t = kg * 4 + r;
            float z = 1.f / (1.f + __expf(-(g0[r] + gb)));
            float gv = s_gcn[t][col], vv = s_value[t][col];
            size_t ob = base + (size_t)t * DD + col;
            out[ob] = z * gv + (1.f - z) * vv + hidden[ob];
        }
        if (kg < 2) {
#pragma unroll
            for (int r = 0; r < 4; ++r) {
                int t = 16 + kg * 4 + r;
                float z = 1.f / (1.f + __expf(-(g1[r] + gb)));
                float gv = s_gcn[t][col], vv = s_value[t][col];
                size_t ob = base + (size_t)t * DD + col;
                out[ob] = z * gv + (1.f - z) * vv + hidden[ob];
            }
        }
    }
}

extern "C" void kernel_launch(void* const* d_in, const int* in_sizes, int n_in,
                              void* d_out, int out_size, void* d_ws, size_t ws_size,
                              hipStream_t stream) {
    const float* hidden   = (const float*)d_in[0];
    const float* tXin     = (const float*)d_in[1];
    const float* matrix   = (const float*)d_in[2];
    const float* gcn_w    = (const float*)d_in[3];
    const float* gcn_b    = (const float*)d_in[4];
    const float* node_emb = (const float*)d_in[5];
    const float* tproj_w  = (const float*)d_in[6];
    const float* tproj_b  = (const float*)d_in[7];
    const float* WK_      = (const float*)d_in[8];   // dict order: WK, WQ, WV
    const float* WQ_      = (const float*)d_in[9];
    const float* WV_      = (const float*)d_in[10];
    const float* out_w    = (const float*)d_in[11];
    const float* out_b    = (const float*)d_in[12];
    const float* gate_w   = (const float*)d_in[13];
    const float* gate_b   = (const float*)d_in[14];
    float* out = (float*)d_out;

    char* ws = (char*)d_ws;
    float* tfeat   = (float*)ws;                         // 512 B
    float* gcn_out = (float*)(ws + 512);                 // 15,974,400 B
    size_t off_ht  = 512 + (size_t)BB * NN * TT * DD * 4;
    size_t ht_size = (size_t)BB * TT * DD * HTM * 2 + 4096;
    size_t off_cw  = off_ht + ht_size;
    size_t off_wb  = off_cw + 32768;
    size_t wb_size = (size_t)3 * 1024 * 64 * 8 * 2;      // 3,145,728 B
    size_t off_wp  = off_wb + wb_size;

    const size_t per_wp  = 3 * (size_t)E2 * E2 * 2;      // 98304 B per node (bf16)
    const size_t per_qkv = 3 * (size_t)TT * E2 * 2;      // 18432 B per node (bf16)
    long long avail = (long long)ws_size - (long long)off_wp;
    long long Ull = avail / (long long)(per_wp + per_qkv);
    int U = (Ull < 1) ? 1 : ((Ull > NNODE) ? NNODE : (int)Ull);
    if (U > UCAP) U = UCAP;   // 2 passes, 129 MB wp chunk (L3-resident); grids stay >=1300 blocks

    unsigned short* ht_buf  = (unsigned short*)(ws + off_ht);
    unsigned short* cw_buf  = (unsigned short*)(ws + off_cw);
    unsigned short* wb_buf  = (unsigned short*)(ws + off_wb);
    unsigned short* wp_buf  = (unsigned short*)(ws + off_wp);
    unsigned short* qkv_buf = (unsigned short*)(ws + off_wp + (size_t)U * per_wp);

    k_tfeat<<<BB, DD, 0, stream>>>(tXin, tproj_w, tproj_b, tfeat);
    k_cw<<<1, 256, 0, stream>>>(out_w, gate_w, cw_buf);
    k_wconv<<<768, 256, 0, stream>>>(WQ_, WK_, WV_, wb_buf);
    k_ht<<<dim3(BB * TT, 6), 256, 0, stream>>>(hidden, ht_buf);
    k_gcn<<<dim3(BB * TT, 6), 256, 0, stream>>>(matrix, ht_buf, gcn_w, gcn_b, gcn_out);

    for (int u0 = 0; u0 < NNODE; u0 += U) {
        int Uc = (NNODE - u0 < U) ? (NNODE - u0) : U;
        k_wp<<<dim3((Uc + 15) / 16, 48), 256, 0, stream>>>(node_emb, tfeat, wb_buf,
                                                           wp_buf, u0, Uc);
        k_proj<<<Uc, 256, 0, stream>>>(hidden, tXin, wp_buf, qkv_buf, u0);
        k_attn2<<<Uc, 256, 0, stream>>>((const unsigned*)qkv_buf, hidden, cw_buf,
                                        out_b, gate_b, gcn_out, out, u0);
    }
}

// Round 22
// 267.101 us; speedup vs baseline: 1.5435x; 1.0444x over previous
//
#include <hip/hip_runtime.h>
#include <math.h>

#define BB 8
#define NN 325
#define TT 24
#define DD 64
#define HH 8
#define MM 16
#define E2 128
#define DK 16
#define NEG 0.1f
#define NNODE (BB * NN)          // 2600
#define HTM 328                  // padded m-extent of ht rows
#define UCAP 1312                // 2 passes; 129 MB wp chunk stays L3-resident, grids stay large

typedef short bf16x8 __attribute__((ext_vector_type(8)));
typedef float f32x4 __attribute__((ext_vector_type(4)));

__device__ __forceinline__ unsigned short f2bf(float f) {
    union { float f; unsigned u; } v; v.f = f;
    unsigned r = v.u + 0x7fffu + ((v.u >> 16) & 1u);   // RNE
    return (unsigned short)(r >> 16);
}
__device__ __forceinline__ unsigned packbf(float a, float b) {
    return (unsigned)f2bf(a) | ((unsigned)f2bf(b) << 16);
}
__device__ __forceinline__ float bflo(unsigned u) { return __uint_as_float(u << 16); }
__device__ __forceinline__ float bfhi(unsigned u) { return __uint_as_float(u & 0xffff0000u); }

__device__ __forceinline__ bf16x8 pack_bf8(float4 lo, float4 hi) {
    bf16x8 r;
    r[0] = (short)f2bf(lo.x); r[1] = (short)f2bf(lo.y);
    r[2] = (short)f2bf(lo.z); r[3] = (short)f2bf(lo.w);
    r[4] = (short)f2bf(hi.x); r[5] = (short)f2bf(hi.y);
    r[6] = (short)f2bf(hi.z); r[7] = (short)f2bf(hi.w);
    return r;
}

// ---------------- K_pre: merged prologue (tfeat | cw | wconv | ht), blockIdx-dispatched.
// bid 0..7: tfeat; bid 8: cw; bid 9..776: wconv; bid 777..1928: ht (bt, m-tile).
__global__ __launch_bounds__(256) void k_pre(
    const float* __restrict__ tXin, const float* __restrict__ tproj_w,
    const float* __restrict__ tproj_b, float* __restrict__ tfeat,
    const float* __restrict__ out_w, const float* __restrict__ gate_w,
    unsigned short* __restrict__ cw,
    const float* __restrict__ WQ, const float* __restrict__ WK,
    const float* __restrict__ WV, unsigned short* __restrict__ wb,
    const float* __restrict__ hidden, unsigned short* __restrict__ ht) {
    int bid = blockIdx.x;
    int tid = threadIdx.x;
    __shared__ float mv[DD];
    __shared__ float s[64][67];

    if (bid < BB) {
        // ---- tfeat[b][m] = tanh(mean_t(tXin[b,0,t,:]) @ tproj_w + tproj_b)
        int b = bid, d = tid;
        if (d < DD) {
            float a = 0.f;
            for (int t = 0; t < TT; ++t)
                a += tXin[((size_t)(b * NN + 0) * TT + t) * DD + d];
            mv[d] = a * (1.f / (float)TT);
        }
        __syncthreads();
        if (d < MM) {
            float acc = tproj_b[d];
            for (int j = 0; j < DD; ++j) acc += mv[j] * tproj_w[j * MM + d];
            tfeat[b * MM + d] = tanhf(acc);
        }
        return;
    }
    if (bid == BB) {
        // ---- cw: out_w/gate_w -> bf16 B-fragment layout
        for (int idx = tid; idx < 8192; idx += 256) {
            int i = idx >> 6, k = idx & 63;
            int nt = k >> 4, ks = i >> 5;
            int lane = (k & 15) | (((i >> 3) & 3) << 4);
            int off = (nt * 4 + ks) * 512 + lane * 8 + (i & 7);
            cw[off] = f2bf(out_w[i * 64 + k]);
            cw[8192 + off] = f2bf(gate_w[i * 64 + k]);
        }
        return;
    }
    if (bid < BB + 1 + 768) {
        // ---- wconv: W (fp32) -> bf16 A-fragment tensor over n = k*128 + i ordering
        int idx = (bid - BB - 1) * 256 + tid;   // < 196608
        int lane = idx & 63;
        int pt = idx >> 6;
        int T = pt & 1023, p = pt >> 10;
        const float* __restrict__ W = (p == 0) ? WQ : ((p == 1) ? WK : WV);
        int n = T * 16 + (lane & 15);
        int i = n & 127, k = n >> 7;
        int mb = (lane >> 4) * 8;
        unsigned short v[8];
#pragma unroll
        for (int j = 0; j < 8; ++j) {
            int m = mb + j;
            v[j] = (m < MM) ? f2bf(W[(size_t)m * 16384 + i * 128 + k]) : (unsigned short)0;
        }
        *(uint4*)&wb[(size_t)idx * 8] = *(const uint4*)v;
        return;
    }
    {
        // ---- ht: ht[bt][d][m] = bf16(hidden[b][m][t][d])  (transposed, padded to HTM)
        int bid2 = bid - (BB + 1 + 768);        // < 1152
        int bt = bid2 / 6;
        int b = bt / TT, t = bt % TT;
        int m0 = (bid2 % 6) * 64;
#pragma unroll
        for (int i = 0; i < 4; ++i) {
            int idx = tid + i * 256;
            int mm = idx >> 4, q = idx & 15;
            int m = m0 + mm;
            float4 v = make_float4(0.f, 0.f, 0.f, 0.f);
            if (m < NN) v = *(const float4*)&hidden[((size_t)(b * NN + m) * TT + t) * DD + q * 4];
            s[mm][q * 4 + 0] = v.x; s[mm][q * 4 + 1] = v.y;
            s[mm][q * 4 + 2] = v.z; s[mm][q * 4 + 3] = v.w;
        }
        __syncthreads();
        size_t obase = (size_t)bt * DD * HTM;
        int jcap = HTM - m0;
#pragma unroll
        for (int i = 0; i < 16; ++i) {
            int idx = tid + i * 256;
            int d = idx >> 6, j = idx & 63;
            if (j < jcap) ht[obase + (size_t)d * HTM + m0 + j] = f2bf(s[j][d]);
        }
    }
}

// ---------------- K2 (MFMA): S = matrix(b,t) @ H ; gcn_out = relu(S @ gcn_w + b)
// A-rows PREFETCHED into a named register array in a separate loop BEFORE any MFMA.
__global__ __launch_bounds__(256) void k_gcn(const float* __restrict__ matrix,
                                             const unsigned short* __restrict__ ht,
                                             const float* __restrict__ gcn_w,
                                             const float* __restrict__ gcn_b,
                                             float* __restrict__ gcn_out) {
    int bt = blockIdx.x;
    int tile = blockIdx.y;
    int b = bt / TT, t = bt % TT;
    int n0 = tile * 64;
    int tid = threadIdx.x, lane = tid & 63, wid = tid >> 6;
    int cl = lane & 15, kg = lane >> 4;

    __shared__ unsigned short s_s[64][72];    // S bf16 [n][d]
    __shared__ unsigned short s_gw[64][72];   // gw^T bf16 [e][d]

#pragma unroll
    for (int i = 0; i < 4; ++i) {
        int idx = tid + i * 256;
        int d = idx >> 4, e0 = (idx & 15) * 4;
        float4 v = *(const float4*)&gcn_w[d * DD + e0];
        s_gw[e0 + 0][d] = f2bf(v.x); s_gw[e0 + 1][d] = f2bf(v.y);
        s_gw[e0 + 2][d] = f2bf(v.z); s_gw[e0 + 3][d] = f2bf(v.w);
    }
    __syncthreads();

    const float* mrow = matrix + (size_t)bt * NN * NN;
    const unsigned short* hbase = ht + (size_t)bt * DD * HTM;
    int strip = wid * 16;
    int arow = n0 + strip + cl;
    bool avalid = arow < NN;
    const float* arp = mrow + (size_t)arow * NN;

    // ---- phase 0: issue ALL 10 A-row segment loads (20 float4) up front
    float4 aA[10][2];
#pragma unroll
    for (int s = 0; s < 10; ++s) {
        int m0 = s * 32 + kg * 8;
        if (avalid) {
            aA[s][0] = *(const float4*)&arp[m0];
            aA[s][1] = *(const float4*)&arp[m0 + 4];
        } else {
            aA[s][0] = make_float4(0.f, 0.f, 0.f, 0.f);
            aA[s][1] = aA[s][0];
        }
    }
    float vtail[8];
    {
        int m0 = 320 + kg * 8;
#pragma unroll
        for (int j = 0; j < 8; ++j)
            vtail[j] = (avalid && (m0 + j) < NN) ? arp[m0 + j] : 0.f;
    }

    f32x4 acc[4];
#pragma unroll
    for (int nt = 0; nt < 4; ++nt) acc[nt] = (f32x4){0.f, 0.f, 0.f, 0.f};

    // ---- phase 1: pack + MFMA sweep (A already in registers; B is L2-resident)
#pragma unroll
    for (int s = 0; s < 10; ++s) {
        int m0 = s * 32 + kg * 8;
        bf16x8 af = pack_bf8(aA[s][0], aA[s][1]);
#pragma unroll
        for (int nt = 0; nt < 4; ++nt) {
            union { uint4 u4; bf16x8 v; } bf;
            bf.u4 = *(const uint4*)&hbase[(size_t)(nt * 16 + cl) * HTM + m0];
            acc[nt] = __builtin_amdgcn_mfma_f32_16x16x32_bf16(af, bf.v, acc[nt], 0, 0, 0);
        }
    }
    {
        int m0 = 320 + kg * 8;
        bf16x8 af = pack_bf8(make_float4(vtail[0], vtail[1], vtail[2], vtail[3]),
                             make_float4(vtail[4], vtail[5], vtail[6], vtail[7]));
#pragma unroll
        for (int nt = 0; nt < 4; ++nt) {
            union { uint4 u4; bf16x8 v4; } bf;
            bf.u4 = *(const uint4*)&hbase[(size_t)(nt * 16 + cl) * HTM + m0];
            acc[nt] = __builtin_amdgcn_mfma_f32_16x16x32_bf16(af, bf.v4, acc[nt], 0, 0, 0);
        }
    }

#pragma unroll
    for (int nt = 0; nt < 4; ++nt)
#pragma unroll
        for (int r = 0; r < 4; ++r)
            s_s[strip + kg * 4 + r][nt * 16 + cl] = f2bf(acc[nt][r]);

    f32x4 g[4];
#pragma unroll
    for (int nt = 0; nt < 4; ++nt) g[nt] = (f32x4){0.f, 0.f, 0.f, 0.f};
#pragma unroll
    for (int kk = 0; kk < 2; ++kk) {
        union { uint4 u4; bf16x8 v; } sa;
        sa.u4 = *(const uint4*)&s_s[strip + cl][kk * 32 + kg * 8];
#pragma unroll
        for (int nt = 0; nt < 4; ++nt) {
            union { uint4 u4; bf16x8 v; } bf;
            bf.u4 = *(const uint4*)&s_gw[nt * 16 + cl][kk * 32 + kg * 8];
            g[nt] = __builtin_amdgcn_mfma_f32_16x16x32_bf16(sa.v, bf.v, g[nt], 0, 0, 0);
        }
    }

#pragma unroll
    for (int nt = 0; nt < 4; ++nt) {
        float bias = gcn_b[nt * 16 + cl];
#pragma unroll
        for (int r = 0; r < 4; ++r) {
            int n = n0 + strip + kg * 4 + r;
            if (n < NN) {
                float v = g[nt][r] + bias;
                v = (v > 0.f) ? v : 0.f;
                gcn_out[((size_t)(b * NN + n) * TT + t) * DD + nt * 16 + cl] = v;
            }
        }
    }
}

// ---------------- K3a (MFMA): Wp[u] = e_u-weighted sum of W; LDS-staged coalesced writeout.
__global__ __launch_bounds__(256) void k_wp(
    const float* __restrict__ node_emb, const float* __restrict__ tfeat,
    const unsigned short* __restrict__ wb, unsigned short* __restrict__ wp,
    int u0, int Uc) {
    int un0 = blockIdx.x * 16;
    int chunk = blockIdx.y;                 // 0..47
    int p = chunk >> 4, tr = chunk & 15;
    int tid = threadIdx.x, lane = tid & 63, wid = tid >> 6;

    __shared__ float s_e[16][MM];
    __shared__ __align__(16) unsigned short s_out[16 * 1032];   // ~33 KB

    {
        int nn = tid >> 4, m = tid & 15;    // 256 = 16*16 exactly
        int us = un0 + nn;
        float e = 0.f;
        if (us < Uc) {
            int u = u0 + us;
            int b = u / NN, n = u % NN;
            e = node_emb[n * MM + m] * tfeat[b * MM + m];
        }
        s_e[nn][m] = e;
    }
    __syncthreads();

    int node = lane & 15;
    int mb = (lane >> 4) * 8;
    bf16x8 ef = {0, 0, 0, 0, 0, 0, 0, 0};
    if (mb < MM) {
#pragma unroll
        for (int j = 0; j < 8; ++j) ef[j] = (short)f2bf(s_e[node][mb + j]);
    }
    const unsigned short* wsrc = wb + (size_t)p * 1024 * 512;

#pragma unroll 1
    for (int t16 = 0; t16 < 16; ++t16) {
        int T = tr * 64 + wid * 16 + t16;
        union { uint4 u4; bf16x8 v; } af;
        af.u4 = *(const uint4*)&wsrc[((size_t)T * 64 + lane) * 8];
        f32x4 acc = {0.f, 0.f, 0.f, 0.f};
        acc = __builtin_amdgcn_mfma_f32_16x16x32_bf16(af.v, ef, acc, 0, 0, 0);
        int k = T >> 3;
        int i0 = (T & 7) * 16 + (lane >> 4) * 4;
        int ksl = i0 >> 5, Ll = (i0 >> 3) & 3, jf0 = i0 & 7, kk = k & 7;
        int loc = node * 1032 + ((ksl * 4 + Ll) * 8 + kk) * 8 + jf0;
        uint2 pk;
        pk.x = packbf(acc[0], acc[1]);
        pk.y = packbf(acc[2], acc[3]);
        *(uint2*)&s_out[loc] = pk;
    }
    __syncthreads();

    // coalesced writeout: 2048 uint4, 8/thread; 8-lane groups write 128 B contiguous runs
    int nt = tr >> 1, c1 = tr & 1;
    size_t gbase = (size_t)p * 16384 + (size_t)nt * 2048 + (size_t)c1 * 64;
#pragma unroll
    for (int step = 0; step < 8; ++step) {
        int idx = step * 256 + tid;
        int nd = idx >> 7, rem = idx & 127;
        int ksw = rem >> 5, Lw = (rem >> 3) & 3, q = rem & 7;
        int us = un0 + nd;
        if (us < Uc) {
            uint4 v = *(const uint4*)&s_out[nd * 1032 + ((ksw * 4 + Lw) * 8 + q) * 8];
            *(uint4*)&wp[(size_t)us * 49152 + gbase + (size_t)ksw * 512 + Lw * 128 + q * 8] = v;
        }
    }
}

// ---------------- K3b: per node MFMA proj -> lrelu -> qkv bf16 to workspace.
__global__ __launch_bounds__(256) void k_proj(
    const float* __restrict__ hidden, const float* __restrict__ tXin,
    const unsigned short* __restrict__ wp, unsigned short* __restrict__ qkv,
    int u0) {
    int us = blockIdx.x;
    int u = u0 + us;
    int tid = threadIdx.x;
    int lane = tid & 63, wid = tid >> 6;
    int trow = lane & 15, kgrp = lane >> 4;

    size_t base = (size_t)u * TT * DD;

    bf16x8 afrag[2][4];
#pragma unroll
    for (int mt = 0; mt < 2; ++mt) {
        int t = mt * 16 + trow;
        bool valid = (t < TT);
#pragma unroll
        for (int ks = 0; ks < 4; ++ks) {
            int i0 = ks * 32 + kgrp * 8;
            float4 lo = make_float4(0.f, 0.f, 0.f, 0.f), hi = lo;
            if (valid) {
                const float* src = (i0 < DD) ? &hidden[base + t * DD + i0]
                                             : &tXin[base + t * DD + (i0 - DD)];
                lo = *(const float4*)src;
                hi = *(const float4*)(src + 4);
            }
            afrag[mt][ks] = pack_bf8(lo, hi);
        }
    }

    const unsigned short* wbase = wp + (size_t)us * 49152;
    unsigned short* qbase = qkv + (size_t)us * (3 * TT * E2);
    int rowg = kgrp * 4;
    int col0 = wid * 16 + trow;
    int col1 = (wid + 4) * 16 + trow;
#pragma unroll 1
    for (int p = 0; p < 3; ++p) {
        f32x4 acc00 = {0.f, 0.f, 0.f, 0.f}, acc01 = acc00, acc10 = acc00, acc11 = acc00;
#pragma unroll
        for (int ks = 0; ks < 4; ++ks) {
            union { uint4 u4; bf16x8 v; } c0, c1;
            c0.u4 = *(const uint4*)(wbase + (size_t)p * 16384 + (((wid) * 4 + ks) * 64 + lane) * 8);
            c1.u4 = *(const uint4*)(wbase + (size_t)p * 16384 + (((wid + 4) * 4 + ks) * 64 + lane) * 8);
            acc00 = __builtin_amdgcn_mfma_f32_16x16x32_bf16(afrag[0][ks], c0.v, acc00, 0, 0, 0);
            acc10 = __builtin_amdgcn_mfma_f32_16x16x32_bf16(afrag[1][ks], c0.v, acc10, 0, 0, 0);
            acc01 = __builtin_amdgcn_mfma_f32_16x16x32_bf16(afrag[0][ks], c1.v, acc01, 0, 0, 0);
            acc11 = __builtin_amdgcn_mfma_f32_16x16x32_bf16(afrag[1][ks], c1.v, acc11, 0, 0, 0);
        }
#pragma unroll
        for (int r = 0; r < 4; ++r) {
            int t = rowg + r;
            float v0 = acc00[r]; v0 = (v0 >= 0.f) ? v0 : NEG * v0;
            float v1 = acc01[r]; v1 = (v1 >= 0.f) ? v1 : NEG * v1;
            qbase[(p * TT + t) * E2 + col0] = f2bf(v0);
            qbase[(p * TT + t) * E2 + col1] = f2bf(v1);
        }
        if (rowg < 8) {
#pragma unroll
            for (int r = 0; r < 4; ++r) {
                int t = 16 + rowg + r;
                float v0 = acc10[r]; v0 = (v0 >= 0.f) ? v0 : NEG * v0;
                float v1 = acc11[r]; v1 = (v1 >= 0.f) ? v1 : NEG * v1;
                qbase[(p * TT + t) * E2 + col0] = f2bf(v0);
                qbase[(p * TT + t) * E2 + col1] = f2bf(v1);
            }
        }
    }
}

// ---------------- K3c: per node: attention (scalar C1/C2) + MFMA out-proj/gate + residual
#define QKS 66
#define QKP (TT * QKS)
#define SC_OFF 4752
#define VAL_OFF 7248
#define VQS 68
__global__ __launch_bounds__(256) void k_attn2(
    const unsigned* __restrict__ qkv, const float* __restrict__ hidden,
    const unsigned short* __restrict__ cw,
    const float* __restrict__ out_b, const float* __restrict__ gate_b,
    const float* __restrict__ gcn_out, float* __restrict__ out,
    int u0) {
    int us = blockIdx.x;
    int u = u0 + us;
    int tid = threadIdx.x;

    __shared__ __align__(16) unsigned arena[8880];
    __shared__ float s_gcn[TT][VQS];
    __shared__ float s_value[TT][VQS];

    size_t base = (size_t)u * TT * DD;

    const unsigned* src = qkv + (size_t)us * (3 * TT * 64);
    for (int idx = tid; idx < 3 * TT * 64; idx += 256) {
        int p = idx / (TT * 64);
        int r = idx % (TT * 64);
        int t = r >> 6, kp = r & 63;
        arena[p * QKP + t * QKS + kp] = src[idx];
    }
    for (int idx = tid; idx < TT * DD; idx += 256)
        s_gcn[idx >> 6][idx & 63] = gcn_out[base + idx];
    unsigned* s_qkv = arena;
    __syncthreads();

    // ---- phase C1: scores (scalar)
    unsigned* s_sc = arena + SC_OFF;
    if (tid < HH * TT) {
        int h = tid / TT, t = tid % TT;
        const float scale = 0.25f;
        float qf[16];
#pragma unroll
        for (int j = 0; j < 8; ++j) {
            unsigned uq = s_qkv[0 * QKP + t * QKS + 8 * h + j];
            qf[2 * j] = bflo(uq); qf[2 * j + 1] = bfhi(uq);
        }
#pragma unroll
        for (int s2 = 0; s2 < 12; ++s2) {
            int s0 = 2 * s2;
            float d0 = 0.f, d1 = 0.f;
#pragma unroll
            for (int j = 0; j < 8; ++j) {
                unsigned ka = s_qkv[1 * QKP + s0 * QKS + 8 * h + j];
                unsigned kb = s_qkv[1 * QKP + (s0 + 1) * QKS + 8 * h + j];
                d0 += qf[2 * j] * bflo(ka) + qf[2 * j + 1] * bfhi(ka);
                d1 += qf[2 * j] * bflo(kb) + qf[2 * j + 1] * bfhi(kb);
            }
            float w0 = (s0 <= t) ? __expf(d0 * scale) : 0.f;
            float w1 = (s0 + 1 <= t) ? __expf(d1 * scale) : 0.f;
            s_sc[(h * TT + t) * 13 + s2] = packbf(w0, w1);
        }
    }
    __syncthreads();

    // ---- phase C2: normalize + PV -> packed val[24][VQS]
    unsigned* s_val = arena + VAL_OFF;
#pragma unroll
    for (int it = 0; it < 3; ++it) {
        int item = tid + it * 256;
        int h = item / 96;
        int r = item % 96;
        int t = r >> 2, d4 = r & 3;
        int kg0 = 8 * h + 2 * d4;
        float sum = 0.f, v0 = 0.f, v1 = 0.f, v2 = 0.f, v3 = 0.f;
#pragma unroll
        for (int s2 = 0; s2 < 12; ++s2) {
            unsigned uw = s_sc[(h * TT + t) * 13 + s2];
            float w0 = bflo(uw), w1 = bfhi(uw);
            sum += w0 + w1;
            unsigned ua = s_qkv[2 * QKP + (2 * s2) * QKS + kg0];
            unsigned ub = s_qkv[2 * QKP + (2 * s2) * QKS + kg0 + 1];
            v0 += w0 * bflo(ua); v1 += w0 * bfhi(ua);
            v2 += w0 * bflo(ub); v3 += w0 * bfhi(ub);
            unsigned uc = s_qkv[2 * QKP + (2 * s2 + 1) * QKS + kg0];
            unsigned ud = s_qkv[2 * QKP + (2 * s2 + 1) * QKS + kg0 + 1];
            v0 += w1 * bflo(uc); v1 += w1 * bfhi(uc);
            v2 += w1 * bflo(ud); v3 += w1 * bfhi(ud);
        }
        float inv = 1.f / sum;
        s_val[t * VQS + kg0]     = packbf(v0 * inv, v1 * inv);
        s_val[t * VQS + kg0 + 1] = packbf(v2 * inv, v3 * inv);
    }
    __syncthreads();

    // ---- phase D (MFMA): value = lrelu(val @ out_w + out_b)
    int lane = tid & 63, wid = tid >> 6;
    int cl = lane & 15, kg = lane >> 4;
    {
        f32x4 d0 = {0.f, 0.f, 0.f, 0.f}, d1 = d0;
#pragma unroll
        for (int ks = 0; ks < 4; ++ks) {
            union { uint4 u4; bf16x8 v; } a0, a1, bw;
            a0.u4 = *(const uint4*)&s_val[cl * VQS + ks * 16 + kg * 4];
            if (cl < 8) a1.u4 = *(const uint4*)&s_val[(16 + cl) * VQS + ks * 16 + kg * 4];
            else a1.u4 = make_uint4(0, 0, 0, 0);
            bw.u4 = *(const uint4*)&cw[((size_t)(wid * 4 + ks) * 64 + lane) * 8];
            d0 = __builtin_amdgcn_mfma_f32_16x16x32_bf16(a0.v, bw.v, d0, 0, 0, 0);
            d1 = __builtin_amdgcn_mfma_f32_16x16x32_bf16(a1.v, bw.v, d1, 0, 0, 0);
        }
        int col = wid * 16 + cl;
        float bias = out_b[col];
#pragma unroll
        for (int r = 0; r < 4; ++r) {
            int t = kg * 4 + r;
            float v = d0[r] + bias; v = (v >= 0.f) ? v : NEG * v;
            s_value[t][col] = v;
        }
        if (kg < 2) {
#pragma unroll
            for (int r = 0; r < 4; ++r) {
                int t = 16 + kg * 4 + r;
                float v = d1[r] + bias; v = (v >= 0.f) ? v : NEG * v;
                s_value[t][col] = v;
            }
        }
    }
    __syncthreads();

    // ---- phase E (MFMA): z = sigmoid([gcn|value] @ gate_w + gate_b); out = z*g + (1-z)*v + hidden
    {
        f32x4 g0 = {0.f, 0.f, 0.f, 0.f}, g1 = g0;
#pragma unroll
        for (int ks = 0; ks < 4; ++ks) {
            int i0 = ks * 32 + kg * 8;
            const float* src0 = (i0 < DD) ? &s_gcn[cl][i0] : &s_value[cl][i0 - DD];
            float4 lo = *(const float4*)src0;
            float4 hi = *(const float4*)(src0 + 4);
            bf16x8 a0 = pack_bf8(lo, hi);
            bf16x8 a1 = {0, 0, 0, 0, 0, 0, 0, 0};
            if (cl < 8) {
                const float* src1 = (i0 < DD) ? &s_gcn[16 + cl][i0] : &s_value[16 + cl][i0 - DD];
                float4 lo1 = *(const float4*)src1;
                float4 hi1 = *(const float4*)(src1 + 4);
                a1 = pack_bf8(lo1, hi1);
            }
            union { uint4 u4; bf16x8 v; } bw;
            bw.u4 = *(const uint4*)&cw[8192 + ((size_t)(wid * 4 + ks) * 64 + lane) * 8];
            g0 = __builtin_amdgcn_mfma_f32_16x16x32_bf16(a0, bw.v, g0, 0, 0, 0);
            g1 = __builtin_amdgcn_mfma_f32_16x16x32_bf16(a1, bw.v, g1, 0, 0, 0);
        }
        int col = wid * 16 + cl;
        float gb = gate_b[col];
#pragma unroll
        for (int r = 0; r < 4; ++r) {
            int t = kg * 4 + r;
            float z = 1.f / (1.f + __expf(-(g0[r] + gb)));
            float gv = s_gcn[t][col], vv = s_value[t][col];
            size_t ob = base + (size_t)t * DD + col;
            out[ob] = z * gv + (1.f - z) * vv + hidden[ob];
        }
        if (kg < 2) {
#pragma unroll
            for (int r = 0; r < 4; ++r) {
                int t = 16 + kg * 4 + r;
                float z = 1.f / (1.f + __expf(-(g1[r] + gb)));
                float gv = s_gcn[t][col], vv = s_value[t][col];
                size_t ob = base + (size_t)t * DD + col;
                out[ob] = z * gv + (1.f - z) * vv + hidden[ob];
            }
        }
    }
}

extern "C" void kernel_launch(void* const* d_in, const int* in_sizes, int n_in,
                              void* d_out, int out_size, void* d_ws, size_t ws_size,
                              hipStream_t stream) {
    const float* hidden   = (const float*)d_in[0];
    const float* tXin     = (const float*)d_in[1];
    const float* matrix   = (const float*)d_in[2];
    const float* gcn_w    = (const float*)d_in[3];
    const float* gcn_b    = (const float*)d_in[4];
    const float* node_emb = (const float*)d_in[5];
    const float* tproj_w  = (const float*)d_in[6];
    const float* tproj_b  = (const float*)d_in[7];
    const float* WK_      = (const float*)d_in[8];   // dict order: WK, WQ, WV
    const float* WQ_      = (const float*)d_in[9];
    const float* WV_      = (const float*)d_in[10];
    const float* out_w    = (const float*)d_in[11];
    const float* out_b    = (const float*)d_in[12];
    const float* gate_w   = (const float*)d_in[13];
    const float* gate_b   = (const float*)d_in[14];
    float* out = (float*)d_out;

    char* ws = (char*)d_ws;
    float* tfeat   = (float*)ws;                         // 512 B
    float* gcn_out = (float*)(ws + 512);                 // 15,974,400 B
    size_t off_ht  = 512 + (size_t)BB * NN * TT * DD * 4;
    size_t ht_size = (size_t)BB * TT * DD * HTM * 2 + 4096;
    size_t off_cw  = off_ht + ht_size;
    size_t off_wb  = off_cw + 32768;
    size_t wb_size = (size_t)3 * 1024 * 64 * 8 * 2;      // 3,145,728 B
    size_t off_wp  = off_wb + wb_size;

    const size_t per_wp  = 3 * (size_t)E2 * E2 * 2;      // 98304 B per node (bf16)
    const size_t per_qkv = 3 * (size_t)TT * E2 * 2;      // 18432 B per node (bf16)
    long long avail = (long long)ws_size - (long long)off_wp;
    long long Ull = avail / (long long)(per_wp + per_qkv);
    int U = (Ull < 1) ? 1 : ((Ull > NNODE) ? NNODE : (int)Ull);
    if (U > UCAP) U = UCAP;   // 2 passes, 129 MB wp chunk (L3-resident); grids stay >=1300 blocks

    unsigned short* ht_buf  = (unsigned short*)(ws + off_ht);
    unsigned short* cw_buf  = (unsigned short*)(ws + off_cw);
    unsigned short* wb_buf  = (unsigned short*)(ws + off_wb);
    unsigned short* wp_buf  = (unsigned short*)(ws + off_wp);
    unsigned short* qkv_buf = (unsigned short*)(ws + off_wp + (size_t)U * per_wp);

    // merged prologue: tfeat(8) | cw(1) | wconv(768) | ht(1152) = 1929 blocks
    k_pre<<<BB + 1 + 768 + 1152, 256, 0, stream>>>(
        tXin, tproj_w, tproj_b, tfeat, out_w, gate_w, cw_buf,
        WQ_, WK_, WV_, wb_buf, hidden, ht_buf);
    k_gcn<<<dim3(BB * TT, 6), 256, 0, stream>>>(matrix, ht_buf, gcn_w, gcn_b, gcn_out);

    for (int u0 = 0; u0 < NNODE; u0 += U) {
        int Uc = (NNODE - u0 < U) ? (NNODE - u0) : U;
        k_wp<<<dim3((Uc + 15) / 16, 48), 256, 0, stream>>>(node_emb, tfeat, wb_buf,
                                                           wp_buf, u0, Uc);
        k_proj<<<Uc, 256, 0, stream>>>(hidden, tXin, wp_buf, qkv_buf, u0);
        k_attn2<<<Uc, 256, 0, stream>>>((const unsigned*)qkv_buf, hidden, cw_buf,
                                        out_b, gate_b, gcn_out, out, u0);
    }
}